// Round 1
// baseline (1822.148 us; speedup 1.0000x reference)
//
#include <hip/hip_runtime.h>
#include <hip/hip_bf16.h>
#include <cstdint>

#define HDIM 128
#define BN_EPS 1e-5f

static inline size_t align256(size_t x) { return (x + 255) & ~size_t(255); }

// ---------- edge dtype detection (int64 vs int32) ----------
__global__ void detect_kernel(const int* __restrict__ ebuf, int* __restrict__ flag) {
    __shared__ int r[256];
    int tid = threadIdx.x;
    int o = 0;
    for (int i = tid; i < 4096; i += 256) o |= ebuf[2 * i + 1];
    r[tid] = o;
    __syncthreads();
    for (int s = 128; s > 0; s >>= 1) {
        if (tid < s) r[tid] |= r[tid + s];
        __syncthreads();
    }
    if (tid == 0) *flag = (r[0] == 0) ? 1 : 0;  // all-zero odd words => int64
}

__global__ void convert_edges(const int* __restrict__ ebuf, const int* __restrict__ flag,
                              int* __restrict__ es, int* __restrict__ ed, int E) {
    int e = blockIdx.x * 256 + threadIdx.x;
    if (e >= E) return;
    if (*flag) { es[e] = ebuf[2 * e]; ed[e] = ebuf[2 * (E + e)]; }
    else       { es[e] = ebuf[e];     ed[e] = ebuf[E + e]; }
}

// ---------- degree / norm ----------
__global__ void deg_count(const int* __restrict__ ed, int* __restrict__ deg, int E) {
    int e = blockIdx.x * 256 + threadIdx.x;
    if (e < E) atomicAdd(&deg[ed[e]], 1);
}

__global__ void dinv_kernel(const int* __restrict__ deg, float* __restrict__ dinv, int n) {
    int i = blockIdx.x * 256 + threadIdx.x;
    if (i < n) dinv[i] = rsqrtf((float)(deg[i] + 1));  // +1 self-loop
}

// ---------- exclusive scan of deg -> row_ptr (single block, shfl-based) ----------
__global__ __launch_bounds__(1024) void scan_kernel(const int* __restrict__ deg,
                                                    int* __restrict__ row_ptr,
                                                    int* __restrict__ cursor, int n) {
    __shared__ int wsum[16];
    __shared__ int chunk_off;
    int tid = threadIdx.x, lane = tid & 63, w = tid >> 6;
    if (tid == 0) chunk_off = 0;
    __syncthreads();
    for (int base = 0; base < n; base += 1024) {
        int i = base + tid;
        int v = (i < n) ? deg[i] : 0;
        int x = v;
        for (int off = 1; off < 64; off <<= 1) {
            int y = __shfl_up(x, off);
            if (lane >= off) x += y;
        }
        if (lane == 63) wsum[w] = x;
        __syncthreads();
        if (w == 0 && lane < 16) {
            int s = wsum[lane];
            for (int off = 1; off < 16; off <<= 1) {
                int y = __shfl_up(s, off);
                if (lane >= off) s += y;
            }
            wsum[lane] = s;
        }
        __syncthreads();
        int waveoff = (w > 0) ? wsum[w - 1] : 0;
        int incl = x + waveoff + chunk_off;
        if (i < n) { int ex = incl - v; row_ptr[i] = ex; cursor[i] = ex; }
        __syncthreads();
        if (tid == 1023) chunk_off = incl;
        __syncthreads();
    }
    if (threadIdx.x == 0) row_ptr[n] = chunk_off;
}

__global__ void fill_csr(const int* __restrict__ es, const int* __restrict__ ed,
                         const float* __restrict__ dinv, int* __restrict__ cursor,
                         int* __restrict__ csr_src, float* __restrict__ csr_w, int E) {
    int e = blockIdx.x * 256 + threadIdx.x;
    if (e >= E) return;
    int s = es[e], d = ed[e];
    int pos = atomicAdd(&cursor[d], 1);
    csr_src[pos] = s;
    csr_w[pos] = dinv[s] * dinv[d];
}

// ---------- BN statistics (deterministic 2-stage) ----------
__global__ __launch_bounds__(256) void bn_partial(const float* __restrict__ x,
                                                  float* __restrict__ part, int n) {
    int c = threadIdx.x;   // 0..127
    int yy = threadIdx.y;  // 0..1
    int b = blockIdx.x;
    int chunk = (n + gridDim.x - 1) / gridDim.x;
    int start = b * chunk, end = min(start + chunk, n);
    float s = 0.f, s2 = 0.f;
    for (int r = start + yy; r < end; r += 2) {
        float v = x[(size_t)r * HDIM + c];
        s += v; s2 += v * v;
    }
    __shared__ float sh[2][HDIM][2];
    sh[yy][c][0] = s; sh[yy][c][1] = s2;
    __syncthreads();
    if (yy == 0) {
        part[((size_t)b * HDIM + c) * 2 + 0] = s + sh[1][c][0];
        part[((size_t)b * HDIM + c) * 2 + 1] = s2 + sh[1][c][1];
    }
}

__global__ __launch_bounds__(128) void bn_finalize(const float* __restrict__ part,
                                                   const float* __restrict__ gamma,
                                                   const float* __restrict__ beta,
                                                   const float* __restrict__ W,
                                                   float* __restrict__ Wp,
                                                   float* __restrict__ hb, int n, int nb) {
    int c = threadIdx.x;
    float s = 0.f, s2 = 0.f;
    for (int b = 0; b < nb; ++b) {
        s  += part[((size_t)b * HDIM + c) * 2 + 0];
        s2 += part[((size_t)b * HDIM + c) * 2 + 1];
    }
    float mean = s / n;
    float var = s2 / n - mean * mean;
    float sc = gamma[c] * rsqrtf(var + BN_EPS);
    float sf = beta[c] - mean * sc;
    __shared__ float scs[HDIM], shs[HDIM];
    scs[c] = sc; shs[c] = sf;
    __syncthreads();
    float acc = 0.f;
    for (int k = 0; k < HDIM; ++k) {
        float w = W[k * HDIM + c];
        Wp[k * HDIM + c] = scs[k] * w;
        acc += shs[k] * w;
    }
    hb[c] = acc;
}

// ---------- GEMM: h[N][128] = x[N][128] @ Wp + hb ----------
__global__ __launch_bounds__(256) void gemm128(const float* __restrict__ x,
                                               const float* __restrict__ Wp,
                                               const float* __restrict__ hb,
                                               float* __restrict__ h, int n) {
    __shared__ __align__(16) float wls[HDIM * HDIM];  // 64 KiB
    __shared__ __align__(16) float xs[16 * HDIM];     // 8 KiB
    __shared__ float hbs[HDIM];
    int t = threadIdx.x;
    {
        const float4* w4 = (const float4*)Wp;
        float4* l4 = (float4*)wls;
#pragma unroll
        for (int i = 0; i < 16; ++i) l4[t + 256 * i] = w4[t + 256 * i];
    }
    if (t < HDIM) hbs[t] = hb[t];
    int lane = t & 63, wv = t >> 6;
    const float2* wl2 = (const float2*)wls;
    const float4* xs4 = (const float4*)xs;
    int rowBase = blockIdx.x * 128;
    for (int chunk = 0; chunk < 128; chunk += 16) {
        int cb = rowBase + chunk;
        __syncthreads();
#pragma unroll
        for (int i = 0; i < 2; ++i) {
            int idx = t + 256 * i;       // float4 index into xs (512 total)
            int r = idx >> 5, c4 = idx & 31;
            int gr = cb + r;
            float4 v = make_float4(0.f, 0.f, 0.f, 0.f);
            if (gr < n) v = ((const float4*)x)[(size_t)gr * 32 + c4];
            ((float4*)xs)[idx] = v;
        }
        __syncthreads();
        int r0 = wv * 4;
        float2 a0 = make_float2(0.f, 0.f), a1 = a0, a2 = a0, a3 = a0;
#pragma unroll 4
        for (int k4 = 0; k4 < 32; ++k4) {
            float4 xr0 = xs4[(r0 + 0) * 32 + k4];
            float4 xr1 = xs4[(r0 + 1) * 32 + k4];
            float4 xr2 = xs4[(r0 + 2) * 32 + k4];
            float4 xr3 = xs4[(r0 + 3) * 32 + k4];
#define KSTEP(kk, e0, e1, e2, e3)                                   \
            {                                                        \
                float2 wvv = wl2[(k4 * 4 + kk) * 64 + lane];         \
                a0.x = fmaf(e0, wvv.x, a0.x); a0.y = fmaf(e0, wvv.y, a0.y); \
                a1.x = fmaf(e1, wvv.x, a1.x); a1.y = fmaf(e1, wvv.y, a1.y); \
                a2.x = fmaf(e2, wvv.x, a2.x); a2.y = fmaf(e2, wvv.y, a2.y); \
                a3.x = fmaf(e3, wvv.x, a3.x); a3.y = fmaf(e3, wvv.y, a3.y); \
            }
            KSTEP(0, xr0.x, xr1.x, xr2.x, xr3.x)
            KSTEP(1, xr0.y, xr1.y, xr2.y, xr3.y)
            KSTEP(2, xr0.z, xr1.z, xr2.z, xr3.z)
            KSTEP(3, xr0.w, xr1.w, xr2.w, xr3.w)
#undef KSTEP
        }
        float hb0 = hbs[2 * lane], hb1 = hbs[2 * lane + 1];
        int gr0 = cb + r0;
        if (gr0 + 0 < n) ((float2*)h)[(size_t)(gr0 + 0) * 64 + lane] = make_float2(a0.x + hb0, a0.y + hb1);
        if (gr0 + 1 < n) ((float2*)h)[(size_t)(gr0 + 1) * 64 + lane] = make_float2(a1.x + hb0, a1.y + hb1);
        if (gr0 + 2 < n) ((float2*)h)[(size_t)(gr0 + 2) * 64 + lane] = make_float2(a2.x + hb0, a2.y + hb1);
        if (gr0 + 3 < n) ((float2*)h)[(size_t)(gr0 + 3) * 64 + lane] = make_float2(a3.x + hb0, a3.y + hb1);
    }
}

// ---------- aggregation: x_next[d] = relu(sum_e w_e h[src_e] + dinv[d]^2 h[d] + b) ----------
__global__ __launch_bounds__(256) void agg_kernel(const float* __restrict__ h,
                                                  const int* __restrict__ row_ptr,
                                                  const int* __restrict__ csr_src,
                                                  const float* __restrict__ csr_w,
                                                  const float* __restrict__ dinv,
                                                  const float* __restrict__ bias,
                                                  float* __restrict__ xn, int n) {
    int c = threadIdx.x;                    // 0..127
    int d = blockIdx.x * 2 + threadIdx.y;   // node
    if (d >= n) return;
    float dv = dinv[d];
    float acc = dv * dv * h[(size_t)d * HDIM + c];
    int e0 = row_ptr[d], e1 = row_ptr[d + 1];
    for (int e = e0; e < e1; ++e) {
        int s = csr_src[e];
        float w = csr_w[e];
        acc = fmaf(w, h[(size_t)s * HDIM + c], acc);
    }
    xn[(size_t)d * HDIM + c] = fmaxf(acc + bias[c], 0.f);
}

// ---------- final projection: out[N][40] = x @ Wo + bo ----------
__global__ __launch_bounds__(320) void gemm_out(const float* __restrict__ x,
                                                const float* __restrict__ Wo,
                                                const float* __restrict__ bo,
                                                float* __restrict__ out, int n, int C) {
    __shared__ __align__(16) float wls[HDIM * 40];   // 20 KiB
    __shared__ __align__(16) float xs[32 * HDIM];    // 16 KiB
    __shared__ float bos[40];
    int t = threadIdx.x;
    for (int i = t; i < HDIM * 40; i += 320) wls[i] = Wo[i];
    if (t < 40) bos[t] = bo[t];
    int c = t % 40, lr = t / 40;  // lr in 0..7
    int rowBase = blockIdx.x * 32;
    for (int i = t; i < 1024; i += 320) {  // 1024 float4 = 32 rows
        int r = i >> 5, c4 = i & 31;
        int gr = rowBase + r;
        float4 v = make_float4(0.f, 0.f, 0.f, 0.f);
        if (gr < n) v = ((const float4*)x)[(size_t)gr * 32 + c4];
        ((float4*)xs)[i] = v;
    }
    __syncthreads();
    const float4* xsr0 = (const float4*)(xs + (lr + 0) * HDIM);
    const float4* xsr1 = (const float4*)(xs + (lr + 8) * HDIM);
    const float4* xsr2 = (const float4*)(xs + (lr + 16) * HDIM);
    const float4* xsr3 = (const float4*)(xs + (lr + 24) * HDIM);
    float acc0 = 0.f, acc1 = 0.f, acc2 = 0.f, acc3 = 0.f;
#pragma unroll 4
    for (int k4 = 0; k4 < 32; ++k4) {
        float4 xv0 = xsr0[k4], xv1 = xsr1[k4], xv2 = xsr2[k4], xv3 = xsr3[k4];
#define OSTEP(kk, e0, e1, e2, e3)                          \
        {                                                   \
            float wv = wls[(k4 * 4 + kk) * 40 + c];         \
            acc0 = fmaf(e0, wv, acc0);                      \
            acc1 = fmaf(e1, wv, acc1);                      \
            acc2 = fmaf(e2, wv, acc2);                      \
            acc3 = fmaf(e3, wv, acc3);                      \
        }
        OSTEP(0, xv0.x, xv1.x, xv2.x, xv3.x)
        OSTEP(1, xv0.y, xv1.y, xv2.y, xv3.y)
        OSTEP(2, xv0.z, xv1.z, xv2.z, xv3.z)
        OSTEP(3, xv0.w, xv1.w, xv2.w, xv3.w)
#undef OSTEP
    }
    float bb = bos[c];
    int g0 = rowBase + lr;
    if (g0 < n)      out[(size_t)g0 * 40 + c]        = acc0 + bb;
    if (g0 + 8 < n)  out[(size_t)(g0 + 8) * 40 + c]  = acc1 + bb;
    if (g0 + 16 < n) out[(size_t)(g0 + 16) * 40 + c] = acc2 + bb;
    if (g0 + 24 < n) out[(size_t)(g0 + 24) * 40 + c] = acc3 + bb;
}

extern "C" void kernel_launch(void* const* d_in, const int* in_sizes, int n_in,
                              void* d_out, int out_size, void* d_ws, size_t ws_size,
                              hipStream_t stream) {
    const float* x_in  = (const float*)d_in[0];
    const int*   ebuf  = (const int*)d_in[1];
    const float* gamma = (const float*)d_in[2];
    const float* beta  = (const float*)d_in[3];
    const float* Wall  = (const float*)d_in[4];
    const float* ball  = (const float*)d_in[5];
    const float* Wo    = (const float*)d_in[6];
    const float* bo    = (const float*)d_in[7];
    float* out = (float*)d_out;
    const int N = in_sizes[0] / HDIM;
    const int E = in_sizes[1] / 2;
    const int C = 40;

    char* base = (char*)d_ws;
    size_t off = 0;
    auto alloc = [&](size_t bytes) -> void* {
        void* p = base + off;
        off = align256(off + bytes);
        return p;
    };
    float* P0      = (float*)alloc((size_t)N * HDIM * 4);
    float* P1      = (float*)alloc((size_t)N * HDIM * 4);
    float* Q       = (float*)alloc((size_t)N * HDIM * 4);
    int*   es      = (int*)alloc((size_t)E * 4);
    int*   ed      = (int*)alloc((size_t)E * 4);
    int*   csr_src = (int*)alloc((size_t)E * 4);
    float* csr_w   = (float*)alloc((size_t)E * 4);
    int*   deg     = (int*)alloc((size_t)N * 4);
    float* dinv    = (float*)alloc((size_t)N * 4);
    int*   row_ptr = (int*)alloc((size_t)(N + 1) * 4);
    int*   cursor  = (int*)alloc((size_t)N * 4);
    float* part    = (float*)alloc((size_t)250 * HDIM * 2 * 4);
    float* Wp      = (float*)alloc((size_t)HDIM * HDIM * 4);
    float* hb      = (float*)alloc((size_t)HDIM * 4);
    int*   flag    = (int*)alloc(4);

    hipMemsetAsync(deg, 0, (size_t)N * 4, stream);
    detect_kernel<<<1, 256, 0, stream>>>(ebuf, flag);
    int ge = (E + 255) / 256;
    convert_edges<<<ge, 256, 0, stream>>>(ebuf, flag, es, ed, E);
    deg_count<<<ge, 256, 0, stream>>>(ed, deg, E);
    dinv_kernel<<<(N + 255) / 256, 256, 0, stream>>>(deg, dinv, N);
    scan_kernel<<<1, 1024, 0, stream>>>(deg, row_ptr, cursor, N);
    fill_csr<<<ge, 256, 0, stream>>>(es, ed, dinv, cursor, csr_src, csr_w, E);

    for (int l = 0; l < 3; ++l) {
        const float* xc = (l == 0) ? x_in : ((l == 1) ? P0 : P1);
        float* xn = (l == 0) ? P0 : ((l == 1) ? P1 : P0);
        bn_partial<<<250, dim3(128, 2), 0, stream>>>(xc, part, N);
        bn_finalize<<<1, 128, 0, stream>>>(part, gamma + l * HDIM, beta + l * HDIM,
                                           Wall + (size_t)l * HDIM * HDIM, Wp, hb, N, 250);
        gemm128<<<(N + 127) / 128, 256, 0, stream>>>(xc, Wp, hb, Q, N);
        agg_kernel<<<(N + 1) / 2, dim3(128, 2), 0, stream>>>(Q, row_ptr, csr_src, csr_w,
                                                             dinv, ball + l * HDIM, xn, N);
    }
    gemm_out<<<(N + 31) / 32, 320, 0, stream>>>(P0, Wo, bo, out, N, C);
}

// Round 2
// 1038.374 us; speedup vs baseline: 1.7548x; 1.7548x over previous
//
#include <hip/hip_runtime.h>
#include <hip/hip_bf16.h>
#include <hip/hip_fp16.h>
#include <cstdint>

#define HDIM 128
#define BN_EPS 1e-5f
#define SCAN_CHUNK 1024

static inline size_t align256(size_t x) { return (x + 255) & ~size_t(255); }

// ---------- edge dtype detection (int64 vs int32) ----------
__global__ void detect_kernel(const int* __restrict__ ebuf, int* __restrict__ flag) {
    __shared__ int r[256];
    int tid = threadIdx.x;
    int o = 0;
    for (int i = tid; i < 4096; i += 256) o |= ebuf[2 * i + 1];
    r[tid] = o;
    __syncthreads();
    for (int s = 128; s > 0; s >>= 1) {
        if (tid < s) r[tid] |= r[tid + s];
        __syncthreads();
    }
    if (tid == 0) *flag = (r[0] == 0) ? 1 : 0;  // all-zero odd words => int64
}

// convert + degree count fused
__global__ void convert_edges(const int* __restrict__ ebuf, const int* __restrict__ flag,
                              int* __restrict__ es, int* __restrict__ ed,
                              int* __restrict__ deg, int E) {
    int e = blockIdx.x * 256 + threadIdx.x;
    if (e >= E) return;
    int s, d;
    if (*flag) { s = ebuf[2 * e]; d = ebuf[2 * (E + e)]; }
    else       { s = ebuf[e];     d = ebuf[E + e]; }
    es[e] = s; ed[e] = d;
    atomicAdd(&deg[d], 1);
}

__global__ void dinv_kernel(const int* __restrict__ deg, float* __restrict__ dinv, int n) {
    int i = blockIdx.x * 256 + threadIdx.x;
    if (i < n) dinv[i] = rsqrtf((float)(deg[i] + 1));  // +1 self-loop
}

// ---------- multi-block exclusive scan of deg -> row_ptr ----------
__global__ __launch_bounds__(256) void scan_partial(const int* __restrict__ deg,
                                                    int* __restrict__ bsum, int n) {
    int base = blockIdx.x * SCAN_CHUNK;
    int t = threadIdx.x, lane = t & 63, w = t >> 6;
    int s = 0;
#pragma unroll
    for (int i = 0; i < 4; ++i) {
        int idx = base + t + 256 * i;
        if (idx < n) s += deg[idx];
    }
#pragma unroll
    for (int off = 32; off > 0; off >>= 1) s += __shfl_down(s, off);
    __shared__ int wred[4];
    if (lane == 0) wred[w] = s;
    __syncthreads();
    if (t == 0) bsum[blockIdx.x] = wred[0] + wred[1] + wred[2] + wred[3];
}

__global__ __launch_bounds__(128) void scan_offsets(const int* __restrict__ bsum,
                                                    int* __restrict__ bofs, int nb) {
    int t = threadIdx.x;
    int v = (t < nb) ? bsum[t] : 0;
    int x = v;
#pragma unroll
    for (int off = 1; off < 64; off <<= 1) {
        int y = __shfl_up(x, off);
        if ((t & 63) >= off) x += y;
    }
    __shared__ int w0tot;
    if (t == 63) w0tot = x;
    __syncthreads();
    int incl = x + ((t >= 64) ? w0tot : 0);
    if (t < nb) bofs[t] = incl - v;
}

__global__ __launch_bounds__(256) void scan_final(const int* __restrict__ deg,
                                                  const int* __restrict__ bofs,
                                                  int* __restrict__ row_ptr,
                                                  int* __restrict__ cursor, int n, int E) {
    int base = blockIdx.x * SCAN_CHUNK;
    int t = threadIdx.x, lane = t & 63, w = t >> 6;
    int d0[4]; int s = 0;
#pragma unroll
    for (int i = 0; i < 4; ++i) {
        int idx = base + t * 4 + i;
        d0[i] = (idx < n) ? deg[idx] : 0;
        s += d0[i];
    }
    int x = s;
#pragma unroll
    for (int off = 1; off < 64; off <<= 1) {
        int y = __shfl_up(x, off);
        if (lane >= off) x += y;
    }
    __shared__ int wsum[4];
    if (lane == 63) wsum[w] = x;
    __syncthreads();
    int woff = 0;
#pragma unroll
    for (int k = 0; k < 4; ++k) if (k < w) woff += wsum[k];
    int ex = x - s + woff + bofs[blockIdx.x];
#pragma unroll
    for (int i = 0; i < 4; ++i) {
        int idx = base + t * 4 + i;
        if (idx < n) { row_ptr[idx] = ex; cursor[idx] = ex; ex += d0[i]; }
    }
    if (blockIdx.x == 0 && t == 0) row_ptr[n] = E;
}

__global__ void fill_csr(const int* __restrict__ es, const int* __restrict__ ed,
                         const float* __restrict__ dinv, int* __restrict__ cursor,
                         int* __restrict__ csr_src, float* __restrict__ csr_w, int E) {
    int e = blockIdx.x * 256 + threadIdx.x;
    if (e >= E) return;
    int s = es[e], d = ed[e];
    int pos = atomicAdd(&cursor[d], 1);
    csr_src[pos] = s;
    csr_w[pos] = dinv[s] * dinv[d];
}

// ---------- BN statistics (deterministic 2-stage) ----------
__global__ __launch_bounds__(256) void bn_partial(const float* __restrict__ x,
                                                  float* __restrict__ part, int n) {
    int c = threadIdx.x;   // 0..127
    int yy = threadIdx.y;  // 0..1
    int b = blockIdx.x;
    int chunk = (n + gridDim.x - 1) / gridDim.x;
    int start = b * chunk, end = min(start + chunk, n);
    float s = 0.f, s2 = 0.f;
    for (int r = start + yy; r < end; r += 2) {
        float v = x[(size_t)r * HDIM + c];
        s += v; s2 += v * v;
    }
    __shared__ float sh[2][HDIM][2];
    sh[yy][c][0] = s; sh[yy][c][1] = s2;
    __syncthreads();
    if (yy == 0) {
        part[((size_t)b * HDIM + c) * 2 + 0] = s + sh[1][c][0];
        part[((size_t)b * HDIM + c) * 2 + 1] = s2 + sh[1][c][1];
    }
}

__global__ __launch_bounds__(128) void bn_finalize(const float* __restrict__ part,
                                                   const float* __restrict__ gamma,
                                                   const float* __restrict__ beta,
                                                   const float* __restrict__ W,
                                                   float* __restrict__ Wp,
                                                   float* __restrict__ hb, int n, int nb) {
    int c = threadIdx.x;
    float s = 0.f, s2 = 0.f;
    for (int b = 0; b < nb; ++b) {
        s  += part[((size_t)b * HDIM + c) * 2 + 0];
        s2 += part[((size_t)b * HDIM + c) * 2 + 1];
    }
    float mean = s / n;
    float var = s2 / n - mean * mean;
    float sc = gamma[c] * rsqrtf(var + BN_EPS);
    float sf = beta[c] - mean * sc;
    __shared__ float scs[HDIM], shs[HDIM];
    scs[c] = sc; shs[c] = sf;
    __syncthreads();
    float acc = 0.f;
    for (int k = 0; k < HDIM; ++k) {
        float w = W[k * HDIM + c];
        Wp[k * HDIM + c] = scs[k] * w;
        acc += shs[k] * w;
    }
    hb[c] = acc;
}

// ---------- GEMM: h[N][128] = half(x[N][128] @ Wp + hb) ----------
__global__ __launch_bounds__(256) void gemm128(const float* __restrict__ x,
                                               const float* __restrict__ Wp,
                                               const float* __restrict__ hb,
                                               __half* __restrict__ h, int n) {
    __shared__ __align__(16) float wls[HDIM * HDIM];  // 64 KiB
    __shared__ __align__(16) float xs[16 * HDIM];     // 8 KiB
    __shared__ float hbs[HDIM];
    int t = threadIdx.x;
    {
        const float4* w4 = (const float4*)Wp;
        float4* l4 = (float4*)wls;
#pragma unroll
        for (int i = 0; i < 16; ++i) l4[t + 256 * i] = w4[t + 256 * i];
    }
    if (t < HDIM) hbs[t] = hb[t];
    int lane = t & 63, wv = t >> 6;
    const float2* wl2 = (const float2*)wls;
    const float4* xs4 = (const float4*)xs;
    int rowBase = blockIdx.x * 128;
    for (int chunk = 0; chunk < 128; chunk += 16) {
        int cb = rowBase + chunk;
        __syncthreads();
#pragma unroll
        for (int i = 0; i < 2; ++i) {
            int idx = t + 256 * i;       // float4 index into xs (512 total)
            int r = idx >> 5, c4 = idx & 31;
            int gr = cb + r;
            float4 v = make_float4(0.f, 0.f, 0.f, 0.f);
            if (gr < n) v = ((const float4*)x)[(size_t)gr * 32 + c4];
            ((float4*)xs)[idx] = v;
        }
        __syncthreads();
        int r0 = wv * 4;
        float2 a0 = make_float2(0.f, 0.f), a1 = a0, a2 = a0, a3 = a0;
#pragma unroll 4
        for (int k4 = 0; k4 < 32; ++k4) {
            float4 xr0 = xs4[(r0 + 0) * 32 + k4];
            float4 xr1 = xs4[(r0 + 1) * 32 + k4];
            float4 xr2 = xs4[(r0 + 2) * 32 + k4];
            float4 xr3 = xs4[(r0 + 3) * 32 + k4];
#define KSTEP(kk, e0, e1, e2, e3)                                   \
            {                                                        \
                float2 wvv = wl2[(k4 * 4 + kk) * 64 + lane];         \
                a0.x = fmaf(e0, wvv.x, a0.x); a0.y = fmaf(e0, wvv.y, a0.y); \
                a1.x = fmaf(e1, wvv.x, a1.x); a1.y = fmaf(e1, wvv.y, a1.y); \
                a2.x = fmaf(e2, wvv.x, a2.x); a2.y = fmaf(e2, wvv.y, a2.y); \
                a3.x = fmaf(e3, wvv.x, a3.x); a3.y = fmaf(e3, wvv.y, a3.y); \
            }
            KSTEP(0, xr0.x, xr1.x, xr2.x, xr3.x)
            KSTEP(1, xr0.y, xr1.y, xr2.y, xr3.y)
            KSTEP(2, xr0.z, xr1.z, xr2.z, xr3.z)
            KSTEP(3, xr0.w, xr1.w, xr2.w, xr3.w)
#undef KSTEP
        }
        float hb0 = hbs[2 * lane], hb1 = hbs[2 * lane + 1];
        int gr0 = cb + r0;
        __half2* h2 = (__half2*)h;
        if (gr0 + 0 < n) h2[(size_t)(gr0 + 0) * 64 + lane] = __floats2half2_rn(a0.x + hb0, a0.y + hb1);
        if (gr0 + 1 < n) h2[(size_t)(gr0 + 1) * 64 + lane] = __floats2half2_rn(a1.x + hb0, a1.y + hb1);
        if (gr0 + 2 < n) h2[(size_t)(gr0 + 2) * 64 + lane] = __floats2half2_rn(a2.x + hb0, a2.y + hb1);
        if (gr0 + 3 < n) h2[(size_t)(gr0 + 3) * 64 + lane] = __floats2half2_rn(a3.x + hb0, a3.y + hb1);
    }
}

// ---------- aggregation: xn[d] = relu(sum_e w_e h[src_e] + dinv[d]^2 h[d] + b) ----------
__device__ __forceinline__ void fma8(float acc[8], uint4 v, float w) {
    const __half2* p = (const __half2*)&v;
#pragma unroll
    for (int j = 0; j < 4; ++j) {
        float2 f = __half22float2(p[j]);
        acc[2 * j]     = fmaf(w, f.x, acc[2 * j]);
        acc[2 * j + 1] = fmaf(w, f.y, acc[2 * j + 1]);
    }
}

__global__ __launch_bounds__(256) void agg_kernel(const __half* __restrict__ h,
                                                  const int* __restrict__ row_ptr,
                                                  const int* __restrict__ csr_src,
                                                  const float* __restrict__ csr_w,
                                                  const float* __restrict__ dinv,
                                                  const float* __restrict__ bias,
                                                  float* __restrict__ xn, int n) {
    int lane16 = threadIdx.x & 15;        // channel group: 8 halves each
    int d = blockIdx.x * 16 + (threadIdx.x >> 4);
    if (d >= n) return;
    const uint4* h4 = (const uint4*)h;    // 16 uint4 per row (128 halves)
    float dv = dinv[d];
    float acc[8];
    {
        uint4 hv = h4[(size_t)d * 16 + lane16];
        const __half2* p = (const __half2*)&hv;
        float dv2 = dv * dv;
#pragma unroll
        for (int j = 0; j < 4; ++j) {
            float2 f = __half22float2(p[j]);
            acc[2 * j]     = dv2 * f.x;
            acc[2 * j + 1] = dv2 * f.y;
        }
    }
    int e = row_ptr[d], e1 = row_ptr[d + 1];
    for (; e + 4 <= e1; e += 4) {
        int s0 = csr_src[e], s1 = csr_src[e + 1], s2 = csr_src[e + 2], s3 = csr_src[e + 3];
        float w0 = csr_w[e], w1 = csr_w[e + 1], w2 = csr_w[e + 2], w3 = csr_w[e + 3];
        uint4 v0 = h4[(size_t)s0 * 16 + lane16];
        uint4 v1 = h4[(size_t)s1 * 16 + lane16];
        uint4 v2 = h4[(size_t)s2 * 16 + lane16];
        uint4 v3 = h4[(size_t)s3 * 16 + lane16];
        fma8(acc, v0, w0); fma8(acc, v1, w1); fma8(acc, v2, w2); fma8(acc, v3, w3);
    }
    for (; e < e1; ++e) {
        int s = csr_src[e];
        float w = csr_w[e];
        uint4 v = h4[(size_t)s * 16 + lane16];
        fma8(acc, v, w);
    }
    const float4* bb = (const float4*)(bias + lane16 * 8);
    float4 b0 = bb[0], b1 = bb[1];
    float4 o0 = make_float4(fmaxf(acc[0] + b0.x, 0.f), fmaxf(acc[1] + b0.y, 0.f),
                            fmaxf(acc[2] + b0.z, 0.f), fmaxf(acc[3] + b0.w, 0.f));
    float4 o1 = make_float4(fmaxf(acc[4] + b1.x, 0.f), fmaxf(acc[5] + b1.y, 0.f),
                            fmaxf(acc[6] + b1.z, 0.f), fmaxf(acc[7] + b1.w, 0.f));
    float4* xo = (float4*)(xn + (size_t)d * HDIM + lane16 * 8);
    xo[0] = o0; xo[1] = o1;
}

// ---------- final projection: out[N][40] = x @ Wo + bo ----------
__global__ __launch_bounds__(320) void gemm_out(const float* __restrict__ x,
                                                const float* __restrict__ Wo,
                                                const float* __restrict__ bo,
                                                float* __restrict__ out, int n, int C) {
    __shared__ __align__(16) float wls[HDIM * 40];   // 20 KiB
    __shared__ __align__(16) float xs[32 * HDIM];    // 16 KiB
    __shared__ float bos[40];
    int t = threadIdx.x;
    for (int i = t; i < HDIM * 40; i += 320) wls[i] = Wo[i];
    if (t < 40) bos[t] = bo[t];
    int c = t % 40, lr = t / 40;  // lr in 0..7
    int rowBase = blockIdx.x * 32;
    for (int i = t; i < 1024; i += 320) {  // 1024 float4 = 32 rows
        int r = i >> 5, c4 = i & 31;
        int gr = rowBase + r;
        float4 v = make_float4(0.f, 0.f, 0.f, 0.f);
        if (gr < n) v = ((const float4*)x)[(size_t)gr * 32 + c4];
        ((float4*)xs)[i] = v;
    }
    __syncthreads();
    const float4* xsr0 = (const float4*)(xs + (lr + 0) * HDIM);
    const float4* xsr1 = (const float4*)(xs + (lr + 8) * HDIM);
    const float4* xsr2 = (const float4*)(xs + (lr + 16) * HDIM);
    const float4* xsr3 = (const float4*)(xs + (lr + 24) * HDIM);
    float acc0 = 0.f, acc1 = 0.f, acc2 = 0.f, acc3 = 0.f;
#pragma unroll 4
    for (int k4 = 0; k4 < 32; ++k4) {
        float4 xv0 = xsr0[k4], xv1 = xsr1[k4], xv2 = xsr2[k4], xv3 = xsr3[k4];
#define OSTEP(kk, e0, e1, e2, e3)                          \
        {                                                   \
            float wv = wls[(k4 * 4 + kk) * 40 + c];         \
            acc0 = fmaf(e0, wv, acc0);                      \
            acc1 = fmaf(e1, wv, acc1);                      \
            acc2 = fmaf(e2, wv, acc2);                      \
            acc3 = fmaf(e3, wv, acc3);                      \
        }
        OSTEP(0, xv0.x, xv1.x, xv2.x, xv3.x)
        OSTEP(1, xv0.y, xv1.y, xv2.y, xv3.y)
        OSTEP(2, xv0.z, xv1.z, xv2.z, xv3.z)
        OSTEP(3, xv0.w, xv1.w, xv2.w, xv3.w)
#undef OSTEP
    }
    float bb = bos[c];
    int g0 = rowBase + lr;
    if (g0 < n)      out[(size_t)g0 * 40 + c]        = acc0 + bb;
    if (g0 + 8 < n)  out[(size_t)(g0 + 8) * 40 + c]  = acc1 + bb;
    if (g0 + 16 < n) out[(size_t)(g0 + 16) * 40 + c] = acc2 + bb;
    if (g0 + 24 < n) out[(size_t)(g0 + 24) * 40 + c] = acc3 + bb;
}

extern "C" void kernel_launch(void* const* d_in, const int* in_sizes, int n_in,
                              void* d_out, int out_size, void* d_ws, size_t ws_size,
                              hipStream_t stream) {
    const float* x_in  = (const float*)d_in[0];
    const int*   ebuf  = (const int*)d_in[1];
    const float* gamma = (const float*)d_in[2];
    const float* beta  = (const float*)d_in[3];
    const float* Wall  = (const float*)d_in[4];
    const float* ball  = (const float*)d_in[5];
    const float* Wo    = (const float*)d_in[6];
    const float* bo    = (const float*)d_in[7];
    float* out = (float*)d_out;
    const int N = in_sizes[0] / HDIM;
    const int E = in_sizes[1] / 2;
    const int C = 40;

    char* base = (char*)d_ws;
    size_t off = 0;
    auto alloc = [&](size_t bytes) -> void* {
        void* p = base + off;
        off = align256(off + bytes);
        return p;
    };
    float*  P0      = (float*)alloc((size_t)N * HDIM * 4);
    float*  P1      = (float*)alloc((size_t)N * HDIM * 4);
    __half* Q       = (__half*)alloc((size_t)N * HDIM * 2);
    int*    es      = (int*)alloc((size_t)E * 4);
    int*    ed      = (int*)alloc((size_t)E * 4);
    int*    csr_src = (int*)alloc((size_t)E * 4);
    float*  csr_w   = (float*)alloc((size_t)E * 4);
    int*    deg     = (int*)alloc((size_t)N * 4);
    float*  dinv    = (float*)alloc((size_t)N * 4);
    int*    row_ptr = (int*)alloc((size_t)(N + 1) * 4);
    int*    cursor  = (int*)alloc((size_t)N * 4);
    float*  part    = (float*)alloc((size_t)250 * HDIM * 2 * 4);
    float*  Wp      = (float*)alloc((size_t)HDIM * HDIM * 4);
    float*  hb      = (float*)alloc((size_t)HDIM * 4);
    int*    bsum    = (int*)alloc((size_t)256 * 4);
    int*    bofs    = (int*)alloc((size_t)256 * 4);
    int*    flag    = (int*)alloc(4);

    hipMemsetAsync(deg, 0, (size_t)N * 4, stream);
    detect_kernel<<<1, 256, 0, stream>>>(ebuf, flag);
    int ge = (E + 255) / 256;
    convert_edges<<<ge, 256, 0, stream>>>(ebuf, flag, es, ed, deg, E);
    dinv_kernel<<<(N + 255) / 256, 256, 0, stream>>>(deg, dinv, N);
    int nb = (N + SCAN_CHUNK - 1) / SCAN_CHUNK;   // 98 for N=100000 (<=128 required)
    scan_partial<<<nb, 256, 0, stream>>>(deg, bsum, N);
    scan_offsets<<<1, 128, 0, stream>>>(bsum, bofs, nb);
    scan_final<<<nb, 256, 0, stream>>>(deg, bofs, row_ptr, cursor, N, E);
    fill_csr<<<ge, 256, 0, stream>>>(es, ed, dinv, cursor, csr_src, csr_w, E);

    for (int l = 0; l < 3; ++l) {
        const float* xc = (l == 0) ? x_in : ((l == 1) ? P0 : P1);
        float* xn = (l == 0) ? P0 : ((l == 1) ? P1 : P0);
        bn_partial<<<250, dim3(128, 2), 0, stream>>>(xc, part, N);
        bn_finalize<<<1, 128, 0, stream>>>(part, gamma + l * HDIM, beta + l * HDIM,
                                           Wall + (size_t)l * HDIM * HDIM, Wp, hb, N, 250);
        gemm128<<<(N + 127) / 128, 256, 0, stream>>>(xc, Wp, hb, Q, N);
        agg_kernel<<<(N + 15) / 16, 256, 0, stream>>>(Q, row_ptr, csr_src, csr_w,
                                                      dinv, ball + l * HDIM, xn, N);
    }
    gemm_out<<<(N + 31) / 32, 320, 0, stream>>>(P0, Wo, bo, out, N, C);
}

// Round 3
// 959.428 us; speedup vs baseline: 1.8992x; 1.0823x over previous
//
#include <hip/hip_runtime.h>
#include <hip/hip_bf16.h>
#include <hip/hip_fp16.h>
#include <cstdint>

#define HDIM 128
#define BN_EPS 1e-5f
#define SCAN_CHUNK 1024

static inline size_t align256(size_t x) { return (x + 255) & ~size_t(255); }

// ---------- edge dtype detection (int64 vs int32) ----------
__global__ void detect_kernel(const int* __restrict__ ebuf, int* __restrict__ flag) {
    __shared__ int r[256];
    int tid = threadIdx.x;
    int o = 0;
    for (int i = tid; i < 4096; i += 256) o |= ebuf[2 * i + 1];
    r[tid] = o;
    __syncthreads();
    for (int s = 128; s > 0; s >>= 1) {
        if (tid < s) r[tid] |= r[tid + s];
        __syncthreads();
    }
    if (tid == 0) *flag = (r[0] == 0) ? 1 : 0;  // all-zero odd words => int64
}

// ---------- degree count straight from ebuf ----------
__global__ void deg_from_edges(const int* __restrict__ ebuf, const int* __restrict__ flag,
                               int* __restrict__ deg, int E) {
    int e = blockIdx.x * 256 + threadIdx.x;
    if (e >= E) return;
    int d = (*flag) ? ebuf[2 * (E + e)] : ebuf[E + e];
    atomicAdd(&deg[d], 1);
}

__global__ void dinv_kernel(const int* __restrict__ deg, float* __restrict__ dinv, int n) {
    int i = blockIdx.x * 256 + threadIdx.x;
    if (i < n) dinv[i] = rsqrtf((float)(deg[i] + 1));  // +1 self-loop
}

// ---------- multi-block exclusive scan of deg -> row_ptr ----------
__global__ __launch_bounds__(256) void scan_partial(const int* __restrict__ deg,
                                                    int* __restrict__ bsum, int n) {
    int base = blockIdx.x * SCAN_CHUNK;
    int t = threadIdx.x, lane = t & 63, w = t >> 6;
    int s = 0;
#pragma unroll
    for (int i = 0; i < 4; ++i) {
        int idx = base + t + 256 * i;
        if (idx < n) s += deg[idx];
    }
#pragma unroll
    for (int off = 32; off > 0; off >>= 1) s += __shfl_down(s, off);
    __shared__ int wred[4];
    if (lane == 0) wred[w] = s;
    __syncthreads();
    if (t == 0) bsum[blockIdx.x] = wred[0] + wred[1] + wred[2] + wred[3];
}

__global__ __launch_bounds__(128) void scan_offsets(const int* __restrict__ bsum,
                                                    int* __restrict__ bofs, int nb) {
    int t = threadIdx.x;
    int v = (t < nb) ? bsum[t] : 0;
    int x = v;
#pragma unroll
    for (int off = 1; off < 64; off <<= 1) {
        int y = __shfl_up(x, off);
        if ((t & 63) >= off) x += y;
    }
    __shared__ int w0tot;
    if (t == 63) w0tot = x;
    __syncthreads();
    int incl = x + ((t >= 64) ? w0tot : 0);
    if (t < nb) bofs[t] = incl - v;
}

__global__ __launch_bounds__(256) void scan_final(const int* __restrict__ deg,
                                                  const int* __restrict__ bofs,
                                                  int* __restrict__ row_ptr,
                                                  int* __restrict__ cursor, int n, int E) {
    int base = blockIdx.x * SCAN_CHUNK;
    int t = threadIdx.x, lane = t & 63, w = t >> 6;
    int d0[4]; int s = 0;
#pragma unroll
    for (int i = 0; i < 4; ++i) {
        int idx = base + t * 4 + i;
        d0[i] = (idx < n) ? deg[idx] : 0;
        s += d0[i];
    }
    int x = s;
#pragma unroll
    for (int off = 1; off < 64; off <<= 1) {
        int y = __shfl_up(x, off);
        if (lane >= off) x += y;
    }
    __shared__ int wsum[4];
    if (lane == 63) wsum[w] = x;
    __syncthreads();
    int woff = 0;
#pragma unroll
    for (int k = 0; k < 4; ++k) if (k < w) woff += wsum[k];
    int ex = x - s + woff + bofs[blockIdx.x];
#pragma unroll
    for (int i = 0; i < 4; ++i) {
        int idx = base + t * 4 + i;
        if (idx < n) { row_ptr[idx] = ex; cursor[idx] = ex; ex += d0[i]; }
    }
    if (blockIdx.x == 0 && t == 0) row_ptr[n] = E;
}

// ---------- CSR fill: single scattered 4B store per edge ----------
__global__ void fill_csr(const int* __restrict__ ebuf, const int* __restrict__ flag,
                         int* __restrict__ cursor, int* __restrict__ csr_src, int E) {
    int e = blockIdx.x * 256 + threadIdx.x;
    if (e >= E) return;
    int s, d;
    if (*flag) { s = ebuf[2 * e]; d = ebuf[2 * (E + e)]; }
    else       { s = ebuf[e];     d = ebuf[E + e]; }
    int pos = atomicAdd(&cursor[d], 1);
    csr_src[pos] = s;
}

// ---------- BN statistics (deterministic 2-stage) ----------
__global__ __launch_bounds__(256) void bn_partial(const float* __restrict__ x,
                                                  float* __restrict__ part, int n) {
    int c = threadIdx.x;   // 0..127
    int yy = threadIdx.y;  // 0..1
    int b = blockIdx.x;
    int chunk = (n + gridDim.x - 1) / gridDim.x;
    int start = b * chunk, end = min(start + chunk, n);
    float s = 0.f, s2 = 0.f;
    for (int r = start + yy; r < end; r += 2) {
        float v = x[(size_t)r * HDIM + c];
        s += v; s2 += v * v;
    }
    __shared__ float sh[2][HDIM][2];
    sh[yy][c][0] = s; sh[yy][c][1] = s2;
    __syncthreads();
    if (yy == 0) {
        part[((size_t)b * HDIM + c) * 2 + 0] = s + sh[1][c][0];
        part[((size_t)b * HDIM + c) * 2 + 1] = s2 + sh[1][c][1];
    }
}

__global__ __launch_bounds__(128) void bn_finalize(const float* __restrict__ part,
                                                   const float* __restrict__ gamma,
                                                   const float* __restrict__ beta,
                                                   const float* __restrict__ W,
                                                   float* __restrict__ Wp,
                                                   float* __restrict__ hb, int n, int nb) {
    int c = threadIdx.x;
    float s = 0.f, s2 = 0.f;
#pragma unroll 5
    for (int b = 0; b < nb; ++b) {
        s  += part[((size_t)b * HDIM + c) * 2 + 0];
        s2 += part[((size_t)b * HDIM + c) * 2 + 1];
    }
    float mean = s / n;
    float var = s2 / n - mean * mean;
    float sc = gamma[c] * rsqrtf(var + BN_EPS);
    float sf = beta[c] - mean * sc;
    __shared__ float scs[HDIM], shs[HDIM];
    scs[c] = sc; shs[c] = sf;
    __syncthreads();
    float acc = 0.f;
    for (int k = 0; k < HDIM; ++k) {
        float w = W[k * HDIM + c];
        Wp[k * HDIM + c] = scs[k] * w;
        acc += shs[k] * w;
    }
    hb[c] = acc;
}

// ---------- GEMM: hs[N][128] = half(dinv[r] * (x[N][128] @ Wp + hb)) ----------
__global__ __launch_bounds__(256) void gemm128(const float* __restrict__ x,
                                               const float* __restrict__ Wp,
                                               const float* __restrict__ hb,
                                               const float* __restrict__ dinv,
                                               __half* __restrict__ h, int n) {
    __shared__ __align__(16) float wls[HDIM * HDIM];  // 64 KiB
    __shared__ __align__(16) float xs[16 * HDIM];     // 8 KiB
    __shared__ float hbs[HDIM];
    int t = threadIdx.x;
    {
        const float4* w4 = (const float4*)Wp;
        float4* l4 = (float4*)wls;
#pragma unroll
        for (int i = 0; i < 16; ++i) l4[t + 256 * i] = w4[t + 256 * i];
    }
    if (t < HDIM) hbs[t] = hb[t];
    int lane = t & 63, wv = t >> 6;
    const float2* wl2 = (const float2*)wls;
    const float4* xs4 = (const float4*)xs;
    int rowBase = blockIdx.x * 128;
    for (int chunk = 0; chunk < 128; chunk += 16) {
        int cb = rowBase + chunk;
        __syncthreads();
#pragma unroll
        for (int i = 0; i < 2; ++i) {
            int idx = t + 256 * i;       // float4 index into xs (512 total)
            int r = idx >> 5, c4 = idx & 31;
            int gr = cb + r;
            float4 v = make_float4(0.f, 0.f, 0.f, 0.f);
            if (gr < n) v = ((const float4*)x)[(size_t)gr * 32 + c4];
            ((float4*)xs)[idx] = v;
        }
        __syncthreads();
        int r0 = wv * 4;
        float2 a0 = make_float2(0.f, 0.f), a1 = a0, a2 = a0, a3 = a0;
#pragma unroll 4
        for (int k4 = 0; k4 < 32; ++k4) {
            float4 xr0 = xs4[(r0 + 0) * 32 + k4];
            float4 xr1 = xs4[(r0 + 1) * 32 + k4];
            float4 xr2 = xs4[(r0 + 2) * 32 + k4];
            float4 xr3 = xs4[(r0 + 3) * 32 + k4];
#define KSTEP(kk, e0, e1, e2, e3)                                   \
            {                                                        \
                float2 wvv = wl2[(k4 * 4 + kk) * 64 + lane];         \
                a0.x = fmaf(e0, wvv.x, a0.x); a0.y = fmaf(e0, wvv.y, a0.y); \
                a1.x = fmaf(e1, wvv.x, a1.x); a1.y = fmaf(e1, wvv.y, a1.y); \
                a2.x = fmaf(e2, wvv.x, a2.x); a2.y = fmaf(e2, wvv.y, a2.y); \
                a3.x = fmaf(e3, wvv.x, a3.x); a3.y = fmaf(e3, wvv.y, a3.y); \
            }
            KSTEP(0, xr0.x, xr1.x, xr2.x, xr3.x)
            KSTEP(1, xr0.y, xr1.y, xr2.y, xr3.y)
            KSTEP(2, xr0.z, xr1.z, xr2.z, xr3.z)
            KSTEP(3, xr0.w, xr1.w, xr2.w, xr3.w)
#undef KSTEP
        }
        float hb0 = hbs[2 * lane], hb1 = hbs[2 * lane + 1];
        int gr0 = cb + r0;
        __half2* h2 = (__half2*)h;
#pragma unroll
        for (int i = 0; i < 4; ++i) {
            int gr = gr0 + i;
            if (gr < n) {
                float dvr = dinv[gr];
                float2 a = (i == 0) ? a0 : (i == 1) ? a1 : (i == 2) ? a2 : a3;
                h2[(size_t)gr * 64 + lane] =
                    __floats2half2_rn(dvr * (a.x + hb0), dvr * (a.y + hb1));
            }
        }
    }
}

// ---------- aggregation: xn[d] = relu(dinv[d]*(hs[d] + sum_e hs[src_e]) + b) ----------
__device__ __forceinline__ void add8(float acc[8], uint4 v) {
    const __half2* p = (const __half2*)&v;
#pragma unroll
    for (int j = 0; j < 4; ++j) {
        float2 f = __half22float2(p[j]);
        acc[2 * j]     += f.x;
        acc[2 * j + 1] += f.y;
    }
}

__global__ __launch_bounds__(256) void agg_kernel(const __half* __restrict__ h,
                                                  const int* __restrict__ row_ptr,
                                                  const int* __restrict__ csr_src,
                                                  const float* __restrict__ dinv,
                                                  const float* __restrict__ bias,
                                                  float* __restrict__ xn, int n) {
    int lane16 = threadIdx.x & 15;        // channel group: 8 halves each
    int d = blockIdx.x * 16 + (threadIdx.x >> 4);
    if (d >= n) return;
    const uint4* h4 = (const uint4*)h;    // 16 uint4 per row (128 halves)
    float acc[8];
    {
        uint4 hv = h4[(size_t)d * 16 + lane16];   // self-loop term (weight 1)
        const __half2* p = (const __half2*)&hv;
#pragma unroll
        for (int j = 0; j < 4; ++j) {
            float2 f = __half22float2(p[j]);
            acc[2 * j]     = f.x;
            acc[2 * j + 1] = f.y;
        }
    }
    int e = row_ptr[d], e1 = row_ptr[d + 1];
    for (; e + 8 <= e1; e += 8) {
        int s0 = csr_src[e],     s1 = csr_src[e + 1], s2 = csr_src[e + 2], s3 = csr_src[e + 3];
        int s4 = csr_src[e + 4], s5 = csr_src[e + 5], s6 = csr_src[e + 6], s7 = csr_src[e + 7];
        uint4 v0 = h4[(size_t)s0 * 16 + lane16];
        uint4 v1 = h4[(size_t)s1 * 16 + lane16];
        uint4 v2 = h4[(size_t)s2 * 16 + lane16];
        uint4 v3 = h4[(size_t)s3 * 16 + lane16];
        uint4 v4 = h4[(size_t)s4 * 16 + lane16];
        uint4 v5 = h4[(size_t)s5 * 16 + lane16];
        uint4 v6 = h4[(size_t)s6 * 16 + lane16];
        uint4 v7 = h4[(size_t)s7 * 16 + lane16];
        add8(acc, v0); add8(acc, v1); add8(acc, v2); add8(acc, v3);
        add8(acc, v4); add8(acc, v5); add8(acc, v6); add8(acc, v7);
    }
    for (; e < e1; ++e) {
        int s = csr_src[e];
        uint4 v = h4[(size_t)s * 16 + lane16];
        add8(acc, v);
    }
    float dv = dinv[d];
    const float4* bb = (const float4*)(bias + lane16 * 8);
    float4 b0 = bb[0], b1 = bb[1];
    float4 o0 = make_float4(fmaxf(fmaf(dv, acc[0], b0.x), 0.f), fmaxf(fmaf(dv, acc[1], b0.y), 0.f),
                            fmaxf(fmaf(dv, acc[2], b0.z), 0.f), fmaxf(fmaf(dv, acc[3], b0.w), 0.f));
    float4 o1 = make_float4(fmaxf(fmaf(dv, acc[4], b1.x), 0.f), fmaxf(fmaf(dv, acc[5], b1.y), 0.f),
                            fmaxf(fmaf(dv, acc[6], b1.z), 0.f), fmaxf(fmaf(dv, acc[7], b1.w), 0.f));
    float4* xo = (float4*)(xn + (size_t)d * HDIM + lane16 * 8);
    xo[0] = o0; xo[1] = o1;
}

// ---------- final projection: out[N][40] = x @ Wo + bo ----------
__global__ __launch_bounds__(320) void gemm_out(const float* __restrict__ x,
                                                const float* __restrict__ Wo,
                                                const float* __restrict__ bo,
                                                float* __restrict__ out, int n, int C) {
    __shared__ __align__(16) float wls[HDIM * 40];   // 20 KiB
    __shared__ __align__(16) float xs[32 * HDIM];    // 16 KiB
    __shared__ float bos[40];
    int t = threadIdx.x;
    for (int i = t; i < HDIM * 40; i += 320) wls[i] = Wo[i];
    if (t < 40) bos[t] = bo[t];
    int c = t % 40, lr = t / 40;  // lr in 0..7
    int rowBase = blockIdx.x * 32;
    for (int i = t; i < 1024; i += 320) {  // 1024 float4 = 32 rows
        int r = i >> 5, c4 = i & 31;
        int gr = rowBase + r;
        float4 v = make_float4(0.f, 0.f, 0.f, 0.f);
        if (gr < n) v = ((const float4*)x)[(size_t)gr * 32 + c4];
        ((float4*)xs)[i] = v;
    }
    __syncthreads();
    const float4* xsr0 = (const float4*)(xs + (lr + 0) * HDIM);
    const float4* xsr1 = (const float4*)(xs + (lr + 8) * HDIM);
    const float4* xsr2 = (const float4*)(xs + (lr + 16) * HDIM);
    const float4* xsr3 = (const float4*)(xs + (lr + 24) * HDIM);
    float acc0 = 0.f, acc1 = 0.f, acc2 = 0.f, acc3 = 0.f;
#pragma unroll 4
    for (int k4 = 0; k4 < 32; ++k4) {
        float4 xv0 = xsr0[k4], xv1 = xsr1[k4], xv2 = xsr2[k4], xv3 = xsr3[k4];
#define OSTEP(kk, e0, e1, e2, e3)                          \
        {                                                   \
            float wv = wls[(k4 * 4 + kk) * 40 + c];         \
            acc0 = fmaf(e0, wv, acc0);                      \
            acc1 = fmaf(e1, wv, acc1);                      \
            acc2 = fmaf(e2, wv, acc2);                      \
            acc3 = fmaf(e3, wv, acc3);                      \
        }
        OSTEP(0, xv0.x, xv1.x, xv2.x, xv3.x)
        OSTEP(1, xv0.y, xv1.y, xv2.y, xv3.y)
        OSTEP(2, xv0.z, xv1.z, xv2.z, xv3.z)
        OSTEP(3, xv0.w, xv1.w, xv2.w, xv3.w)
#undef OSTEP
    }
    float bb = bos[c];
    int g0 = rowBase + lr;
    if (g0 < n)      out[(size_t)g0 * 40 + c]        = acc0 + bb;
    if (g0 + 8 < n)  out[(size_t)(g0 + 8) * 40 + c]  = acc1 + bb;
    if (g0 + 16 < n) out[(size_t)(g0 + 16) * 40 + c] = acc2 + bb;
    if (g0 + 24 < n) out[(size_t)(g0 + 24) * 40 + c] = acc3 + bb;
}

extern "C" void kernel_launch(void* const* d_in, const int* in_sizes, int n_in,
                              void* d_out, int out_size, void* d_ws, size_t ws_size,
                              hipStream_t stream) {
    const float* x_in  = (const float*)d_in[0];
    const int*   ebuf  = (const int*)d_in[1];
    const float* gamma = (const float*)d_in[2];
    const float* beta  = (const float*)d_in[3];
    const float* Wall  = (const float*)d_in[4];
    const float* ball  = (const float*)d_in[5];
    const float* Wo    = (const float*)d_in[6];
    const float* bo    = (const float*)d_in[7];
    float* out = (float*)d_out;
    const int N = in_sizes[0] / HDIM;
    const int E = in_sizes[1] / 2;
    const int C = 40;

    char* base = (char*)d_ws;
    size_t off = 0;
    auto alloc = [&](size_t bytes) -> void* {
        void* p = base + off;
        off = align256(off + bytes);
        return p;
    };
    float*  P0      = (float*)alloc((size_t)N * HDIM * 4);
    float*  P1      = (float*)alloc((size_t)N * HDIM * 4);
    __half* Q       = (__half*)alloc((size_t)N * HDIM * 2);
    int*    csr_src = (int*)alloc((size_t)E * 4);
    int*    deg     = (int*)alloc((size_t)N * 4);
    float*  dinv    = (float*)alloc((size_t)N * 4);
    int*    row_ptr = (int*)alloc((size_t)(N + 1) * 4);
    int*    cursor  = (int*)alloc((size_t)N * 4);
    float*  part    = (float*)alloc((size_t)250 * HDIM * 2 * 4);
    float*  Wp      = (float*)alloc((size_t)HDIM * HDIM * 4);
    float*  hb      = (float*)alloc((size_t)HDIM * 4);
    int*    bsum    = (int*)alloc((size_t)256 * 4);
    int*    bofs    = (int*)alloc((size_t)256 * 4);
    int*    flag    = (int*)alloc(4);

    hipMemsetAsync(deg, 0, (size_t)N * 4, stream);
    detect_kernel<<<1, 256, 0, stream>>>(ebuf, flag);
    int ge = (E + 255) / 256;
    deg_from_edges<<<ge, 256, 0, stream>>>(ebuf, flag, deg, E);
    dinv_kernel<<<(N + 255) / 256, 256, 0, stream>>>(deg, dinv, N);
    int nb = (N + SCAN_CHUNK - 1) / SCAN_CHUNK;   // 98 for N=100000 (<=128 required)
    scan_partial<<<nb, 256, 0, stream>>>(deg, bsum, N);
    scan_offsets<<<1, 128, 0, stream>>>(bsum, bofs, nb);
    scan_final<<<nb, 256, 0, stream>>>(deg, bofs, row_ptr, cursor, N, E);
    fill_csr<<<ge, 256, 0, stream>>>(ebuf, flag, cursor, csr_src, E);

    for (int l = 0; l < 3; ++l) {
        const float* xc = (l == 0) ? x_in : ((l == 1) ? P0 : P1);
        float* xn = (l == 0) ? P0 : ((l == 1) ? P1 : P0);
        bn_partial<<<250, dim3(128, 2), 0, stream>>>(xc, part, N);
        bn_finalize<<<1, 128, 0, stream>>>(part, gamma + l * HDIM, beta + l * HDIM,
                                           Wall + (size_t)l * HDIM * HDIM, Wp, hb, N, 250);
        gemm128<<<(N + 127) / 128, 256, 0, stream>>>(xc, Wp, hb, dinv, Q, N);
        agg_kernel<<<(N + 15) / 16, 256, 0, stream>>>(Q, row_ptr, csr_src,
                                                      dinv, ball + l * HDIM, xn, N);
    }
    gemm_out<<<(N + 31) / 32, 320, 0, stream>>>(P0, Wo, bo, out, N, C);
}

// Round 4
// 904.335 us; speedup vs baseline: 2.0149x; 1.0609x over previous
//
#include <hip/hip_runtime.h>
#include <hip/hip_bf16.h>
#include <hip/hip_fp16.h>
#include <cstdint>

#define HDIM 128
#define BN_EPS 1e-5f
#define SCAN_CHUNK 1024

typedef _Float16 hf2 __attribute__((ext_vector_type(2)));

static inline size_t align256(size_t x) { return (x + 255) & ~size_t(255); }

// ---------- edge dtype detection (int64 vs int32) ----------
__global__ void detect_kernel(const int* __restrict__ ebuf, int* __restrict__ flag) {
    __shared__ int r[256];
    int tid = threadIdx.x;
    int o = 0;
    for (int i = tid; i < 4096; i += 256) o |= ebuf[2 * i + 1];
    r[tid] = o;
    __syncthreads();
    for (int s = 128; s > 0; s >>= 1) {
        if (tid < s) r[tid] |= r[tid + s];
        __syncthreads();
    }
    if (tid == 0) *flag = (r[0] == 0) ? 1 : 0;  // all-zero odd words => int64
}

// ---------- degree count straight from ebuf, 8 edges/thread ----------
__global__ void deg_from_edges(const int* __restrict__ ebuf, const int* __restrict__ flag,
                               int* __restrict__ deg, int E) {
    int base = blockIdx.x * 2048 + threadIdx.x;
    bool f = (*flag != 0);
#pragma unroll
    for (int i = 0; i < 8; ++i) {
        int e = base + i * 256;
        if (e < E) {
            int d = f ? ebuf[2 * (E + e)] : ebuf[E + e];
            atomicAdd(&deg[d], 1);
        }
    }
}

__global__ void dinv_kernel(const int* __restrict__ deg, float* __restrict__ dinv, int n) {
    int i = blockIdx.x * 256 + threadIdx.x;
    if (i < n) dinv[i] = rsqrtf((float)(deg[i] + 1));  // +1 self-loop
}

// ---------- multi-block exclusive scan of deg -> row_ptr ----------
__global__ __launch_bounds__(256) void scan_partial(const int* __restrict__ deg,
                                                    int* __restrict__ bsum, int n) {
    int base = blockIdx.x * SCAN_CHUNK;
    int t = threadIdx.x, lane = t & 63, w = t >> 6;
    int s = 0;
#pragma unroll
    for (int i = 0; i < 4; ++i) {
        int idx = base + t + 256 * i;
        if (idx < n) s += deg[idx];
    }
#pragma unroll
    for (int off = 32; off > 0; off >>= 1) s += __shfl_down(s, off);
    __shared__ int wred[4];
    if (lane == 0) wred[w] = s;
    __syncthreads();
    if (t == 0) bsum[blockIdx.x] = wred[0] + wred[1] + wred[2] + wred[3];
}

__global__ __launch_bounds__(128) void scan_offsets(const int* __restrict__ bsum,
                                                    int* __restrict__ bofs, int nb) {
    int t = threadIdx.x;
    int v = (t < nb) ? bsum[t] : 0;
    int x = v;
#pragma unroll
    for (int off = 1; off < 64; off <<= 1) {
        int y = __shfl_up(x, off);
        if ((t & 63) >= off) x += y;
    }
    __shared__ int w0tot;
    if (t == 63) w0tot = x;
    __syncthreads();
    int incl = x + ((t >= 64) ? w0tot : 0);
    if (t < nb) bofs[t] = incl - v;
}

__global__ __launch_bounds__(256) void scan_final(const int* __restrict__ deg,
                                                  const int* __restrict__ bofs,
                                                  int* __restrict__ row_ptr,
                                                  int* __restrict__ cursor, int n, int E) {
    int base = blockIdx.x * SCAN_CHUNK;
    int t = threadIdx.x, lane = t & 63, w = t >> 6;
    int d0[4]; int s = 0;
#pragma unroll
    for (int i = 0; i < 4; ++i) {
        int idx = base + t * 4 + i;
        d0[i] = (idx < n) ? deg[idx] : 0;
        s += d0[i];
    }
    int x = s;
#pragma unroll
    for (int off = 1; off < 64; off <<= 1) {
        int y = __shfl_up(x, off);
        if (lane >= off) x += y;
    }
    __shared__ int wsum[4];
    if (lane == 63) wsum[w] = x;
    __syncthreads();
    int woff = 0;
#pragma unroll
    for (int k = 0; k < 4; ++k) if (k < w) woff += wsum[k];
    int ex = x - s + woff + bofs[blockIdx.x];
#pragma unroll
    for (int i = 0; i < 4; ++i) {
        int idx = base + t * 4 + i;
        if (idx < n) { row_ptr[idx] = ex; cursor[idx] = ex; ex += d0[i]; }
    }
    if (blockIdx.x == 0 && t == 0) row_ptr[n] = E;
}

// ---------- CSR fill: 8 edges/thread for ILP on the atomic+scatter chain ----------
__global__ void fill_csr(const int* __restrict__ ebuf, const int* __restrict__ flag,
                         int* __restrict__ cursor, int* __restrict__ csr_src, int E) {
    int base = blockIdx.x * 2048 + threadIdx.x;
    bool f = (*flag != 0);
    int sv[8], dv[8];
#pragma unroll
    for (int i = 0; i < 8; ++i) {
        int e = base + i * 256;
        if (e < E) {
            if (f) { sv[i] = ebuf[2 * e]; dv[i] = ebuf[2 * (E + e)]; }
            else   { sv[i] = ebuf[e];     dv[i] = ebuf[E + e]; }
        }
    }
#pragma unroll
    for (int i = 0; i < 8; ++i) {
        int e = base + i * 256;
        if (e < E) {
            int pos = atomicAdd(&cursor[dv[i]], 1);
            csr_src[pos] = sv[i];
        }
    }
}

// ---------- BN statistics, fp32 input (layer 0) ----------
__global__ __launch_bounds__(256) void bn_partial(const float* __restrict__ x,
                                                  float* __restrict__ part, int n) {
    int c = threadIdx.x;   // 0..127
    int yy = threadIdx.y;  // 0..1
    int b = blockIdx.x;
    int chunk = (n + gridDim.x - 1) / gridDim.x;
    int start = b * chunk, end = min(start + chunk, n);
    float s = 0.f, s2 = 0.f;
    for (int r = start + yy; r < end; r += 2) {
        float v = x[(size_t)r * HDIM + c];
        s += v; s2 += v * v;
    }
    __shared__ float sh[2][HDIM][2];
    sh[yy][c][0] = s; sh[yy][c][1] = s2;
    __syncthreads();
    if (yy == 0) {
        part[((size_t)b * HDIM + c) * 2 + 0] = s + sh[1][c][0];
        part[((size_t)b * HDIM + c) * 2 + 1] = s2 + sh[1][c][1];
    }
}

// ---------- BN statistics, fp16 input (layers 1,2) ----------
__global__ __launch_bounds__(256) void bn_partial_h(const hf2* __restrict__ x,
                                                    float* __restrict__ part, int n) {
    int c2 = threadIdx.x & 63;     // half2 index (2 channels)
    int yy = threadIdx.x >> 6;     // 0..3
    int b = blockIdx.x;
    int chunk = (n + gridDim.x - 1) / gridDim.x;
    int start = b * chunk, end = min(start + chunk, n);
    float s0 = 0.f, q0 = 0.f, s1 = 0.f, q1 = 0.f;
    for (int r = start + yy; r < end; r += 4) {
        hf2 v = x[(size_t)r * 64 + c2];
        float f0 = (float)v.x, f1 = (float)v.y;
        s0 += f0; q0 += f0 * f0;
        s1 += f1; q1 += f1 * f1;
    }
    __shared__ float sh[4][64][4];
    sh[yy][c2][0] = s0; sh[yy][c2][1] = q0; sh[yy][c2][2] = s1; sh[yy][c2][3] = q1;
    __syncthreads();
    if (yy == 0) {
#pragma unroll
        for (int k = 1; k < 4; ++k) {
            s0 += sh[k][c2][0]; q0 += sh[k][c2][1];
            s1 += sh[k][c2][2]; q1 += sh[k][c2][3];
        }
        // layout [b][c][2] floats, c = 2*c2 -> one float4
        ((float4*)part)[(size_t)b * 64 + c2] = make_float4(s0, q0, s1, q1);
    }
}

// ---------- finalize stats; build fp16 col-major k-paired Wp + fp32 hb ----------
__global__ __launch_bounds__(128) void bn_finalize(const float* __restrict__ part,
                                                   const float* __restrict__ gamma,
                                                   const float* __restrict__ beta,
                                                   const float* __restrict__ W,
                                                   hf2* __restrict__ Wph2,
                                                   float* __restrict__ hb, int n, int nb) {
    int c = threadIdx.x;
    float s = 0.f, s2 = 0.f;
    for (int b = 0; b < nb; ++b) {
        s  += part[((size_t)b * HDIM + c) * 2 + 0];
        s2 += part[((size_t)b * HDIM + c) * 2 + 1];
    }
    float mean = s / n;
    float var = s2 / n - mean * mean;
    float sc = gamma[c] * rsqrtf(var + BN_EPS);
    float sf = beta[c] - mean * sc;
    __shared__ float scs[HDIM], shs[HDIM];
    scs[c] = sc; shs[c] = sf;
    __syncthreads();
    float acc = 0.f;
#pragma unroll 4
    for (int k2 = 0; k2 < 64; ++k2) {
        float wa = W[(2 * k2) * HDIM + c];
        float wb = W[(2 * k2 + 1) * HDIM + c];
        hf2 wv;
        wv.x = (_Float16)(scs[2 * k2] * wa);
        wv.y = (_Float16)(scs[2 * k2 + 1] * wb);
        Wph2[c * 64 + k2] = wv;                    // col-major, k-paired
        acc += shs[2 * k2] * wa + shs[2 * k2 + 1] * wb;
    }
    hb[c] = acc;
}

// ---------- GEMM: Q[N][128] = fp16(dinv[r] * (BN(x) @ W + hb)), fdot2 inner ----------
template<bool F16SRC>
__global__ __launch_bounds__(256) void gemm_dot(const void* __restrict__ xsrc,
                                                const hf2* __restrict__ Wph2,
                                                const float* __restrict__ hb,
                                                const float* __restrict__ dinv,
                                                hf2* __restrict__ Q, int n) {
    __shared__ hf2 xs[128][66];    // rows, pad->2-way-free banks
    __shared__ hf2 wls[128][66];   // cols, pad
    __shared__ float hbs[HDIM];
    int t = threadIdx.x;
    int rowBase = blockIdx.x * 128;
    // stage W (32KB, col-major k-paired)
    {
        const uint2* wg = (const uint2*)Wph2;   // 4096 uint2
#pragma unroll
        for (int i = 0; i < 16; ++i) {
            int idx = t + 256 * i;
            int col = idx >> 5, ko = (idx & 31) * 2;
            *(uint2*)&wls[col][ko] = wg[idx];
        }
    }
    if (t < HDIM) hbs[t] = hb[t];
    // stage x tile (128 rows)
    if (F16SRC) {
        const uint4* xg = (const uint4*)xsrc;
#pragma unroll
        for (int i = 0; i < 8; ++i) {
            int idx = t + 256 * i;          // 2048 uint4
            int row = idx >> 4, o4 = idx & 15;
            int gr = rowBase + row;
            uint4 v = make_uint4(0, 0, 0, 0);
            if (gr < n) v = xg[(size_t)gr * 16 + o4];
            *(uint2*)&xs[row][o4 * 4]     = make_uint2(v.x, v.y);
            *(uint2*)&xs[row][o4 * 4 + 2] = make_uint2(v.z, v.w);
        }
    } else {
        const float4* xg = (const float4*)xsrc;
#pragma unroll
        for (int i = 0; i < 16; ++i) {
            int idx = t + 256 * i;          // 4096 float4
            int row = idx >> 5, o = idx & 31;
            int gr = rowBase + row;
            float4 v = make_float4(0.f, 0.f, 0.f, 0.f);
            if (gr < n) v = xg[(size_t)gr * 32 + o];
            hf2 a; a.x = (_Float16)v.x; a.y = (_Float16)v.y;
            hf2 b; b.x = (_Float16)v.z; b.y = (_Float16)v.w;
            xs[row][o * 2] = a; xs[row][o * 2 + 1] = b;
        }
    }
    __syncthreads();
    int tc = t & 15, tr = t >> 4;
    float acc[8][8];
#pragma unroll
    for (int r = 0; r < 8; ++r)
#pragma unroll
        for (int q = 0; q < 8; ++q) acc[r][q] = 0.f;
#pragma unroll 2
    for (int k2 = 0; k2 < 64; k2 += 2) {
        uint2 xr[8], wc[8];
#pragma unroll
        for (int r = 0; r < 8; ++r) xr[r] = *(const uint2*)&xs[8 * tr + r][k2];
#pragma unroll
        for (int i = 0; i < 4; ++i)
#pragma unroll
            for (int j = 0; j < 2; ++j)
                wc[i * 2 + j] = *(const uint2*)&wls[32 * i + 2 * tc + j][k2];
#pragma unroll
        for (int r = 0; r < 8; ++r)
#pragma unroll
            for (int q = 0; q < 8; ++q) {
                hf2 xa = ((const hf2*)&xr[r])[0];
                hf2 xb = ((const hf2*)&xr[r])[1];
                hf2 wa = ((const hf2*)&wc[q])[0];
                hf2 wb = ((const hf2*)&wc[q])[1];
                acc[r][q] = __builtin_amdgcn_fdot2(xa, wa, acc[r][q], false);
                acc[r][q] = __builtin_amdgcn_fdot2(xb, wb, acc[r][q], false);
            }
    }
#pragma unroll
    for (int r = 0; r < 8; ++r) {
        int row = rowBase + 8 * tr + r;
        if (row < n) {
            float dvr = dinv[row];
#pragma unroll
            for (int i = 0; i < 4; ++i) {
                int c0 = 32 * i + 2 * tc;
                hf2 v;
                v.x = (_Float16)(dvr * (acc[r][2 * i + 0] + hbs[c0]));
                v.y = (_Float16)(dvr * (acc[r][2 * i + 1] + hbs[c0 + 1]));
                Q[(size_t)row * 64 + 16 * i + tc] = v;
            }
        }
    }
}

// ---------- aggregation: xn[d] = fp16(relu(dinv[d]*(hs[d] + sum_e hs[src_e]) + b)) ----------
__device__ __forceinline__ void add8(float acc[8], uint4 v) {
    const __half2* p = (const __half2*)&v;
#pragma unroll
    for (int j = 0; j < 4; ++j) {
        float2 f = __half22float2(p[j]);
        acc[2 * j]     += f.x;
        acc[2 * j + 1] += f.y;
    }
}

__global__ __launch_bounds__(256) void agg_kernel(const __half* __restrict__ h,
                                                  const int* __restrict__ row_ptr,
                                                  const int* __restrict__ csr_src,
                                                  const float* __restrict__ dinv,
                                                  const float* __restrict__ bias,
                                                  __half* __restrict__ xn, int n) {
    int lane16 = threadIdx.x & 15;        // channel group: 8 halves each
    int d = blockIdx.x * 16 + (threadIdx.x >> 4);
    if (d >= n) return;
    const uint4* h4 = (const uint4*)h;    // 16 uint4 per row (128 halves)
    float acc[8];
    {
        uint4 hv = h4[(size_t)d * 16 + lane16];   // self-loop term (weight 1)
        const __half2* p = (const __half2*)&hv;
#pragma unroll
        for (int j = 0; j < 4; ++j) {
            float2 f = __half22float2(p[j]);
            acc[2 * j]     = f.x;
            acc[2 * j + 1] = f.y;
        }
    }
    int e = row_ptr[d], e1 = row_ptr[d + 1];
    for (; e + 8 <= e1; e += 8) {
        int s0 = csr_src[e],     s1 = csr_src[e + 1], s2 = csr_src[e + 2], s3 = csr_src[e + 3];
        int s4 = csr_src[e + 4], s5 = csr_src[e + 5], s6 = csr_src[e + 6], s7 = csr_src[e + 7];
        uint4 v0 = h4[(size_t)s0 * 16 + lane16];
        uint4 v1 = h4[(size_t)s1 * 16 + lane16];
        uint4 v2 = h4[(size_t)s2 * 16 + lane16];
        uint4 v3 = h4[(size_t)s3 * 16 + lane16];
        uint4 v4 = h4[(size_t)s4 * 16 + lane16];
        uint4 v5 = h4[(size_t)s5 * 16 + lane16];
        uint4 v6 = h4[(size_t)s6 * 16 + lane16];
        uint4 v7 = h4[(size_t)s7 * 16 + lane16];
        add8(acc, v0); add8(acc, v1); add8(acc, v2); add8(acc, v3);
        add8(acc, v4); add8(acc, v5); add8(acc, v6); add8(acc, v7);
    }
    for (; e < e1; ++e) {
        int s = csr_src[e];
        uint4 v = h4[(size_t)s * 16 + lane16];
        add8(acc, v);
    }
    float dv = dinv[d];
    const float4* bb = (const float4*)(bias + lane16 * 8);
    float4 b0 = bb[0], b1 = bb[1];
    union { uint4 u; __half2 h2[4]; } o;
    o.h2[0] = __floats2half2_rn(fmaxf(fmaf(dv, acc[0], b0.x), 0.f),
                                fmaxf(fmaf(dv, acc[1], b0.y), 0.f));
    o.h2[1] = __floats2half2_rn(fmaxf(fmaf(dv, acc[2], b0.z), 0.f),
                                fmaxf(fmaf(dv, acc[3], b0.w), 0.f));
    o.h2[2] = __floats2half2_rn(fmaxf(fmaf(dv, acc[4], b1.x), 0.f),
                                fmaxf(fmaf(dv, acc[5], b1.y), 0.f));
    o.h2[3] = __floats2half2_rn(fmaxf(fmaf(dv, acc[6], b1.z), 0.f),
                                fmaxf(fmaf(dv, acc[7], b1.w), 0.f));
    ((uint4*)xn)[(size_t)d * 16 + lane16] = o.u;
}

// ---------- final projection: out[N][40] = x(fp16) @ Wo + bo ----------
__global__ __launch_bounds__(320) void gemm_out(const __half* __restrict__ x,
                                                const float* __restrict__ Wo,
                                                const float* __restrict__ bo,
                                                float* __restrict__ out, int n, int C) {
    __shared__ __align__(16) float wls[HDIM * 40];   // 20 KiB
    __shared__ __align__(16) float xs[32 * HDIM];    // 16 KiB
    __shared__ float bos[40];
    int t = threadIdx.x;
    for (int i = t; i < HDIM * 40; i += 320) wls[i] = Wo[i];
    if (t < 40) bos[t] = bo[t];
    int c = t % 40, lr = t / 40;  // lr in 0..7
    int rowBase = blockIdx.x * 32;
    const uint4* xg = (const uint4*)x;
    for (int i = t; i < 512; i += 320) {  // 512 uint4 = 32 rows of fp16
        int row = i >> 4, o4 = i & 15;
        int gr = rowBase + row;
        uint4 v = make_uint4(0, 0, 0, 0);
        if (gr < n) v = xg[(size_t)gr * 16 + o4];
        union { uint4 u; __half2 h2[4]; } cv; cv.u = v;
        float2 f0 = __half22float2(cv.h2[0]);
        float2 f1 = __half22float2(cv.h2[1]);
        float2 f2 = __half22float2(cv.h2[2]);
        float2 f3 = __half22float2(cv.h2[3]);
        ((float4*)xs)[i * 2]     = make_float4(f0.x, f0.y, f1.x, f1.y);
        ((float4*)xs)[i * 2 + 1] = make_float4(f2.x, f2.y, f3.x, f3.y);
    }
    __syncthreads();
    const float4* xsr0 = (const float4*)(xs + (lr + 0) * HDIM);
    const float4* xsr1 = (const float4*)(xs + (lr + 8) * HDIM);
    const float4* xsr2 = (const float4*)(xs + (lr + 16) * HDIM);
    const float4* xsr3 = (const float4*)(xs + (lr + 24) * HDIM);
    float acc0 = 0.f, acc1 = 0.f, acc2 = 0.f, acc3 = 0.f;
#pragma unroll 4
    for (int k4 = 0; k4 < 32; ++k4) {
        float4 xv0 = xsr0[k4], xv1 = xsr1[k4], xv2 = xsr2[k4], xv3 = xsr3[k4];
#define OSTEP(kk, e0, e1, e2, e3)                          \
        {                                                   \
            float wv = wls[(k4 * 4 + kk) * 40 + c];         \
            acc0 = fmaf(e0, wv, acc0);                      \
            acc1 = fmaf(e1, wv, acc1);                      \
            acc2 = fmaf(e2, wv, acc2);                      \
            acc3 = fmaf(e3, wv, acc3);                      \
        }
        OSTEP(0, xv0.x, xv1.x, xv2.x, xv3.x)
        OSTEP(1, xv0.y, xv1.y, xv2.y, xv3.y)
        OSTEP(2, xv0.z, xv1.z, xv2.z, xv3.z)
        OSTEP(3, xv0.w, xv1.w, xv2.w, xv3.w)
#undef OSTEP
    }
    float bb = bos[c];
    int g0 = rowBase + lr;
    if (g0 < n)      out[(size_t)g0 * 40 + c]        = acc0 + bb;
    if (g0 + 8 < n)  out[(size_t)(g0 + 8) * 40 + c]  = acc1 + bb;
    if (g0 + 16 < n) out[(size_t)(g0 + 16) * 40 + c] = acc2 + bb;
    if (g0 + 24 < n) out[(size_t)(g0 + 24) * 40 + c] = acc3 + bb;
}

extern "C" void kernel_launch(void* const* d_in, const int* in_sizes, int n_in,
                              void* d_out, int out_size, void* d_ws, size_t ws_size,
                              hipStream_t stream) {
    const float* x_in  = (const float*)d_in[0];
    const int*   ebuf  = (const int*)d_in[1];
    const float* gamma = (const float*)d_in[2];
    const float* beta  = (const float*)d_in[3];
    const float* Wall  = (const float*)d_in[4];
    const float* ball  = (const float*)d_in[5];
    const float* Wo    = (const float*)d_in[6];
    const float* bo    = (const float*)d_in[7];
    float* out = (float*)d_out;
    const int N = in_sizes[0] / HDIM;
    const int E = in_sizes[1] / 2;
    const int C = 40;

    char* base = (char*)d_ws;
    size_t off = 0;
    auto alloc = [&](size_t bytes) -> void* {
        void* p = base + off;
        off = align256(off + bytes);
        return p;
    };
    __half* Xh0     = (__half*)alloc((size_t)N * HDIM * 2);
    __half* Xh1     = (__half*)alloc((size_t)N * HDIM * 2);
    __half* Q       = (__half*)alloc((size_t)N * HDIM * 2);
    int*    csr_src = (int*)alloc((size_t)E * 4);
    int*    deg     = (int*)alloc((size_t)N * 4);
    float*  dinv    = (float*)alloc((size_t)N * 4);
    int*    row_ptr = (int*)alloc((size_t)(N + 1) * 4);
    int*    cursor  = (int*)alloc((size_t)N * 4);
    float*  part    = (float*)alloc((size_t)250 * HDIM * 2 * 4);
    hf2*    Wph2    = (hf2*)alloc((size_t)64 * HDIM * 4);
    float*  hb      = (float*)alloc((size_t)HDIM * 4);
    int*    bsum    = (int*)alloc((size_t)256 * 4);
    int*    bofs    = (int*)alloc((size_t)256 * 4);
    int*    flag    = (int*)alloc(4);

    hipMemsetAsync(deg, 0, (size_t)N * 4, stream);
    detect_kernel<<<1, 256, 0, stream>>>(ebuf, flag);
    int ge8 = (E + 2047) / 2048;
    deg_from_edges<<<ge8, 256, 0, stream>>>(ebuf, flag, deg, E);
    dinv_kernel<<<(N + 255) / 256, 256, 0, stream>>>(deg, dinv, N);
    int nb = (N + SCAN_CHUNK - 1) / SCAN_CHUNK;   // 98 for N=100000 (<=128 required)
    scan_partial<<<nb, 256, 0, stream>>>(deg, bsum, N);
    scan_offsets<<<1, 128, 0, stream>>>(bsum, bofs, nb);
    scan_final<<<nb, 256, 0, stream>>>(deg, bofs, row_ptr, cursor, N, E);
    fill_csr<<<ge8, 256, 0, stream>>>(ebuf, flag, cursor, csr_src, E);

    int gg = (N + 127) / 128;
    for (int l = 0; l < 3; ++l) {
        const void* xc = (l == 0) ? (const void*)x_in
                                  : (l == 1) ? (const void*)Xh0 : (const void*)Xh1;
        __half* xn = (l == 0) ? Xh0 : (l == 1) ? Xh1 : Xh0;
        if (l == 0) bn_partial<<<250, dim3(128, 2), 0, stream>>>((const float*)xc, part, N);
        else        bn_partial_h<<<250, 256, 0, stream>>>((const hf2*)xc, part, N);
        bn_finalize<<<1, 128, 0, stream>>>(part, gamma + l * HDIM, beta + l * HDIM,
                                           Wall + (size_t)l * HDIM * HDIM, Wph2, hb, N, 250);
        if (l == 0) gemm_dot<false><<<gg, 256, 0, stream>>>(xc, Wph2, hb, dinv, (hf2*)Q, N);
        else        gemm_dot<true ><<<gg, 256, 0, stream>>>(xc, Wph2, hb, dinv, (hf2*)Q, N);
        agg_kernel<<<(N + 15) / 16, 256, 0, stream>>>(Q, row_ptr, csr_src,
                                                      dinv, ball + l * HDIM, xn, N);
    }
    gemm_out<<<(N + 31) / 32, 320, 0, stream>>>(Xh0, Wo, bo, out, N, C);
}

// Round 5
// 710.221 us; speedup vs baseline: 2.5656x; 1.2733x over previous
//
#include <hip/hip_runtime.h>
#include <hip/hip_bf16.h>
#include <hip/hip_fp16.h>
#include <cstdint>

#define HDIM 128
#define BN_EPS 1e-5f
#define SCAN_CHUNK 1024

typedef _Float16 hf2 __attribute__((ext_vector_type(2)));

static inline size_t align256(size_t x) { return (x + 255) & ~size_t(255); }

// ---------- edge dtype detection (int64 vs int32) ----------
__global__ void detect_kernel(const int* __restrict__ ebuf, int* __restrict__ flag) {
    __shared__ int r[256];
    int tid = threadIdx.x;
    int o = 0;
    for (int i = tid; i < 4096; i += 256) o |= ebuf[2 * i + 1];
    r[tid] = o;
    __syncthreads();
    for (int s = 128; s > 0; s >>= 1) {
        if (tid < s) r[tid] |= r[tid + s];
        __syncthreads();
    }
    if (tid == 0) *flag = (r[0] == 0) ? 1 : 0;  // all-zero odd words => int64
}

// ---------- degree count + per-edge rank (atomic return value) ----------
__global__ void deg_rank(const int* __restrict__ ebuf, const int* __restrict__ flag,
                         int* __restrict__ deg, int* __restrict__ rank, int E) {
    int e = blockIdx.x * 256 + threadIdx.x;
    if (e >= E) return;
    int d = (*flag) ? ebuf[2 * (E + e)] : ebuf[E + e];
    rank[e] = atomicAdd(&deg[d], 1);
}

// ---------- multi-block exclusive scan of deg -> row_ptr (+dinv fused) ----------
__global__ __launch_bounds__(256) void scan_partial(const int* __restrict__ deg,
                                                    int* __restrict__ bsum, int n) {
    int base = blockIdx.x * SCAN_CHUNK;
    int t = threadIdx.x, lane = t & 63, w = t >> 6;
    int s = 0;
#pragma unroll
    for (int i = 0; i < 4; ++i) {
        int idx = base + t + 256 * i;
        if (idx < n) s += deg[idx];
    }
#pragma unroll
    for (int off = 32; off > 0; off >>= 1) s += __shfl_down(s, off);
    __shared__ int wred[4];
    if (lane == 0) wred[w] = s;
    __syncthreads();
    if (t == 0) bsum[blockIdx.x] = wred[0] + wred[1] + wred[2] + wred[3];
}

__global__ __launch_bounds__(128) void scan_offsets(const int* __restrict__ bsum,
                                                    int* __restrict__ bofs, int nb) {
    int t = threadIdx.x;
    int v = (t < nb) ? bsum[t] : 0;
    int x = v;
#pragma unroll
    for (int off = 1; off < 64; off <<= 1) {
        int y = __shfl_up(x, off);
        if ((t & 63) >= off) x += y;
    }
    __shared__ int w0tot;
    if (t == 63) w0tot = x;
    __syncthreads();
    int incl = x + ((t >= 64) ? w0tot : 0);
    if (t < nb) bofs[t] = incl - v;
}

__global__ __launch_bounds__(256) void scan_final(const int* __restrict__ deg,
                                                  const int* __restrict__ bofs,
                                                  int* __restrict__ row_ptr,
                                                  float* __restrict__ dinv, int n, int E) {
    int base = blockIdx.x * SCAN_CHUNK;
    int t = threadIdx.x, lane = t & 63, w = t >> 6;
    int d0[4]; int s = 0;
#pragma unroll
    for (int i = 0; i < 4; ++i) {
        int idx = base + t * 4 + i;
        d0[i] = (idx < n) ? deg[idx] : 0;
        s += d0[i];
    }
    int x = s;
#pragma unroll
    for (int off = 1; off < 64; off <<= 1) {
        int y = __shfl_up(x, off);
        if (lane >= off) x += y;
    }
    __shared__ int wsum[4];
    if (lane == 63) wsum[w] = x;
    __syncthreads();
    int woff = 0;
#pragma unroll
    for (int k = 0; k < 4; ++k) if (k < w) woff += wsum[k];
    int ex = x - s + woff + bofs[blockIdx.x];
#pragma unroll
    for (int i = 0; i < 4; ++i) {
        int idx = base + t * 4 + i;
        if (idx < n) {
            row_ptr[idx] = ex;
            dinv[idx] = rsqrtf((float)(d0[i] + 1));   // +1 self-loop
            ex += d0[i];
        }
    }
    if (blockIdx.x == 0 && t == 0) row_ptr[n] = E;
}

// ---------- CSR fill: no atomic, pure load->store ----------
__global__ void fill_csr(const int* __restrict__ ebuf, const int* __restrict__ flag,
                         const int* __restrict__ row_ptr, const int* __restrict__ rank,
                         int* __restrict__ csr_src, int E) {
    int e = blockIdx.x * 256 + threadIdx.x;
    if (e >= E) return;
    int s, d;
    if (*flag) { s = ebuf[2 * e]; d = ebuf[2 * (E + e)]; }
    else       { s = ebuf[e];     d = ebuf[E + e]; }
    csr_src[row_ptr[d] + rank[e]] = s;
}

// ---------- BN statistics, fp32 input (layer 0 only) ----------
// part layout: [block][256] floats, (2c, 2c+1) = (sum, sumsq) of channel c
__global__ __launch_bounds__(256) void bn_partial(const float* __restrict__ x,
                                                  float* __restrict__ part, int n) {
    int c = threadIdx.x;   // 0..127
    int yy = threadIdx.y;  // 0..1
    int b = blockIdx.x;
    int chunk = (n + gridDim.x - 1) / gridDim.x;
    int start = b * chunk, end = min(start + chunk, n);
    float s = 0.f, s2 = 0.f;
    for (int r = start + yy; r < end; r += 2) {
        float v = x[(size_t)r * HDIM + c];
        s += v; s2 += v * v;
    }
    __shared__ float sh[2][HDIM][2];
    sh[yy][c][0] = s; sh[yy][c][1] = s2;
    __syncthreads();
    if (yy == 0) {
        ((float2*)part)[(size_t)b * 128 + c] = make_float2(s + sh[1][c][0], s2 + sh[1][c][1]);
    }
}

// ---------- reduce agg-produced partials (rows x 256) -> 64 x 256 ----------
__global__ __launch_bounds__(256) void bn_reduce1(const float* __restrict__ part,
                                                  float* __restrict__ part2, int rows) {
    int t = threadIdx.x;
    int per = (rows + gridDim.x - 1) / gridDim.x;
    int b0 = blockIdx.x * per, b1 = min(b0 + per, rows);
    float acc = 0.f;
    for (int r = b0; r < b1; ++r) acc += part[(size_t)r * 256 + t];
    part2[(size_t)blockIdx.x * 256 + t] = acc;
}

// ---------- finalize stats; build fp16 col-major k-paired Wp + fp32 hb ----------
__global__ __launch_bounds__(128) void bn_finalize(const float* __restrict__ part,
                                                   const float* __restrict__ gamma,
                                                   const float* __restrict__ beta,
                                                   const float* __restrict__ W,
                                                   hf2* __restrict__ Wph2,
                                                   float* __restrict__ hb, int n, int nb) {
    int c = threadIdx.x;
    float s = 0.f, s2 = 0.f;
    for (int b = 0; b < nb; ++b) {
        float2 v = ((const float2*)part)[(size_t)b * 128 + c];
        s += v.x; s2 += v.y;
    }
    float mean = s / n;
    float var = s2 / n - mean * mean;
    float sc = gamma[c] * rsqrtf(var + BN_EPS);
    float sf = beta[c] - mean * sc;
    __shared__ float scs[HDIM], shs[HDIM];
    scs[c] = sc; shs[c] = sf;
    __syncthreads();
    float acc = 0.f;
#pragma unroll 4
    for (int k2 = 0; k2 < 64; ++k2) {
        float wa = W[(2 * k2) * HDIM + c];
        float wb = W[(2 * k2 + 1) * HDIM + c];
        hf2 wv;
        wv.x = (_Float16)(scs[2 * k2] * wa);
        wv.y = (_Float16)(scs[2 * k2 + 1] * wb);
        Wph2[c * 64 + k2] = wv;                    // col-major, k-paired
        acc += shs[2 * k2] * wa + shs[2 * k2 + 1] * wb;
    }
    hb[c] = acc;
}

// ---------- GEMM: Q[N][128] = fp16(dinv[r] * (BN(x) @ W + hb)), fdot2 inner ----------
template<bool F16SRC>
__global__ __launch_bounds__(256) void gemm_dot(const void* __restrict__ xsrc,
                                                const hf2* __restrict__ Wph2,
                                                const float* __restrict__ hb,
                                                const float* __restrict__ dinv,
                                                hf2* __restrict__ Q, int n) {
    __shared__ hf2 xs[128][66];    // rows, pad->2-way-free banks
    __shared__ hf2 wls[128][66];   // cols, pad
    __shared__ float hbs[HDIM];
    int t = threadIdx.x;
    int rowBase = blockIdx.x * 128;
    {
        const uint2* wg = (const uint2*)Wph2;   // 4096 uint2
#pragma unroll
        for (int i = 0; i < 16; ++i) {
            int idx = t + 256 * i;
            int col = idx >> 5, ko = (idx & 31) * 2;
            *(uint2*)&wls[col][ko] = wg[idx];
        }
    }
    if (t < HDIM) hbs[t] = hb[t];
    if (F16SRC) {
        const uint4* xg = (const uint4*)xsrc;
#pragma unroll
        for (int i = 0; i < 8; ++i) {
            int idx = t + 256 * i;          // 2048 uint4
            int row = idx >> 4, o4 = idx & 15;
            int gr = rowBase + row;
            uint4 v = make_uint4(0, 0, 0, 0);
            if (gr < n) v = xg[(size_t)gr * 16 + o4];
            *(uint2*)&xs[row][o4 * 4]     = make_uint2(v.x, v.y);
            *(uint2*)&xs[row][o4 * 4 + 2] = make_uint2(v.z, v.w);
        }
    } else {
        const float4* xg = (const float4*)xsrc;
#pragma unroll
        for (int i = 0; i < 16; ++i) {
            int idx = t + 256 * i;          // 4096 float4
            int row = idx >> 5, o = idx & 31;
            int gr = rowBase + row;
            float4 v = make_float4(0.f, 0.f, 0.f, 0.f);
            if (gr < n) v = xg[(size_t)gr * 32 + o];
            hf2 a; a.x = (_Float16)v.x; a.y = (_Float16)v.y;
            hf2 b; b.x = (_Float16)v.z; b.y = (_Float16)v.w;
            xs[row][o * 2] = a; xs[row][o * 2 + 1] = b;
        }
    }
    __syncthreads();
    int tc = t & 15, tr = t >> 4;
    float acc[8][8];
#pragma unroll
    for (int r = 0; r < 8; ++r)
#pragma unroll
        for (int q = 0; q < 8; ++q) acc[r][q] = 0.f;
#pragma unroll 2
    for (int k2 = 0; k2 < 64; k2 += 2) {
        uint2 xr[8], wc[8];
#pragma unroll
        for (int r = 0; r < 8; ++r) xr[r] = *(const uint2*)&xs[8 * tr + r][k2];
#pragma unroll
        for (int i = 0; i < 4; ++i)
#pragma unroll
            for (int j = 0; j < 2; ++j)
                wc[i * 2 + j] = *(const uint2*)&wls[32 * i + 2 * tc + j][k2];
#pragma unroll
        for (int r = 0; r < 8; ++r)
#pragma unroll
            for (int q = 0; q < 8; ++q) {
                hf2 xa = ((const hf2*)&xr[r])[0];
                hf2 xb = ((const hf2*)&xr[r])[1];
                hf2 wa = ((const hf2*)&wc[q])[0];
                hf2 wb = ((const hf2*)&wc[q])[1];
                acc[r][q] = __builtin_amdgcn_fdot2(xa, wa, acc[r][q], false);
                acc[r][q] = __builtin_amdgcn_fdot2(xb, wb, acc[r][q], false);
            }
    }
#pragma unroll
    for (int r = 0; r < 8; ++r) {
        int row = rowBase + 8 * tr + r;
        if (row < n) {
            float dvr = dinv[row];
#pragma unroll
            for (int i = 0; i < 4; ++i) {
                int c0 = 32 * i + 2 * tc;
                hf2 v;
                v.x = (_Float16)(dvr * (acc[r][2 * i + 0] + hbs[c0]));
                v.y = (_Float16)(dvr * (acc[r][2 * i + 1] + hbs[c0 + 1]));
                Q[(size_t)row * 64 + 16 * i + tc] = v;
            }
        }
    }
}

// ---------- aggregation + fused next-layer BN partial stats ----------
__device__ __forceinline__ void add8(float acc[8], uint4 v) {
    const __half2* p = (const __half2*)&v;
#pragma unroll
    for (int j = 0; j < 4; ++j) {
        float2 f = __half22float2(p[j]);
        acc[2 * j]     += f.x;
        acc[2 * j + 1] += f.y;
    }
}

__global__ __launch_bounds__(256) void agg_kernel(const __half* __restrict__ h,
                                                  const int* __restrict__ row_ptr,
                                                  const int* __restrict__ csr_src,
                                                  const float* __restrict__ dinv,
                                                  const float* __restrict__ bias,
                                                  __half* __restrict__ xn,
                                                  float* __restrict__ part, int n) {
    int t = threadIdx.x;
    int lane16 = t & 15;              // channel group: 8 halves each
    int g = t >> 4;                   // node slot in block
    int d = blockIdx.x * 16 + g;
    bool active = (d < n);
    const uint4* h4 = (const uint4*)h;
    float v[8];
#pragma unroll
    for (int j = 0; j < 8; ++j) v[j] = 0.f;
    if (active) {
        float acc[8];
        {
            uint4 hv = h4[(size_t)d * 16 + lane16];   // self-loop term (weight 1)
            const __half2* p = (const __half2*)&hv;
#pragma unroll
            for (int j = 0; j < 4; ++j) {
                float2 f = __half22float2(p[j]);
                acc[2 * j]     = f.x;
                acc[2 * j + 1] = f.y;
            }
        }
        int e = row_ptr[d], e1 = row_ptr[d + 1];
        for (; e + 8 <= e1; e += 8) {
            int s0 = csr_src[e],     s1 = csr_src[e + 1], s2 = csr_src[e + 2], s3 = csr_src[e + 3];
            int s4 = csr_src[e + 4], s5 = csr_src[e + 5], s6 = csr_src[e + 6], s7 = csr_src[e + 7];
            uint4 v0 = h4[(size_t)s0 * 16 + lane16];
            uint4 v1 = h4[(size_t)s1 * 16 + lane16];
            uint4 v2 = h4[(size_t)s2 * 16 + lane16];
            uint4 v3 = h4[(size_t)s3 * 16 + lane16];
            uint4 v4 = h4[(size_t)s4 * 16 + lane16];
            uint4 v5 = h4[(size_t)s5 * 16 + lane16];
            uint4 v6 = h4[(size_t)s6 * 16 + lane16];
            uint4 v7 = h4[(size_t)s7 * 16 + lane16];
            add8(acc, v0); add8(acc, v1); add8(acc, v2); add8(acc, v3);
            add8(acc, v4); add8(acc, v5); add8(acc, v6); add8(acc, v7);
        }
        for (; e < e1; ++e) {
            int s = csr_src[e];
            uint4 vv = h4[(size_t)s * 16 + lane16];
            add8(acc, vv);
        }
        float dv = dinv[d];
        const float4* bb = (const float4*)(bias + lane16 * 8);
        float4 b0 = bb[0], b1 = bb[1];
        v[0] = fmaxf(fmaf(dv, acc[0], b0.x), 0.f);
        v[1] = fmaxf(fmaf(dv, acc[1], b0.y), 0.f);
        v[2] = fmaxf(fmaf(dv, acc[2], b0.z), 0.f);
        v[3] = fmaxf(fmaf(dv, acc[3], b0.w), 0.f);
        v[4] = fmaxf(fmaf(dv, acc[4], b1.x), 0.f);
        v[5] = fmaxf(fmaf(dv, acc[5], b1.y), 0.f);
        v[6] = fmaxf(fmaf(dv, acc[6], b1.z), 0.f);
        v[7] = fmaxf(fmaf(dv, acc[7], b1.w), 0.f);
        union { uint4 u; __half2 h2[4]; } o;
        o.h2[0] = __floats2half2_rn(v[0], v[1]);
        o.h2[1] = __floats2half2_rn(v[2], v[3]);
        o.h2[2] = __floats2half2_rn(v[4], v[5]);
        o.h2[3] = __floats2half2_rn(v[6], v[7]);
        ((uint4*)xn)[(size_t)d * 16 + lane16] = o.u;
    }
    if (part) {   // fused BN partial stats for the next layer
        __shared__ float redS[16][HDIM];
        __shared__ float redQ[16][HDIM];
#pragma unroll
        for (int j = 0; j < 8; ++j) {
            redS[g][lane16 * 8 + j] = v[j];
            redQ[g][lane16 * 8 + j] = v[j] * v[j];
        }
        __syncthreads();
        if (t < HDIM) {
            float s = 0.f, q = 0.f;
#pragma unroll
            for (int k = 0; k < 16; ++k) { s += redS[k][t]; q += redQ[k][t]; }
            ((float2*)part)[(size_t)blockIdx.x * 128 + t] = make_float2(s, q);
        }
    }
}

// ---------- final projection: out[N][40] = x(fp16) @ Wo + bo ----------
__global__ __launch_bounds__(320) void gemm_out(const __half* __restrict__ x,
                                                const float* __restrict__ Wo,
                                                const float* __restrict__ bo,
                                                float* __restrict__ out, int n, int C) {
    __shared__ __align__(16) float wls[HDIM * 40];   // 20 KiB
    __shared__ __align__(16) float xs[32 * HDIM];    // 16 KiB
    __shared__ float bos[40];
    int t = threadIdx.x;
    for (int i = t; i < HDIM * 40; i += 320) wls[i] = Wo[i];
    if (t < 40) bos[t] = bo[t];
    int c = t % 40, lr = t / 40;  // lr in 0..7
    int rowBase = blockIdx.x * 32;
    const uint4* xg = (const uint4*)x;
    for (int i = t; i < 512; i += 320) {  // 512 uint4 = 32 rows of fp16
        int row = i >> 4, o4 = i & 15;
        int gr = rowBase + row;
        uint4 v = make_uint4(0, 0, 0, 0);
        if (gr < n) v = xg[(size_t)gr * 16 + o4];
        union { uint4 u; __half2 h2[4]; } cv; cv.u = v;
        float2 f0 = __half22float2(cv.h2[0]);
        float2 f1 = __half22float2(cv.h2[1]);
        float2 f2 = __half22float2(cv.h2[2]);
        float2 f3 = __half22float2(cv.h2[3]);
        ((float4*)xs)[i * 2]     = make_float4(f0.x, f0.y, f1.x, f1.y);
        ((float4*)xs)[i * 2 + 1] = make_float4(f2.x, f2.y, f3.x, f3.y);
    }
    __syncthreads();
    const float4* xsr0 = (const float4*)(xs + (lr + 0) * HDIM);
    const float4* xsr1 = (const float4*)(xs + (lr + 8) * HDIM);
    const float4* xsr2 = (const float4*)(xs + (lr + 16) * HDIM);
    const float4* xsr3 = (const float4*)(xs + (lr + 24) * HDIM);
    float acc0 = 0.f, acc1 = 0.f, acc2 = 0.f, acc3 = 0.f;
#pragma unroll 4
    for (int k4 = 0; k4 < 32; ++k4) {
        float4 xv0 = xsr0[k4], xv1 = xsr1[k4], xv2 = xsr2[k4], xv3 = xsr3[k4];
#define OSTEP(kk, e0, e1, e2, e3)                          \
        {                                                   \
            float wv = wls[(k4 * 4 + kk) * 40 + c];         \
            acc0 = fmaf(e0, wv, acc0);                      \
            acc1 = fmaf(e1, wv, acc1);                      \
            acc2 = fmaf(e2, wv, acc2);                      \
            acc3 = fmaf(e3, wv, acc3);                      \
        }
        OSTEP(0, xv0.x, xv1.x, xv2.x, xv3.x)
        OSTEP(1, xv0.y, xv1.y, xv2.y, xv3.y)
        OSTEP(2, xv0.z, xv1.z, xv2.z, xv3.z)
        OSTEP(3, xv0.w, xv1.w, xv2.w, xv3.w)
#undef OSTEP
    }
    float bb = bos[c];
    int g0 = rowBase + lr;
    if (g0 < n)      out[(size_t)g0 * 40 + c]        = acc0 + bb;
    if (g0 + 8 < n)  out[(size_t)(g0 + 8) * 40 + c]  = acc1 + bb;
    if (g0 + 16 < n) out[(size_t)(g0 + 16) * 40 + c] = acc2 + bb;
    if (g0 + 24 < n) out[(size_t)(g0 + 24) * 40 + c] = acc3 + bb;
}

extern "C" void kernel_launch(void* const* d_in, const int* in_sizes, int n_in,
                              void* d_out, int out_size, void* d_ws, size_t ws_size,
                              hipStream_t stream) {
    const float* x_in  = (const float*)d_in[0];
    const int*   ebuf  = (const int*)d_in[1];
    const float* gamma = (const float*)d_in[2];
    const float* beta  = (const float*)d_in[3];
    const float* Wall  = (const float*)d_in[4];
    const float* ball  = (const float*)d_in[5];
    const float* Wo    = (const float*)d_in[6];
    const float* bo    = (const float*)d_in[7];
    float* out = (float*)d_out;
    const int N = in_sizes[0] / HDIM;
    const int E = in_sizes[1] / 2;
    const int C = 40;

    char* base = (char*)d_ws;
    size_t off = 0;
    auto alloc = [&](size_t bytes) -> void* {
        void* p = base + off;
        off = align256(off + bytes);
        return p;
    };
    const int g_agg = (N + 15) / 16;   // agg blocks (= BN partial rows)
    __half* Xh0     = (__half*)alloc((size_t)N * HDIM * 2);
    __half* Xh1     = (__half*)alloc((size_t)N * HDIM * 2);
    __half* Q       = (__half*)alloc((size_t)N * HDIM * 2);
    int*    csr_src = (int*)alloc((size_t)E * 4);
    int*    rank    = (int*)alloc((size_t)E * 4);
    int*    deg     = (int*)alloc((size_t)N * 4);
    float*  dinv    = (float*)alloc((size_t)N * 4);
    int*    row_ptr = (int*)alloc((size_t)(N + 1) * 4);
    float*  part    = (float*)alloc((size_t)g_agg * 256 * 4);
    float*  part2   = (float*)alloc((size_t)64 * 256 * 4);
    hf2*    Wph2    = (hf2*)alloc((size_t)64 * HDIM * 4);
    float*  hb      = (float*)alloc((size_t)HDIM * 4);
    int*    bsum    = (int*)alloc((size_t)256 * 4);
    int*    bofs    = (int*)alloc((size_t)256 * 4);
    int*    flag    = (int*)alloc(4);

    hipMemsetAsync(deg, 0, (size_t)N * 4, stream);
    detect_kernel<<<1, 256, 0, stream>>>(ebuf, flag);
    int ge = (E + 255) / 256;
    deg_rank<<<ge, 256, 0, stream>>>(ebuf, flag, deg, rank, E);
    int nb = (N + SCAN_CHUNK - 1) / SCAN_CHUNK;   // 98 for N=100000 (<=128 required)
    scan_partial<<<nb, 256, 0, stream>>>(deg, bsum, N);
    scan_offsets<<<1, 128, 0, stream>>>(bsum, bofs, nb);
    scan_final<<<nb, 256, 0, stream>>>(deg, bofs, row_ptr, dinv, N, E);
    fill_csr<<<ge, 256, 0, stream>>>(ebuf, flag, row_ptr, rank, csr_src, E);

    int gg = (N + 127) / 128;
    for (int l = 0; l < 3; ++l) {
        const void* xc = (l == 0) ? (const void*)x_in
                                  : (l == 1) ? (const void*)Xh0 : (const void*)Xh1;
        __half* xn = (l == 0) ? Xh0 : (l == 1) ? Xh1 : Xh0;
        int fin_nb;
        const float* fin_part;
        if (l == 0) {
            bn_partial<<<250, dim3(128, 2), 0, stream>>>((const float*)xc, part, N);
            fin_part = part; fin_nb = 250;
        } else {
            bn_reduce1<<<64, 256, 0, stream>>>(part, part2, g_agg);
            fin_part = part2; fin_nb = 64;
        }
        bn_finalize<<<1, 128, 0, stream>>>(fin_part, gamma + l * HDIM, beta + l * HDIM,
                                           Wall + (size_t)l * HDIM * HDIM, Wph2, hb, N, fin_nb);
        if (l == 0) gemm_dot<false><<<gg, 256, 0, stream>>>(xc, Wph2, hb, dinv, (hf2*)Q, N);
        else        gemm_dot<true ><<<gg, 256, 0, stream>>>(xc, Wph2, hb, dinv, (hf2*)Q, N);
        // fused BN stats only needed when another BN layer follows
        float* statp = (l < 2) ? part : nullptr;
        agg_kernel<<<g_agg, 256, 0, stream>>>(Q, row_ptr, csr_src, dinv,
                                              ball + l * HDIM, xn, statp, N);
    }
    gemm_out<<<(N + 31) / 32, 320, 0, stream>>>(Xh0, Wo, bo, out, N, C);
}

// Round 6
// 606.243 us; speedup vs baseline: 3.0056x; 1.1715x over previous
//
#include <hip/hip_runtime.h>
#include <hip/hip_bf16.h>
#include <hip/hip_fp16.h>
#include <cstdint>

#define HDIM 128
#define BN_EPS 1e-5f
#define SCAN_CHUNK 1024

typedef _Float16 hf2 __attribute__((ext_vector_type(2)));

static inline size_t align256(size_t x) { return (x + 255) & ~size_t(255); }

// ---------- edge dtype detection (int64 vs int32) ----------
__global__ void detect_kernel(const int* __restrict__ ebuf, int* __restrict__ flag) {
    __shared__ int r[256];
    int tid = threadIdx.x;
    int o = 0;
    for (int i = tid; i < 4096; i += 256) o |= ebuf[2 * i + 1];
    r[tid] = o;
    __syncthreads();
    for (int s = 128; s > 0; s >>= 1) {
        if (tid < s) r[tid] |= r[tid + s];
        __syncthreads();
    }
    if (tid == 0) *flag = (r[0] == 0) ? 1 : 0;  // all-zero odd words => int64
}

// ---------- degree count + per-edge rank (atomic return value) ----------
__global__ void deg_rank(const int* __restrict__ ebuf, const int* __restrict__ flag,
                         int* __restrict__ deg, int* __restrict__ rank, int E) {
    int e = blockIdx.x * 256 + threadIdx.x;
    if (e >= E) return;
    int d = (*flag) ? ebuf[2 * (E + e)] : ebuf[E + e];
    rank[e] = atomicAdd(&deg[d], 1);
}

// ---------- multi-block exclusive scan of deg -> row_ptr (+dinv fused) ----------
__global__ __launch_bounds__(256) void scan_partial(const int* __restrict__ deg,
                                                    int* __restrict__ bsum, int n) {
    int base = blockIdx.x * SCAN_CHUNK;
    int t = threadIdx.x, lane = t & 63, w = t >> 6;
    int s = 0;
#pragma unroll
    for (int i = 0; i < 4; ++i) {
        int idx = base + t + 256 * i;
        if (idx < n) s += deg[idx];
    }
#pragma unroll
    for (int off = 32; off > 0; off >>= 1) s += __shfl_down(s, off);
    __shared__ int wred[4];
    if (lane == 0) wred[w] = s;
    __syncthreads();
    if (t == 0) bsum[blockIdx.x] = wred[0] + wred[1] + wred[2] + wred[3];
}

__global__ __launch_bounds__(128) void scan_offsets(const int* __restrict__ bsum,
                                                    int* __restrict__ bofs, int nb) {
    int t = threadIdx.x;
    int v = (t < nb) ? bsum[t] : 0;
    int x = v;
#pragma unroll
    for (int off = 1; off < 64; off <<= 1) {
        int y = __shfl_up(x, off);
        if ((t & 63) >= off) x += y;
    }
    __shared__ int w0tot;
    if (t == 63) w0tot = x;
    __syncthreads();
    int incl = x + ((t >= 64) ? w0tot : 0);
    if (t < nb) bofs[t] = incl - v;
}

__global__ __launch_bounds__(256) void scan_final(const int* __restrict__ deg,
                                                  const int* __restrict__ bofs,
                                                  int* __restrict__ row_ptr,
                                                  float* __restrict__ dinv, int n, int E) {
    int base = blockIdx.x * SCAN_CHUNK;
    int t = threadIdx.x, lane = t & 63, w = t >> 6;
    int d0[4]; int s = 0;
#pragma unroll
    for (int i = 0; i < 4; ++i) {
        int idx = base + t * 4 + i;
        d0[i] = (idx < n) ? deg[idx] : 0;
        s += d0[i];
    }
    int x = s;
#pragma unroll
    for (int off = 1; off < 64; off <<= 1) {
        int y = __shfl_up(x, off);
        if (lane >= off) x += y;
    }
    __shared__ int wsum[4];
    if (lane == 63) wsum[w] = x;
    __syncthreads();
    int woff = 0;
#pragma unroll
    for (int k = 0; k < 4; ++k) if (k < w) woff += wsum[k];
    int ex = x - s + woff + bofs[blockIdx.x];
#pragma unroll
    for (int i = 0; i < 4; ++i) {
        int idx = base + t * 4 + i;
        if (idx < n) {
            row_ptr[idx] = ex;
            dinv[idx] = rsqrtf((float)(d0[i] + 1));   // +1 self-loop
            ex += d0[i];
        }
    }
    if (blockIdx.x == 0 && t == 0) row_ptr[n] = E;
}

// ---------- CSR fill: no atomic, pure load->store ----------
__global__ void fill_csr(const int* __restrict__ ebuf, const int* __restrict__ flag,
                         const int* __restrict__ row_ptr, const int* __restrict__ rank,
                         int* __restrict__ csr_src, int E) {
    int e = blockIdx.x * 256 + threadIdx.x;
    if (e >= E) return;
    int s, d;
    if (*flag) { s = ebuf[2 * e]; d = ebuf[2 * (E + e)]; }
    else       { s = ebuf[e];     d = ebuf[E + e]; }
    csr_src[row_ptr[d] + rank[e]] = s;
}

// ---------- BN statistics, fp32 input (layer 0): vectorized, 1024 blocks ----------
// part layout: [block][256] floats, float2 (sum, sumsq) per channel
__global__ __launch_bounds__(256) void bn_partial_f32v(const float4* __restrict__ x4,
                                                       float* __restrict__ part, int n) {
    int t = threadIdx.x;
    int c4 = t & 31;        // float4 column (4 channels)
    int rsub = t >> 5;      // 0..7
    int rowsPer = (n + gridDim.x - 1) / gridDim.x;
    int r0 = blockIdx.x * rowsPer, r1 = min(r0 + rowsPer, n);
    float s[4] = {0.f, 0.f, 0.f, 0.f}, q[4] = {0.f, 0.f, 0.f, 0.f};
    for (int r = r0 + rsub; r < r1; r += 8) {
        float4 v = x4[(size_t)r * 32 + c4];
        s[0] += v.x; q[0] += v.x * v.x;
        s[1] += v.y; q[1] += v.y * v.y;
        s[2] += v.z; q[2] += v.z * v.z;
        s[3] += v.w; q[3] += v.w * v.w;
    }
    __shared__ float sS[8][HDIM], sQ[8][HDIM];
#pragma unroll
    for (int j = 0; j < 4; ++j) { sS[rsub][c4 * 4 + j] = s[j]; sQ[rsub][c4 * 4 + j] = q[j]; }
    __syncthreads();
    if (t < HDIM) {
        float ss = 0.f, qq = 0.f;
#pragma unroll
        for (int k = 0; k < 8; ++k) { ss += sS[k][t]; qq += sQ[k][t]; }
        ((float2*)part)[(size_t)blockIdx.x * 128 + t] = make_float2(ss, qq);
    }
}

// ---------- reduce partials (rows x 256) -> 64 x 256 ----------
__global__ __launch_bounds__(256) void bn_reduce1(const float* __restrict__ part,
                                                  float* __restrict__ part2, int rows) {
    int t = threadIdx.x;
    int per = (rows + gridDim.x - 1) / gridDim.x;
    int b0 = blockIdx.x * per, b1 = min(b0 + per, rows);
    float acc = 0.f;
    for (int r = b0; r < b1; ++r) acc += part[(size_t)r * 256 + t];
    part2[(size_t)blockIdx.x * 256 + t] = acc;
}

// ---------- finalize stats; build fp16 col-major k-paired Wp + fp32 hb ----------
__global__ __launch_bounds__(128) void bn_finalize(const float* __restrict__ part,
                                                   const float* __restrict__ gamma,
                                                   const float* __restrict__ beta,
                                                   const float* __restrict__ W,
                                                   hf2* __restrict__ Wph2,
                                                   float* __restrict__ hb, int n, int nb) {
    int c = threadIdx.x;
    float s = 0.f, s2 = 0.f;
    for (int b = 0; b < nb; ++b) {
        float2 v = ((const float2*)part)[(size_t)b * 128 + c];
        s += v.x; s2 += v.y;
    }
    float mean = s / n;
    float var = s2 / n - mean * mean;
    float sc = gamma[c] * rsqrtf(var + BN_EPS);
    float sf = beta[c] - mean * sc;
    __shared__ float scs[HDIM], shs[HDIM];
    scs[c] = sc; shs[c] = sf;
    __syncthreads();
    float acc = 0.f;
#pragma unroll 4
    for (int k2 = 0; k2 < 64; ++k2) {
        float wa = W[(2 * k2) * HDIM + c];
        float wb = W[(2 * k2 + 1) * HDIM + c];
        hf2 wv;
        wv.x = (_Float16)(scs[2 * k2] * wa);
        wv.y = (_Float16)(scs[2 * k2 + 1] * wb);
        Wph2[c * 64 + k2] = wv;                    // col-major, k-paired
        acc += shs[2 * k2] * wa + shs[2 * k2 + 1] * wb;
    }
    hb[c] = acc;
}

// ---------- GEMM: Q[N][128] = fp16(dinv[r] * (BN(x) @ W + hb)), fdot2 inner ----------
template<bool F16SRC>
__global__ __launch_bounds__(256) void gemm_dot(const void* __restrict__ xsrc,
                                                const hf2* __restrict__ Wph2,
                                                const float* __restrict__ hb,
                                                const float* __restrict__ dinv,
                                                hf2* __restrict__ Q, int n) {
    __shared__ hf2 xs[128][66];    // rows, pad->2-way-free banks
    __shared__ hf2 wls[128][66];   // cols, pad
    __shared__ float hbs[HDIM];
    int t = threadIdx.x;
    int rowBase = blockIdx.x * 128;
    {
        const uint2* wg = (const uint2*)Wph2;   // 4096 uint2
#pragma unroll
        for (int i = 0; i < 16; ++i) {
            int idx = t + 256 * i;
            int col = idx >> 5, ko = (idx & 31) * 2;
            *(uint2*)&wls[col][ko] = wg[idx];
        }
    }
    if (t < HDIM) hbs[t] = hb[t];
    if (F16SRC) {
        const uint4* xg = (const uint4*)xsrc;
#pragma unroll
        for (int i = 0; i < 8; ++i) {
            int idx = t + 256 * i;          // 2048 uint4
            int row = idx >> 4, o4 = idx & 15;
            int gr = rowBase + row;
            uint4 v = make_uint4(0, 0, 0, 0);
            if (gr < n) v = xg[(size_t)gr * 16 + o4];
            *(uint2*)&xs[row][o4 * 4]     = make_uint2(v.x, v.y);
            *(uint2*)&xs[row][o4 * 4 + 2] = make_uint2(v.z, v.w);
        }
    } else {
        const float4* xg = (const float4*)xsrc;
#pragma unroll
        for (int i = 0; i < 16; ++i) {
            int idx = t + 256 * i;          // 4096 float4
            int row = idx >> 5, o = idx & 31;
            int gr = rowBase + row;
            float4 v = make_float4(0.f, 0.f, 0.f, 0.f);
            if (gr < n) v = xg[(size_t)gr * 32 + o];
            hf2 a; a.x = (_Float16)v.x; a.y = (_Float16)v.y;
            hf2 b; b.x = (_Float16)v.z; b.y = (_Float16)v.w;
            xs[row][o * 2] = a; xs[row][o * 2 + 1] = b;
        }
    }
    __syncthreads();
    int tc = t & 15, tr = t >> 4;
    float acc[8][8];
#pragma unroll
    for (int r = 0; r < 8; ++r)
#pragma unroll
        for (int q = 0; q < 8; ++q) acc[r][q] = 0.f;
#pragma unroll 2
    for (int k2 = 0; k2 < 64; k2 += 2) {
        uint2 xr[8], wc[8];
#pragma unroll
        for (int r = 0; r < 8; ++r) xr[r] = *(const uint2*)&xs[8 * tr + r][k2];
#pragma unroll
        for (int i = 0; i < 4; ++i)
#pragma unroll
            for (int j = 0; j < 2; ++j)
                wc[i * 2 + j] = *(const uint2*)&wls[32 * i + 2 * tc + j][k2];
#pragma unroll
        for (int r = 0; r < 8; ++r)
#pragma unroll
            for (int q = 0; q < 8; ++q) {
                hf2 xa = ((const hf2*)&xr[r])[0];
                hf2 xb = ((const hf2*)&xr[r])[1];
                hf2 wa = ((const hf2*)&wc[q])[0];
                hf2 wb = ((const hf2*)&wc[q])[1];
                acc[r][q] = __builtin_amdgcn_fdot2(xa, wa, acc[r][q], false);
                acc[r][q] = __builtin_amdgcn_fdot2(xb, wb, acc[r][q], false);
            }
    }
#pragma unroll
    for (int r = 0; r < 8; ++r) {
        int row = rowBase + 8 * tr + r;
        if (row < n) {
            float dvr = dinv[row];
#pragma unroll
            for (int i = 0; i < 4; ++i) {
                int c0 = 32 * i + 2 * tc;
                hf2 v;
                v.x = (_Float16)(dvr * (acc[r][2 * i + 0] + hbs[c0]));
                v.y = (_Float16)(dvr * (acc[r][2 * i + 1] + hbs[c0 + 1]));
                Q[(size_t)row * 64 + 16 * i + tc] = v;
            }
        }
    }
}

// ---------- aggregation + fused next-layer BN partial stats ----------
__device__ __forceinline__ void add8(float acc[8], uint4 v) {
    const __half2* p = (const __half2*)&v;
#pragma unroll
    for (int j = 0; j < 4; ++j) {
        float2 f = __half22float2(p[j]);
        acc[2 * j]     += f.x;
        acc[2 * j + 1] += f.y;
    }
}

__global__ __launch_bounds__(256) void agg_kernel(const __half* __restrict__ h,
                                                  const int* __restrict__ row_ptr,
                                                  const int* __restrict__ csr_src,
                                                  const float* __restrict__ dinv,
                                                  const float* __restrict__ bias,
                                                  __half* __restrict__ xn,
                                                  float* __restrict__ part, int n) {
    int t = threadIdx.x;
    int lane16 = t & 15;              // channel group: 8 halves each
    int g = t >> 4;                   // node slot in block
    int d = blockIdx.x * 16 + g;
    bool active = (d < n);
    const uint4* h4 = (const uint4*)h;
    float v[8];
#pragma unroll
    for (int j = 0; j < 8; ++j) v[j] = 0.f;
    if (active) {
        float acc[8];
        {
            uint4 hv = h4[(size_t)d * 16 + lane16];   // self-loop term (weight 1)
            const __half2* p = (const __half2*)&hv;
#pragma unroll
            for (int j = 0; j < 4; ++j) {
                float2 f = __half22float2(p[j]);
                acc[2 * j]     = f.x;
                acc[2 * j + 1] = f.y;
            }
        }
        int e0 = row_ptr[d], e1 = row_ptr[d + 1];
        // masked 8-wide loop: all gathers issued every iteration, no serial tail
        for (int e = e0; e < e1; e += 8) {
            int idx[8]; bool m[8];
#pragma unroll
            for (int i = 0; i < 8; ++i) {
                int ee = e + i;
                m[i] = (ee < e1);
                idx[i] = csr_src[m[i] ? ee : e];
            }
            uint4 vv[8];
#pragma unroll
            for (int i = 0; i < 8; ++i) vv[i] = h4[(size_t)idx[i] * 16 + lane16];
#pragma unroll
            for (int i = 0; i < 8; ++i) if (m[i]) add8(acc, vv[i]);
        }
        float dv = dinv[d];
        const float4* bb = (const float4*)(bias + lane16 * 8);
        float4 b0 = bb[0], b1 = bb[1];
        v[0] = fmaxf(fmaf(dv, acc[0], b0.x), 0.f);
        v[1] = fmaxf(fmaf(dv, acc[1], b0.y), 0.f);
        v[2] = fmaxf(fmaf(dv, acc[2], b0.z), 0.f);
        v[3] = fmaxf(fmaf(dv, acc[3], b0.w), 0.f);
        v[4] = fmaxf(fmaf(dv, acc[4], b1.x), 0.f);
        v[5] = fmaxf(fmaf(dv, acc[5], b1.y), 0.f);
        v[6] = fmaxf(fmaf(dv, acc[6], b1.z), 0.f);
        v[7] = fmaxf(fmaf(dv, acc[7], b1.w), 0.f);
        union { uint4 u; __half2 h2[4]; } o;
        o.h2[0] = __floats2half2_rn(v[0], v[1]);
        o.h2[1] = __floats2half2_rn(v[2], v[3]);
        o.h2[2] = __floats2half2_rn(v[4], v[5]);
        o.h2[3] = __floats2half2_rn(v[6], v[7]);
        ((uint4*)xn)[(size_t)d * 16 + lane16] = o.u;
    }
    if (part) {   // fused BN partial stats for the next layer
        __shared__ float redS[16][HDIM];
        __shared__ float redQ[16][HDIM];
#pragma unroll
        for (int j = 0; j < 8; ++j) {
            redS[g][lane16 * 8 + j] = v[j];
            redQ[g][lane16 * 8 + j] = v[j] * v[j];
        }
        __syncthreads();
        if (t < HDIM) {
            float s = 0.f, q = 0.f;
#pragma unroll
            for (int k = 0; k < 16; ++k) { s += redS[k][t]; q += redQ[k][t]; }
            ((float2*)part)[(size_t)blockIdx.x * 128 + t] = make_float2(s, q);
        }
    }
}

// ---------- final projection: out[N][40] = x(fp16) @ Wo + bo ----------
__global__ __launch_bounds__(320) void gemm_out(const __half* __restrict__ x,
                                                const float* __restrict__ Wo,
                                                const float* __restrict__ bo,
                                                float* __restrict__ out, int n, int C) {
    __shared__ __align__(16) float wls[HDIM * 40];   // 20 KiB
    __shared__ __align__(16) float xs[32 * HDIM];    // 16 KiB
    __shared__ float bos[40];
    int t = threadIdx.x;
    for (int i = t; i < HDIM * 40; i += 320) wls[i] = Wo[i];
    if (t < 40) bos[t] = bo[t];
    int c = t % 40, lr = t / 40;  // lr in 0..7
    int rowBase = blockIdx.x * 32;
    const uint4* xg = (const uint4*)x;
    for (int i = t; i < 512; i += 320) {  // 512 uint4 = 32 rows of fp16
        int row = i >> 4, o4 = i & 15;
        int gr = rowBase + row;
        uint4 v = make_uint4(0, 0, 0, 0);
        if (gr < n) v = xg[(size_t)gr * 16 + o4];
        union { uint4 u; __half2 h2[4]; } cv; cv.u = v;
        float2 f0 = __half22float2(cv.h2[0]);
        float2 f1 = __half22float2(cv.h2[1]);
        float2 f2 = __half22float2(cv.h2[2]);
        float2 f3 = __half22float2(cv.h2[3]);
        ((float4*)xs)[i * 2]     = make_float4(f0.x, f0.y, f1.x, f1.y);
        ((float4*)xs)[i * 2 + 1] = make_float4(f2.x, f2.y, f3.x, f3.y);
    }
    __syncthreads();
    const float4* xsr0 = (const float4*)(xs + (lr + 0) * HDIM);
    const float4* xsr1 = (const float4*)(xs + (lr + 8) * HDIM);
    const float4* xsr2 = (const float4*)(xs + (lr + 16) * HDIM);
    const float4* xsr3 = (const float4*)(xs + (lr + 24) * HDIM);
    float acc0 = 0.f, acc1 = 0.f, acc2 = 0.f, acc3 = 0.f;
#pragma unroll 4
    for (int k4 = 0; k4 < 32; ++k4) {
        float4 xv0 = xsr0[k4], xv1 = xsr1[k4], xv2 = xsr2[k4], xv3 = xsr3[k4];
#define OSTEP(kk, e0, e1, e2, e3)                          \
        {                                                   \
            float wv = wls[(k4 * 4 + kk) * 40 + c];         \
            acc0 = fmaf(e0, wv, acc0);                      \
            acc1 = fmaf(e1, wv, acc1);                      \
            acc2 = fmaf(e2, wv, acc2);                      \
            acc3 = fmaf(e3, wv, acc3);                      \
        }
        OSTEP(0, xv0.x, xv1.x, xv2.x, xv3.x)
        OSTEP(1, xv0.y, xv1.y, xv2.y, xv3.y)
        OSTEP(2, xv0.z, xv1.z, xv2.z, xv3.z)
        OSTEP(3, xv0.w, xv1.w, xv2.w, xv3.w)
#undef OSTEP
    }
    float bb = bos[c];
    int g0 = rowBase + lr;
    if (g0 < n)      out[(size_t)g0 * 40 + c]        = acc0 + bb;
    if (g0 + 8 < n)  out[(size_t)(g0 + 8) * 40 + c]  = acc1 + bb;
    if (g0 + 16 < n) out[(size_t)(g0 + 16) * 40 + c] = acc2 + bb;
    if (g0 + 24 < n) out[(size_t)(g0 + 24) * 40 + c] = acc3 + bb;
}

extern "C" void kernel_launch(void* const* d_in, const int* in_sizes, int n_in,
                              void* d_out, int out_size, void* d_ws, size_t ws_size,
                              hipStream_t stream) {
    const float* x_in  = (const float*)d_in[0];
    const int*   ebuf  = (const int*)d_in[1];
    const float* gamma = (const float*)d_in[2];
    const float* beta  = (const float*)d_in[3];
    const float* Wall  = (const float*)d_in[4];
    const float* ball  = (const float*)d_in[5];
    const float* Wo    = (const float*)d_in[6];
    const float* bo    = (const float*)d_in[7];
    float* out = (float*)d_out;
    const int N = in_sizes[0] / HDIM;
    const int E = in_sizes[1] / 2;
    const int C = 40;

    char* base = (char*)d_ws;
    size_t off = 0;
    auto alloc = [&](size_t bytes) -> void* {
        void* p = base + off;
        off = align256(off + bytes);
        return p;
    };
    const int g_agg = (N + 15) / 16;   // agg blocks (= BN partial rows)
    const int g_bn0 = 1024;            // layer-0 BN partial rows
    int part_rows = (g_agg > g_bn0) ? g_agg : g_bn0;
    __half* Xh0     = (__half*)alloc((size_t)N * HDIM * 2);
    __half* Xh1     = (__half*)alloc((size_t)N * HDIM * 2);
    __half* Q       = (__half*)alloc((size_t)N * HDIM * 2);
    int*    csr_src = (int*)alloc((size_t)E * 4);
    int*    rank    = (int*)alloc((size_t)E * 4);
    int*    deg     = (int*)alloc((size_t)N * 4);
    float*  dinv    = (float*)alloc((size_t)N * 4);
    int*    row_ptr = (int*)alloc((size_t)(N + 1) * 4);
    float*  part    = (float*)alloc((size_t)part_rows * 256 * 4);
    float*  part2   = (float*)alloc((size_t)64 * 256 * 4);
    hf2*    Wph2    = (hf2*)alloc((size_t)64 * HDIM * 4);
    float*  hb      = (float*)alloc((size_t)HDIM * 4);
    int*    bsum    = (int*)alloc((size_t)256 * 4);
    int*    bofs    = (int*)alloc((size_t)256 * 4);
    int*    flag    = (int*)alloc(4);

    hipMemsetAsync(deg, 0, (size_t)N * 4, stream);
    detect_kernel<<<1, 256, 0, stream>>>(ebuf, flag);
    int ge = (E + 255) / 256;
    deg_rank<<<ge, 256, 0, stream>>>(ebuf, flag, deg, rank, E);
    int nb = (N + SCAN_CHUNK - 1) / SCAN_CHUNK;   // 98 for N=100000 (<=128 required)
    scan_partial<<<nb, 256, 0, stream>>>(deg, bsum, N);
    scan_offsets<<<1, 128, 0, stream>>>(bsum, bofs, nb);
    scan_final<<<nb, 256, 0, stream>>>(deg, bofs, row_ptr, dinv, N, E);
    fill_csr<<<ge, 256, 0, stream>>>(ebuf, flag, row_ptr, rank, csr_src, E);

    int gg = (N + 127) / 128;
    for (int l = 0; l < 3; ++l) {
        const void* xc = (l == 0) ? (const void*)x_in
                                  : (l == 1) ? (const void*)Xh0 : (const void*)Xh1;
        __half* xn = (l == 0) ? Xh0 : (l == 1) ? Xh1 : Xh0;
        int rows;
        if (l == 0) {
            bn_partial_f32v<<<g_bn0, 256, 0, stream>>>((const float4*)xc, part, N);
            rows = g_bn0;
        } else {
            rows = g_agg;
        }
        bn_reduce1<<<64, 256, 0, stream>>>(part, part2, rows);
        bn_finalize<<<1, 128, 0, stream>>>(part2, gamma + l * HDIM, beta + l * HDIM,
                                           Wall + (size_t)l * HDIM * HDIM, Wph2, hb, N, 64);
        if (l == 0) gemm_dot<false><<<gg, 256, 0, stream>>>(xc, Wph2, hb, dinv, (hf2*)Q, N);
        else        gemm_dot<true ><<<gg, 256, 0, stream>>>(xc, Wph2, hb, dinv, (hf2*)Q, N);
        // fused BN stats only needed when another BN layer follows
        float* statp = (l < 2) ? part : nullptr;
        agg_kernel<<<g_agg, 256, 0, stream>>>(Q, row_ptr, csr_src, dinv,
                                              ball + l * HDIM, xn, statp, N);
    }
    gemm_out<<<(N + 31) / 32, 320, 0, stream>>>(Xh0, Wo, bo, out, N, C);
}

// Round 7
// 537.347 us; speedup vs baseline: 3.3910x; 1.1282x over previous
//
#include <hip/hip_runtime.h>
#include <hip/hip_bf16.h>
#include <hip/hip_fp16.h>
#include <cstdint>

#define HDIM 128
#define BN_EPS 1e-5f
#define SCAN_CHUNK 1024

typedef _Float16 hf2 __attribute__((ext_vector_type(2)));
typedef _Float16 hf8 __attribute__((ext_vector_type(8)));
typedef float f32x4 __attribute__((ext_vector_type(4)));

static inline size_t align256(size_t x) { return (x + 255) & ~size_t(255); }

// ---------- edge dtype detection (int64 vs int32) ----------
__global__ void detect_kernel(const int* __restrict__ ebuf, int* __restrict__ flag) {
    __shared__ int r[256];
    int tid = threadIdx.x;
    int o = 0;
    for (int i = tid; i < 4096; i += 256) o |= ebuf[2 * i + 1];
    r[tid] = o;
    __syncthreads();
    for (int s = 128; s > 0; s >>= 1) {
        if (tid < s) r[tid] |= r[tid + s];
        __syncthreads();
    }
    if (tid == 0) *flag = (r[0] == 0) ? 1 : 0;  // all-zero odd words => int64
}

// ---------- degree count + per-edge rank (atomic return value) ----------
__global__ void deg_rank(const int* __restrict__ ebuf, const int* __restrict__ flag,
                         int* __restrict__ deg, int* __restrict__ rank, int E) {
    int e = blockIdx.x * 256 + threadIdx.x;
    if (e >= E) return;
    int d = (*flag) ? ebuf[2 * (E + e)] : ebuf[E + e];
    rank[e] = atomicAdd(&deg[d], 1);
}

// ---------- multi-block exclusive scan of deg -> row_ptr (+dinv fused) ----------
__global__ __launch_bounds__(256) void scan_partial(const int* __restrict__ deg,
                                                    int* __restrict__ bsum, int n) {
    int base = blockIdx.x * SCAN_CHUNK;
    int t = threadIdx.x, lane = t & 63, w = t >> 6;
    int s = 0;
#pragma unroll
    for (int i = 0; i < 4; ++i) {
        int idx = base + t + 256 * i;
        if (idx < n) s += deg[idx];
    }
#pragma unroll
    for (int off = 32; off > 0; off >>= 1) s += __shfl_down(s, off);
    __shared__ int wred[4];
    if (lane == 0) wred[w] = s;
    __syncthreads();
    if (t == 0) bsum[blockIdx.x] = wred[0] + wred[1] + wred[2] + wred[3];
}

__global__ __launch_bounds__(128) void scan_offsets(const int* __restrict__ bsum,
                                                    int* __restrict__ bofs, int nb) {
    int t = threadIdx.x;
    int v = (t < nb) ? bsum[t] : 0;
    int x = v;
#pragma unroll
    for (int off = 1; off < 64; off <<= 1) {
        int y = __shfl_up(x, off);
        if ((t & 63) >= off) x += y;
    }
    __shared__ int w0tot;
    if (t == 63) w0tot = x;
    __syncthreads();
    int incl = x + ((t >= 64) ? w0tot : 0);
    if (t < nb) bofs[t] = incl - v;
}

__global__ __launch_bounds__(256) void scan_final(const int* __restrict__ deg,
                                                  const int* __restrict__ bofs,
                                                  int* __restrict__ row_ptr,
                                                  float* __restrict__ dinv, int n, int E) {
    int base = blockIdx.x * SCAN_CHUNK;
    int t = threadIdx.x, lane = t & 63, w = t >> 6;
    int d0[4]; int s = 0;
#pragma unroll
    for (int i = 0; i < 4; ++i) {
        int idx = base + t * 4 + i;
        d0[i] = (idx < n) ? deg[idx] : 0;
        s += d0[i];
    }
    int x = s;
#pragma unroll
    for (int off = 1; off < 64; off <<= 1) {
        int y = __shfl_up(x, off);
        if (lane >= off) x += y;
    }
    __shared__ int wsum[4];
    if (lane == 63) wsum[w] = x;
    __syncthreads();
    int woff = 0;
#pragma unroll
    for (int k = 0; k < 4; ++k) if (k < w) woff += wsum[k];
    int ex = x - s + woff + bofs[blockIdx.x];
#pragma unroll
    for (int i = 0; i < 4; ++i) {
        int idx = base + t * 4 + i;
        if (idx < n) {
            row_ptr[idx] = ex;
            dinv[idx] = rsqrtf((float)(d0[i] + 1));   // +1 self-loop
            ex += d0[i];
        }
    }
    if (blockIdx.x == 0 && t == 0) row_ptr[n] = E;
}

// ---------- CSR fill: no atomic, pure load->store ----------
__global__ void fill_csr(const int* __restrict__ ebuf, const int* __restrict__ flag,
                         const int* __restrict__ row_ptr, const int* __restrict__ rank,
                         int* __restrict__ csr_src, int E) {
    int e = blockIdx.x * 256 + threadIdx.x;
    if (e >= E) return;
    int s, d;
    if (*flag) { s = ebuf[2 * e]; d = ebuf[2 * (E + e)]; }
    else       { s = ebuf[e];     d = ebuf[E + e]; }
    csr_src[row_ptr[d] + rank[e]] = s;
}

// ---------- BN statistics, fp32 input (layer 0): vectorized, 1024 blocks ----------
__global__ __launch_bounds__(256) void bn_partial_f32v(const float4* __restrict__ x4,
                                                       float* __restrict__ part, int n) {
    int t = threadIdx.x;
    int c4 = t & 31;        // float4 column (4 channels)
    int rsub = t >> 5;      // 0..7
    int rowsPer = (n + gridDim.x - 1) / gridDim.x;
    int r0 = blockIdx.x * rowsPer, r1 = min(r0 + rowsPer, n);
    float s[4] = {0.f, 0.f, 0.f, 0.f}, q[4] = {0.f, 0.f, 0.f, 0.f};
    for (int r = r0 + rsub; r < r1; r += 8) {
        float4 v = x4[(size_t)r * 32 + c4];
        s[0] += v.x; q[0] += v.x * v.x;
        s[1] += v.y; q[1] += v.y * v.y;
        s[2] += v.z; q[2] += v.z * v.z;
        s[3] += v.w; q[3] += v.w * v.w;
    }
    __shared__ float sS[8][HDIM], sQ[8][HDIM];
#pragma unroll
    for (int j = 0; j < 4; ++j) { sS[rsub][c4 * 4 + j] = s[j]; sQ[rsub][c4 * 4 + j] = q[j]; }
    __syncthreads();
    if (t < HDIM) {
        float ss = 0.f, qq = 0.f;
#pragma unroll
        for (int k = 0; k < 8; ++k) { ss += sS[k][t]; qq += sQ[k][t]; }
        ((float2*)part)[(size_t)blockIdx.x * 128 + t] = make_float2(ss, qq);
    }
}

// ---------- reduce partials (rows x 256) -> 64 x 256 ----------
__global__ __launch_bounds__(256) void bn_reduce1(const float* __restrict__ part,
                                                  float* __restrict__ part2, int rows) {
    int t = threadIdx.x;
    int per = (rows + gridDim.x - 1) / gridDim.x;
    int b0 = blockIdx.x * per, b1 = min(b0 + per, rows);
    float acc = 0.f;
    for (int r = b0; r < b1; ++r) acc += part[(size_t)r * 256 + t];
    part2[(size_t)blockIdx.x * 256 + t] = acc;
}

// ---------- finalize stats; build fp16 FRAGMENT-ORDERED Wf + fp32 hb ----------
// Wf slot: (((col>>4)*4 + (k>>5))*64 + ((k>>3)&3)*16 + (col&15))*8 + (k&7)
//   = B-fragment layout for mfma_f32_16x16x32_f16 with k-perm k = 32*kk + 8*a + j
__global__ __launch_bounds__(128) void bn_finalize(const float* __restrict__ part,
                                                   const float* __restrict__ gamma,
                                                   const float* __restrict__ beta,
                                                   const float* __restrict__ W,
                                                   _Float16* __restrict__ Wf,
                                                   float* __restrict__ hb, int n, int nb) {
    int c = threadIdx.x;
    float s = 0.f, s2 = 0.f;
    for (int b = 0; b < nb; ++b) {
        float2 v = ((const float2*)part)[(size_t)b * 128 + c];
        s += v.x; s2 += v.y;
    }
    float mean = s / n;
    float var = s2 / n - mean * mean;
    float sc = gamma[c] * rsqrtf(var + BN_EPS);
    float sf = beta[c] - mean * sc;
    __shared__ float scs[HDIM], shs[HDIM];
    scs[c] = sc; shs[c] = sf;
    __syncthreads();
    float acc = 0.f;
    int tbase = (c >> 4) * 4;       // n-tile
    int nlane = c & 15;
#pragma unroll 4
    for (int k = 0; k < HDIM; ++k) {
        float w = W[k * HDIM + c];
        int idx = (((tbase + (k >> 5)) * 64) + (((k >> 3) & 3) * 16 + nlane)) * 8 + (k & 7);
        Wf[idx] = (_Float16)(scs[k] * w);
        acc += shs[k] * w;
    }
    hb[c] = acc;
}

// ---------- MFMA GEMM: Q[N][128] = fp16(dinv[r] * (BN(x) @ W + hb)) ----------
// 128x128 tile, 4 waves (2x2), W entirely in registers (frag-ordered Wf).
template<bool F16SRC>
__global__ __launch_bounds__(256) void gemm_mfma(const void* __restrict__ xsrc,
                                                 const _Float16* __restrict__ Wf,
                                                 const float* __restrict__ hb,
                                                 const float* __restrict__ dinv,
                                                 __half* __restrict__ Q, int n) {
    constexpr int XS = 136;                       // halves per LDS row (272B, 16B-aligned)
    __shared__ _Float16 xs[128 * XS];
    __shared__ float dvs[128];
    __shared__ float hbs[128];
    int t = threadIdx.x;
    int rowBase = blockIdx.x * 128;
    if (t < 128) {
        int gr = rowBase + t;
        dvs[t] = (gr < n) ? dinv[gr] : 0.f;
        hbs[t] = hb[t];
    }
    // ---- load all B fragments into registers (coalesced, L2-hot) ----
    int wid = t >> 6, l = t & 63;
    int wm = wid >> 1, wn = wid & 1;
    const hf8* wf8 = (const hf8*)Wf;
    hf8 bf[4][4];                                 // [n-tile local][kk]
#pragma unroll
    for (int i = 0; i < 4; ++i)
#pragma unroll
        for (int kk = 0; kk < 4; ++kk)
            bf[i][kk] = wf8[((4 * wn + i) * 4 + kk) * 64 + l];
    // ---- stage x tile into LDS as fp16 ----
    if (F16SRC) {
        const uint4* xg = (const uint4*)xsrc;     // 16 uint4 per row
#pragma unroll
        for (int i = 0; i < 8; ++i) {
            int idx = t + 256 * i;                // 2048
            int row = idx >> 4, o4 = idx & 15;
            int gr = rowBase + row;
            uint4 v = make_uint4(0, 0, 0, 0);
            if (gr < n) v = xg[(size_t)gr * 16 + o4];
            *(uint4*)&xs[row * XS + o4 * 8] = v;
        }
    } else {
        const float4* xg = (const float4*)xsrc;   // 32 float4 per row
#pragma unroll
        for (int i = 0; i < 16; ++i) {
            int idx = t + 256 * i;                // 4096
            int row = idx >> 5, o = idx & 31;
            int gr = rowBase + row;
            float4 v = make_float4(0.f, 0.f, 0.f, 0.f);
            if (gr < n) v = xg[(size_t)gr * 32 + o];
            hf2 a; a.x = (_Float16)v.x; a.y = (_Float16)v.y;
            hf2 b; b.x = (_Float16)v.z; b.y = (_Float16)v.w;
            *(hf2*)&xs[row * XS + o * 4]     = a;
            *(hf2*)&xs[row * XS + o * 4 + 2] = b;
        }
    }
    __syncthreads();
    // ---- MFMA main: 4 m-tiles x 4 n-tiles per wave over 4 k-steps ----
    f32x4 acc[4][4] = {};
    int mlane = l & 15, agrp = l >> 4;
#pragma unroll
    for (int kk = 0; kk < 4; ++kk) {
        hf8 af[4];
#pragma unroll
        for (int mt = 0; mt < 4; ++mt)
            af[mt] = *(const hf8*)&xs[(64 * wm + 16 * mt + mlane) * XS + 32 * kk + 8 * agrp];
#pragma unroll
        for (int mt = 0; mt < 4; ++mt)
#pragma unroll
            for (int i = 0; i < 4; ++i)
                acc[mt][i] = __builtin_amdgcn_mfma_f32_16x16x32_f16(af[mt], bf[i][kk],
                                                                    acc[mt][i], 0, 0, 0);
    }
    // ---- epilogue: C/D layout col=lane&15, row=(lane>>4)*4+j ----
#pragma unroll
    for (int mt = 0; mt < 4; ++mt) {
        int r0 = 64 * wm + 16 * mt + agrp * 4;
#pragma unroll
        for (int j = 0; j < 4; ++j) {
            int r = r0 + j;
            int grow = rowBase + r;
            if (grow < n) {
                float dv = dvs[r];
#pragma unroll
                for (int i = 0; i < 4; ++i) {
                    int c = 16 * (4 * wn + i) + mlane;
                    Q[(size_t)grow * 128 + c] = __float2half(dv * (acc[mt][i][j] + hbs[c]));
                }
            }
        }
    }
}

// ---------- aggregation + fused next-layer BN partial stats ----------
__device__ __forceinline__ void add8(float acc[8], uint4 v) {
    const __half2* p = (const __half2*)&v;
#pragma unroll
    for (int j = 0; j < 4; ++j) {
        float2 f = __half22float2(p[j]);
        acc[2 * j]     += f.x;
        acc[2 * j + 1] += f.y;
    }
}

__global__ __launch_bounds__(256) void agg_kernel(const __half* __restrict__ h,
                                                  const int* __restrict__ row_ptr,
                                                  const int* __restrict__ csr_src,
                                                  const float* __restrict__ dinv,
                                                  const float* __restrict__ bias,
                                                  __half* __restrict__ xn,
                                                  float* __restrict__ part, int n) {
    int t = threadIdx.x;
    int lane16 = t & 15;              // channel group: 8 halves each
    int g = t >> 4;                   // node slot in block
    int d = blockIdx.x * 16 + g;
    bool active = (d < n);
    const uint4* h4 = (const uint4*)h;
    float v[8];
#pragma unroll
    for (int j = 0; j < 8; ++j) v[j] = 0.f;
    if (active) {
        float acc[8];
        {
            uint4 hv = h4[(size_t)d * 16 + lane16];   // self-loop term (weight 1)
            const __half2* p = (const __half2*)&hv;
#pragma unroll
            for (int j = 0; j < 4; ++j) {
                float2 f = __half22float2(p[j]);
                acc[2 * j]     = f.x;
                acc[2 * j + 1] = f.y;
            }
        }
        int e0 = row_ptr[d], e1 = row_ptr[d + 1];
        for (int e = e0; e < e1; e += 8) {
            int idx[8]; bool m[8];
#pragma unroll
            for (int i = 0; i < 8; ++i) {
                int ee = e + i;
                m[i] = (ee < e1);
                idx[i] = csr_src[m[i] ? ee : e];
            }
            uint4 vv[8];
#pragma unroll
            for (int i = 0; i < 8; ++i) vv[i] = h4[(size_t)idx[i] * 16 + lane16];
#pragma unroll
            for (int i = 0; i < 8; ++i) if (m[i]) add8(acc, vv[i]);
        }
        float dv = dinv[d];
        const float4* bb = (const float4*)(bias + lane16 * 8);
        float4 b0 = bb[0], b1 = bb[1];
        v[0] = fmaxf(fmaf(dv, acc[0], b0.x), 0.f);
        v[1] = fmaxf(fmaf(dv, acc[1], b0.y), 0.f);
        v[2] = fmaxf(fmaf(dv, acc[2], b0.z), 0.f);
        v[3] = fmaxf(fmaf(dv, acc[3], b0.w), 0.f);
        v[4] = fmaxf(fmaf(dv, acc[4], b1.x), 0.f);
        v[5] = fmaxf(fmaf(dv, acc[5], b1.y), 0.f);
        v[6] = fmaxf(fmaf(dv, acc[6], b1.z), 0.f);
        v[7] = fmaxf(fmaf(dv, acc[7], b1.w), 0.f);
        union { uint4 u; __half2 h2[4]; } o;
        o.h2[0] = __floats2half2_rn(v[0], v[1]);
        o.h2[1] = __floats2half2_rn(v[2], v[3]);
        o.h2[2] = __floats2half2_rn(v[4], v[5]);
        o.h2[3] = __floats2half2_rn(v[6], v[7]);
        ((uint4*)xn)[(size_t)d * 16 + lane16] = o.u;
    }
    if (part) {   // fused BN partial stats for the next layer
        __shared__ float redS[16][HDIM];
        __shared__ float redQ[16][HDIM];
#pragma unroll
        for (int j = 0; j < 8; ++j) {
            redS[g][lane16 * 8 + j] = v[j];
            redQ[g][lane16 * 8 + j] = v[j] * v[j];
        }
        __syncthreads();
        if (t < HDIM) {
            float s = 0.f, q = 0.f;
#pragma unroll
            for (int k = 0; k < 16; ++k) { s += redS[k][t]; q += redQ[k][t]; }
            ((float2*)part)[(size_t)blockIdx.x * 128 + t] = make_float2(s, q);
        }
    }
}

// ---------- final projection: out[N][40] = x(fp16) @ Wo + bo ----------
__global__ __launch_bounds__(320) void gemm_out(const __half* __restrict__ x,
                                                const float* __restrict__ Wo,
                                                const float* __restrict__ bo,
                                                float* __restrict__ out, int n, int C) {
    __shared__ __align__(16) float wls[HDIM * 40];   // 20 KiB
    __shared__ __align__(16) float xs[32 * HDIM];    // 16 KiB
    __shared__ float bos[40];
    int t = threadIdx.x;
    for (int i = t; i < HDIM * 40; i += 320) wls[i] = Wo[i];
    if (t < 40) bos[t] = bo[t];
    int c = t % 40, lr = t / 40;  // lr in 0..7
    int rowBase = blockIdx.x * 32;
    const uint4* xg = (const uint4*)x;
    for (int i = t; i < 512; i += 320) {  // 512 uint4 = 32 rows of fp16
        int row = i >> 4, o4 = i & 15;
        int gr = rowBase + row;
        uint4 v = make_uint4(0, 0, 0, 0);
        if (gr < n) v = xg[(size_t)gr * 16 + o4];
        union { uint4 u; __half2 h2[4]; } cv; cv.u = v;
        float2 f0 = __half22float2(cv.h2[0]);
        float2 f1 = __half22float2(cv.h2[1]);
        float2 f2 = __half22float2(cv.h2[2]);
        float2 f3 = __half22float2(cv.h2[3]);
        ((float4*)xs)[i * 2]     = make_float4(f0.x, f0.y, f1.x, f1.y);
        ((float4*)xs)[i * 2 + 1] = make_float4(f2.x, f2.y, f3.x, f3.y);
    }
    __syncthreads();
    const float4* xsr0 = (const float4*)(xs + (lr + 0) * HDIM);
    const float4* xsr1 = (const float4*)(xs + (lr + 8) * HDIM);
    const float4* xsr2 = (const float4*)(xs + (lr + 16) * HDIM);
    const float4* xsr3 = (const float4*)(xs + (lr + 24) * HDIM);
    float acc0 = 0.f, acc1 = 0.f, acc2 = 0.f, acc3 = 0.f;
#pragma unroll 4
    for (int k4 = 0; k4 < 32; ++k4) {
        float4 xv0 = xsr0[k4], xv1 = xsr1[k4], xv2 = xsr2[k4], xv3 = xsr3[k4];
#define OSTEP(kk, e0, e1, e2, e3)                          \
        {                                                   \
            float wv = wls[(k4 * 4 + kk) * 40 + c];         \
            acc0 = fmaf(e0, wv, acc0);                      \
            acc1 = fmaf(e1, wv, acc1);                      \
            acc2 = fmaf(e2, wv, acc2);                      \
            acc3 = fmaf(e3, wv, acc3);                      \
        }
        OSTEP(0, xv0.x, xv1.x, xv2.x, xv3.x)
        OSTEP(1, xv0.y, xv1.y, xv2.y, xv3.y)
        OSTEP(2, xv0.z, xv1.z, xv2.z, xv3.z)
        OSTEP(3, xv0.w, xv1.w, xv2.w, xv3.w)
#undef OSTEP
    }
    float bb = bos[c];
    int g0 = rowBase + lr;
    if (g0 < n)      out[(size_t)g0 * 40 + c]        = acc0 + bb;
    if (g0 + 8 < n)  out[(size_t)(g0 + 8) * 40 + c]  = acc1 + bb;
    if (g0 + 16 < n) out[(size_t)(g0 + 16) * 40 + c] = acc2 + bb;
    if (g0 + 24 < n) out[(size_t)(g0 + 24) * 40 + c] = acc3 + bb;
}

extern "C" void kernel_launch(void* const* d_in, const int* in_sizes, int n_in,
                              void* d_out, int out_size, void* d_ws, size_t ws_size,
                              hipStream_t stream) {
    const float* x_in  = (const float*)d_in[0];
    const int*   ebuf  = (const int*)d_in[1];
    const float* gamma = (const float*)d_in[2];
    const float* beta  = (const float*)d_in[3];
    const float* Wall  = (const float*)d_in[4];
    const float* ball  = (const float*)d_in[5];
    const float* Wo    = (const float*)d_in[6];
    const float* bo    = (const float*)d_in[7];
    float* out = (float*)d_out;
    const int N = in_sizes[0] / HDIM;
    const int E = in_sizes[1] / 2;
    const int C = 40;

    char* base = (char*)d_ws;
    size_t off = 0;
    auto alloc = [&](size_t bytes) -> void* {
        void* p = base + off;
        off = align256(off + bytes);
        return p;
    };
    const int g_agg = (N + 15) / 16;   // agg blocks (= BN partial rows)
    const int g_bn0 = 1024;            // layer-0 BN partial rows
    int part_rows = (g_agg > g_bn0) ? g_agg : g_bn0;
    __half*   Xh0     = (__half*)alloc((size_t)N * HDIM * 2);
    __half*   Xh1     = (__half*)alloc((size_t)N * HDIM * 2);
    __half*   Q       = (__half*)alloc((size_t)N * HDIM * 2);
    int*      csr_src = (int*)alloc((size_t)E * 4);
    int*      rank    = (int*)alloc((size_t)E * 4);
    int*      deg     = (int*)alloc((size_t)N * 4);
    float*    dinv    = (float*)alloc((size_t)N * 4);
    int*      row_ptr = (int*)alloc((size_t)(N + 1) * 4);
    float*    part    = (float*)alloc((size_t)part_rows * 256 * 4);
    float*    part2   = (float*)alloc((size_t)64 * 256 * 4);
    _Float16* Wf      = (_Float16*)alloc((size_t)HDIM * HDIM * 2);
    float*    hb      = (float*)alloc((size_t)HDIM * 4);
    int*      bsum    = (int*)alloc((size_t)256 * 4);
    int*      bofs    = (int*)alloc((size_t)256 * 4);
    int*      flag    = (int*)alloc(4);

    hipMemsetAsync(deg, 0, (size_t)N * 4, stream);
    detect_kernel<<<1, 256, 0, stream>>>(ebuf, flag);
    int ge = (E + 255) / 256;
    deg_rank<<<ge, 256, 0, stream>>>(ebuf, flag, deg, rank, E);
    int nb = (N + SCAN_CHUNK - 1) / SCAN_CHUNK;   // 98 for N=100000 (<=128 required)
    scan_partial<<<nb, 256, 0, stream>>>(deg, bsum, N);
    scan_offsets<<<1, 128, 0, stream>>>(bsum, bofs, nb);
    scan_final<<<nb, 256, 0, stream>>>(deg, bofs, row_ptr, dinv, N, E);
    fill_csr<<<ge, 256, 0, stream>>>(ebuf, flag, row_ptr, rank, csr_src, E);

    int gg = (N + 127) / 128;
    for (int l = 0; l < 3; ++l) {
        const void* xc = (l == 0) ? (const void*)x_in
                                  : (l == 1) ? (const void*)Xh0 : (const void*)Xh1;
        __half* xn = (l == 0) ? Xh0 : (l == 1) ? Xh1 : Xh0;
        int rows;
        if (l == 0) {
            bn_partial_f32v<<<g_bn0, 256, 0, stream>>>((const float4*)xc, part, N);
            rows = g_bn0;
        } else {
            rows = g_agg;
        }
        bn_reduce1<<<64, 256, 0, stream>>>(part, part2, rows);
        bn_finalize<<<1, 128, 0, stream>>>(part2, gamma + l * HDIM, beta + l * HDIM,
                                           Wall + (size_t)l * HDIM * HDIM, Wf, hb, N, 64);
        if (l == 0) gemm_mfma<false><<<gg, 256, 0, stream>>>(xc, Wf, hb, dinv, Q, N);
        else        gemm_mfma<true ><<<gg, 256, 0, stream>>>(xc, Wf, hb, dinv, Q, N);
        // fused BN stats only needed when another BN layer follows
        float* statp = (l < 2) ? part : nullptr;
        agg_kernel<<<g_agg, 256, 0, stream>>>(Q, row_ptr, csr_src, dinv,
                                              ball + l * HDIM, xn, statp, N);
    }
    gemm_out<<<(N + 31) / 32, 320, 0, stream>>>(Xh0, Wo, bo, out, N, C);
}

// Round 8
// 532.538 us; speedup vs baseline: 3.4216x; 1.0090x over previous
//
#include <hip/hip_runtime.h>
#include <hip/hip_bf16.h>
#include <hip/hip_fp16.h>
#include <cstdint>

#define HDIM 128
#define BN_EPS 1e-5f
#define SCAN_CHUNK 1024

typedef _Float16 hf2 __attribute__((ext_vector_type(2)));
typedef _Float16 hf8 __attribute__((ext_vector_type(8)));
typedef float f32x4 __attribute__((ext_vector_type(4)));

static inline size_t align256(size_t x) { return (x + 255) & ~size_t(255); }

// ---------- edge dtype detection (int64 vs int32) ----------
__global__ void detect_kernel(const int* __restrict__ ebuf, int* __restrict__ flag) {
    __shared__ int r[256];
    int tid = threadIdx.x;
    int o = 0;
    for (int i = tid; i < 4096; i += 256) o |= ebuf[2 * i + 1];
    r[tid] = o;
    __syncthreads();
    for (int s = 128; s > 0; s >>= 1) {
        if (tid < s) r[tid] |= r[tid + s];
        __syncthreads();
    }
    if (tid == 0) *flag = (r[0] == 0) ? 1 : 0;  // all-zero odd words => int64
}

// ---------- degree count + per-edge rank (atomic return value) ----------
// At the chip-wide fetch-add throughput wall (~23.5 G/s) — do not "optimize" with ILP (R4).
__global__ void deg_rank(const int* __restrict__ ebuf, const int* __restrict__ flag,
                         int* __restrict__ deg, int* __restrict__ rank, int E) {
    int e = blockIdx.x * 256 + threadIdx.x;
    if (e >= E) return;
    int d = (*flag) ? ebuf[2 * (E + e)] : ebuf[E + e];
    rank[e] = atomicAdd(&deg[d], 1);
}

// ---------- multi-block exclusive scan of deg -> row_ptr (+dinv fused) ----------
__global__ __launch_bounds__(256) void scan_partial(const int* __restrict__ deg,
                                                    int* __restrict__ bsum, int n) {
    int base = blockIdx.x * SCAN_CHUNK;
    int t = threadIdx.x, lane = t & 63, w = t >> 6;
    int s = 0;
#pragma unroll
    for (int i = 0; i < 4; ++i) {
        int idx = base + t + 256 * i;
        if (idx < n) s += deg[idx];
    }
#pragma unroll
    for (int off = 32; off > 0; off >>= 1) s += __shfl_down(s, off);
    __shared__ int wred[4];
    if (lane == 0) wred[w] = s;
    __syncthreads();
    if (t == 0) bsum[blockIdx.x] = wred[0] + wred[1] + wred[2] + wred[3];
}

__global__ __launch_bounds__(128) void scan_offsets(const int* __restrict__ bsum,
                                                    int* __restrict__ bofs, int nb) {
    int t = threadIdx.x;
    int v = (t < nb) ? bsum[t] : 0;
    int x = v;
#pragma unroll
    for (int off = 1; off < 64; off <<= 1) {
        int y = __shfl_up(x, off);
        if ((t & 63) >= off) x += y;
    }
    __shared__ int w0tot;
    if (t == 63) w0tot = x;
    __syncthreads();
    int incl = x + ((t >= 64) ? w0tot : 0);
    if (t < nb) bofs[t] = incl - v;
}

__global__ __launch_bounds__(256) void scan_final(const int* __restrict__ deg,
                                                  const int* __restrict__ bofs,
                                                  int* __restrict__ row_ptr,
                                                  float* __restrict__ dinv, int n, int E) {
    int base = blockIdx.x * SCAN_CHUNK;
    int t = threadIdx.x, lane = t & 63, w = t >> 6;
    int d0[4]; int s = 0;
#pragma unroll
    for (int i = 0; i < 4; ++i) {
        int idx = base + t * 4 + i;
        d0[i] = (idx < n) ? deg[idx] : 0;
        s += d0[i];
    }
    int x = s;
#pragma unroll
    for (int off = 1; off < 64; off <<= 1) {
        int y = __shfl_up(x, off);
        if (lane >= off) x += y;
    }
    __shared__ int wsum[4];
    if (lane == 63) wsum[w] = x;
    __syncthreads();
    int woff = 0;
#pragma unroll
    for (int k = 0; k < 4; ++k) if (k < w) woff += wsum[k];
    int ex = x - s + woff + bofs[blockIdx.x];
#pragma unroll
    for (int i = 0; i < 4; ++i) {
        int idx = base + t * 4 + i;
        if (idx < n) {
            row_ptr[idx] = ex;
            dinv[idx] = rsqrtf((float)(d0[i] + 1));   // +1 self-loop
            ex += d0[i];
        }
    }
    if (blockIdx.x == 0 && t == 0) row_ptr[n] = E;
}

// ---------- CSR fill: no atomic, pure load->store, 2 edges/thread ----------
__global__ void fill_csr(const int* __restrict__ ebuf, const int* __restrict__ flag,
                         const int* __restrict__ row_ptr, const int* __restrict__ rank,
                         int* __restrict__ csr_src, int E) {
    int base = blockIdx.x * 512 + threadIdx.x;
    bool f = (*flag != 0);
#pragma unroll
    for (int i = 0; i < 2; ++i) {
        int e = base + i * 256;
        if (e < E) {
            int s = f ? ebuf[2 * e] : ebuf[e];
            int d = f ? ebuf[2 * (E + e)] : ebuf[E + e];
            csr_src[row_ptr[d] + rank[e]] = s;
        }
    }
}

// ---------- BN statistics, fp32 input (layer 0): vectorized, 1024 blocks ----------
__global__ __launch_bounds__(256) void bn_partial_f32v(const float4* __restrict__ x4,
                                                       float* __restrict__ part, int n) {
    int t = threadIdx.x;
    int c4 = t & 31;        // float4 column (4 channels)
    int rsub = t >> 5;      // 0..7
    int rowsPer = (n + gridDim.x - 1) / gridDim.x;
    int r0 = blockIdx.x * rowsPer, r1 = min(r0 + rowsPer, n);
    float s[4] = {0.f, 0.f, 0.f, 0.f}, q[4] = {0.f, 0.f, 0.f, 0.f};
    for (int r = r0 + rsub; r < r1; r += 8) {
        float4 v = x4[(size_t)r * 32 + c4];
        s[0] += v.x; q[0] += v.x * v.x;
        s[1] += v.y; q[1] += v.y * v.y;
        s[2] += v.z; q[2] += v.z * v.z;
        s[3] += v.w; q[3] += v.w * v.w;
    }
    __shared__ float sS[8][HDIM], sQ[8][HDIM];
#pragma unroll
    for (int j = 0; j < 4; ++j) { sS[rsub][c4 * 4 + j] = s[j]; sQ[rsub][c4 * 4 + j] = q[j]; }
    __syncthreads();
    if (t < HDIM) {
        float ss = 0.f, qq = 0.f;
#pragma unroll
        for (int k = 0; k < 8; ++k) { ss += sS[k][t]; qq += sQ[k][t]; }
        ((float2*)part)[(size_t)blockIdx.x * 128 + t] = make_float2(ss, qq);
    }
}

// ---------- reduce partials (rows x 256) -> 64 x 256 ----------
__global__ __launch_bounds__(256) void bn_reduce1(const float* __restrict__ part,
                                                  float* __restrict__ part2, int rows) {
    int t = threadIdx.x;
    int per = (rows + gridDim.x - 1) / gridDim.x;
    int b0 = blockIdx.x * per, b1 = min(b0 + per, rows);
    float acc = 0.f;
    for (int r = b0; r < b1; ++r) acc += part[(size_t)r * 256 + t];
    part2[(size_t)blockIdx.x * 256 + t] = acc;
}

// ---------- finalize stats; build fp16 FRAGMENT-ORDERED Wf + fp32 hb ----------
// Wf slot: (((col>>4)*4 + (k>>5))*64 + ((k>>3)&3)*16 + (col&15))*8 + (k&7)
//   = B-fragment layout for mfma_f32_16x16x32_f16 with k-perm k = 32*kk + 8*a + j
__global__ __launch_bounds__(128) void bn_finalize(const float* __restrict__ part,
                                                   const float* __restrict__ gamma,
                                                   const float* __restrict__ beta,
                                                   const float* __restrict__ W,
                                                   _Float16* __restrict__ Wf,
                                                   float* __restrict__ hb, int n, int nb) {
    int c = threadIdx.x;
    float s = 0.f, s2 = 0.f;
    for (int b = 0; b < nb; ++b) {
        float2 v = ((const float2*)part)[(size_t)b * 128 + c];
        s += v.x; s2 += v.y;
    }
    float mean = s / n;
    float var = s2 / n - mean * mean;
    float sc = gamma[c] * rsqrtf(var + BN_EPS);
    float sf = beta[c] - mean * sc;
    __shared__ float scs[HDIM], shs[HDIM];
    scs[c] = sc; shs[c] = sf;
    __syncthreads();
    float acc = 0.f;
    int tbase = (c >> 4) * 4;       // n-tile
    int nlane = c & 15;
#pragma unroll 4
    for (int k = 0; k < HDIM; ++k) {
        float w = W[k * HDIM + c];
        int idx = (((tbase + (k >> 5)) * 64) + (((k >> 3) & 3) * 16 + nlane)) * 8 + (k & 7);
        Wf[idx] = (_Float16)(scs[k] * w);
        acc += shs[k] * w;
    }
    hb[c] = acc;
}

// ---------- MFMA GEMM: Q[N][128] = fp16(dinv[r] * (BN(x) @ W + hb)) ----------
// 128x128 tile, 4 waves (2x2), W entirely in registers (frag-ordered Wf).
template<bool F16SRC>
__global__ __launch_bounds__(256) void gemm_mfma(const void* __restrict__ xsrc,
                                                 const _Float16* __restrict__ Wf,
                                                 const float* __restrict__ hb,
                                                 const float* __restrict__ dinv,
                                                 __half* __restrict__ Q, int n) {
    constexpr int XS = 136;                       // halves per LDS row (272B, 16B-aligned)
    __shared__ _Float16 xs[128 * XS];
    __shared__ float dvs[128];
    __shared__ float hbs[128];
    int t = threadIdx.x;
    int rowBase = blockIdx.x * 128;
    if (t < 128) {
        int gr = rowBase + t;
        dvs[t] = (gr < n) ? dinv[gr] : 0.f;
        hbs[t] = hb[t];
    }
    // ---- load all B fragments into registers (coalesced, L2-hot) ----
    int wid = t >> 6, l = t & 63;
    int wm = wid >> 1, wn = wid & 1;
    const hf8* wf8 = (const hf8*)Wf;
    hf8 bf[4][4];                                 // [n-tile local][kk]
#pragma unroll
    for (int i = 0; i < 4; ++i)
#pragma unroll
        for (int kk = 0; kk < 4; ++kk)
            bf[i][kk] = wf8[((4 * wn + i) * 4 + kk) * 64 + l];
    // ---- stage x tile into LDS as fp16 ----
    if (F16SRC) {
        const uint4* xg = (const uint4*)xsrc;     // 16 uint4 per row
#pragma unroll
        for (int i = 0; i < 8; ++i) {
            int idx = t + 256 * i;                // 2048
            int row = idx >> 4, o4 = idx & 15;
            int gr = rowBase + row;
            uint4 v = make_uint4(0, 0, 0, 0);
            if (gr < n) v = xg[(size_t)gr * 16 + o4];
            *(uint4*)&xs[row * XS + o4 * 8] = v;
        }
    } else {
        const float4* xg = (const float4*)xsrc;   // 32 float4 per row
#pragma unroll
        for (int i = 0; i < 16; ++i) {
            int idx = t + 256 * i;                // 4096
            int row = idx >> 5, o = idx & 31;
            int gr = rowBase + row;
            float4 v = make_float4(0.f, 0.f, 0.f, 0.f);
            if (gr < n) v = xg[(size_t)gr * 32 + o];
            hf2 a; a.x = (_Float16)v.x; a.y = (_Float16)v.y;
            hf2 b; b.x = (_Float16)v.z; b.y = (_Float16)v.w;
            *(hf2*)&xs[row * XS + o * 4]     = a;
            *(hf2*)&xs[row * XS + o * 4 + 2] = b;
        }
    }
    __syncthreads();
    // ---- MFMA main: 4 m-tiles x 4 n-tiles per wave over 4 k-steps ----
    f32x4 acc[4][4] = {};
    int mlane = l & 15, agrp = l >> 4;
#pragma unroll
    for (int kk = 0; kk < 4; ++kk) {
        hf8 af[4];
#pragma unroll
        for (int mt = 0; mt < 4; ++mt)
            af[mt] = *(const hf8*)&xs[(64 * wm + 16 * mt + mlane) * XS + 32 * kk + 8 * agrp];
#pragma unroll
        for (int mt = 0; mt < 4; ++mt)
#pragma unroll
            for (int i = 0; i < 4; ++i)
                acc[mt][i] = __builtin_amdgcn_mfma_f32_16x16x32_f16(af[mt], bf[i][kk],
                                                                    acc[mt][i], 0, 0, 0);
    }
    // ---- epilogue: C/D layout col=lane&15, row=(lane>>4)*4+j ----
#pragma unroll
    for (int mt = 0; mt < 4; ++mt) {
        int r0 = 64 * wm + 16 * mt + agrp * 4;
#pragma unroll
        for (int j = 0; j < 4; ++j) {
            int r = r0 + j;
            int grow = rowBase + r;
            if (grow < n) {
                float dv = dvs[r];
#pragma unroll
                for (int i = 0; i < 4; ++i) {
                    int c = 16 * (4 * wn + i) + mlane;
                    Q[(size_t)grow * 128 + c] = __float2half(dv * (acc[mt][i][j] + hbs[c]));
                }
            }
        }
    }
}

// ---------- aggregation + fused next-layer BN partial stats ----------
__device__ __forceinline__ void add8(float acc[8], uint4 v) {
    const __half2* p = (const __half2*)&v;
#pragma unroll
    for (int j = 0; j < 4; ++j) {
        float2 f = __half22float2(p[j]);
        acc[2 * j]     += f.x;
        acc[2 * j + 1] += f.y;
    }
}

__global__ __launch_bounds__(256) void agg_kernel(const __half* __restrict__ h,
                                                  const int* __restrict__ row_ptr,
                                                  const int* __restrict__ csr_src,
                                                  const float* __restrict__ dinv,
                                                  const float* __restrict__ bias,
                                                  __half* __restrict__ xn,
                                                  float* __restrict__ part, int n) {
    int t = threadIdx.x;
    int lane16 = t & 15;              // channel group: 8 halves each
    int g = t >> 4;                   // node slot in block
    int d = blockIdx.x * 16 + g;
    bool active = (d < n);
    const uint4* h4 = (const uint4*)h;
    float v[8];
#pragma unroll
    for (int j = 0; j < 8; ++j) v[j] = 0.f;
    if (active) {
        float acc[8];
        {
            uint4 hv = h4[(size_t)d * 16 + lane16];   // self-loop term (weight 1)
            const __half2* p = (const __half2*)&hv;
#pragma unroll
            for (int j = 0; j < 4; ++j) {
                float2 f = __half22float2(p[j]);
                acc[2 * j]     = f.x;
                acc[2 * j + 1] = f.y;
            }
        }
        int e0 = row_ptr[d], e1 = row_ptr[d + 1];
        int e = e0;
        // full 16-wide batches: unconditional, 16 gathers in flight
        for (; e + 16 <= e1; e += 16) {
            int idx[16];
#pragma unroll
            for (int i = 0; i < 16; ++i) idx[i] = csr_src[e + i];
            uint4 vv[16];
#pragma unroll
            for (int i = 0; i < 16; ++i) vv[i] = h4[(size_t)idx[i] * 16 + lane16];
#pragma unroll
            for (int i = 0; i < 16; ++i) add8(acc, vv[i]);
        }
        // remainder: exec-predicated loads + adds (no clamped duplicate traffic)
        int rem = e1 - e;
        if (rem > 0) {
            int idx[16];
#pragma unroll
            for (int i = 0; i < 16; ++i)
                if (i < rem) idx[i] = csr_src[e + i];
            uint4 vv[16];
#pragma unroll
            for (int i = 0; i < 16; ++i)
                if (i < rem) vv[i] = h4[(size_t)idx[i] * 16 + lane16];
#pragma unroll
            for (int i = 0; i < 16; ++i)
                if (i < rem) add8(acc, vv[i]);
        }
        float dv = dinv[d];
        const float4* bb = (const float4*)(bias + lane16 * 8);
        float4 b0 = bb[0], b1 = bb[1];
        v[0] = fmaxf(fmaf(dv, acc[0], b0.x), 0.f);
        v[1] = fmaxf(fmaf(dv, acc[1], b0.y), 0.f);
        v[2] = fmaxf(fmaf(dv, acc[2], b0.z), 0.f);
        v[3] = fmaxf(fmaf(dv, acc[3], b0.w), 0.f);
        v[4] = fmaxf(fmaf(dv, acc[4], b1.x), 0.f);
        v[5] = fmaxf(fmaf(dv, acc[5], b1.y), 0.f);
        v[6] = fmaxf(fmaf(dv, acc[6], b1.z), 0.f);
        v[7] = fmaxf(fmaf(dv, acc[7], b1.w), 0.f);
        union { uint4 u; __half2 h2[4]; } o;
        o.h2[0] = __floats2half2_rn(v[0], v[1]);
        o.h2[1] = __floats2half2_rn(v[2], v[3]);
        o.h2[2] = __floats2half2_rn(v[4], v[5]);
        o.h2[3] = __floats2half2_rn(v[6], v[7]);
        ((uint4*)xn)[(size_t)d * 16 + lane16] = o.u;
    }
    if (part) {   // fused BN partial stats for the next layer
        __shared__ float redS[16][HDIM];
        __shared__ float redQ[16][HDIM];
#pragma unroll
        for (int j = 0; j < 8; ++j) {
            redS[g][lane16 * 8 + j] = v[j];
            redQ[g][lane16 * 8 + j] = v[j] * v[j];
        }
        __syncthreads();
        if (t < HDIM) {
            float s = 0.f, q = 0.f;
#pragma unroll
            for (int k = 0; k < 16; ++k) { s += redS[k][t]; q += redQ[k][t]; }
            ((float2*)part)[(size_t)blockIdx.x * 128 + t] = make_float2(s, q);
        }
    }
}

// ---------- final projection: out[N][40] = x(fp16) @ Wo + bo ----------
__global__ __launch_bounds__(320) void gemm_out(const __half* __restrict__ x,
                                                const float* __restrict__ Wo,
                                                const float* __restrict__ bo,
                                                float* __restrict__ out, int n, int C) {
    __shared__ __align__(16) float wls[HDIM * 40];   // 20 KiB
    __shared__ __align__(16) float xs[32 * HDIM];    // 16 KiB
    __shared__ float bos[40];
    int t = threadIdx.x;
    for (int i = t; i < HDIM * 40; i += 320) wls[i] = Wo[i];
    if (t < 40) bos[t] = bo[t];
    int c = t % 40, lr = t / 40;  // lr in 0..7
    int rowBase = blockIdx.x * 32;
    const uint4* xg = (const uint4*)x;
    for (int i = t; i < 512; i += 320) {  // 512 uint4 = 32 rows of fp16
        int row = i >> 4, o4 = i & 15;
        int gr = rowBase + row;
        uint4 v = make_uint4(0, 0, 0, 0);
        if (gr < n) v = xg[(size_t)gr * 16 + o4];
        union { uint4 u; __half2 h2[4]; } cv; cv.u = v;
        float2 f0 = __half22float2(cv.h2[0]);
        float2 f1 = __half22float2(cv.h2[1]);
        float2 f2 = __half22float2(cv.h2[2]);
        float2 f3 = __half22float2(cv.h2[3]);
        ((float4*)xs)[i * 2]     = make_float4(f0.x, f0.y, f1.x, f1.y);
        ((float4*)xs)[i * 2 + 1] = make_float4(f2.x, f2.y, f3.x, f3.y);
    }
    __syncthreads();
    const float4* xsr0 = (const float4*)(xs + (lr + 0) * HDIM);
    const float4* xsr1 = (const float4*)(xs + (lr + 8) * HDIM);
    const float4* xsr2 = (const float4*)(xs + (lr + 16) * HDIM);
    const float4* xsr3 = (const float4*)(xs + (lr + 24) * HDIM);
    float acc0 = 0.f, acc1 = 0.f, acc2 = 0.f, acc3 = 0.f;
#pragma unroll 4
    for (int k4 = 0; k4 < 32; ++k4) {
        float4 xv0 = xsr0[k4], xv1 = xsr1[k4], xv2 = xsr2[k4], xv3 = xsr3[k4];
#define OSTEP(kk, e0, e1, e2, e3)                          \
        {                                                   \
            float wv = wls[(k4 * 4 + kk) * 40 + c];         \
            acc0 = fmaf(e0, wv, acc0);                      \
            acc1 = fmaf(e1, wv, acc1);                      \
            acc2 = fmaf(e2, wv, acc2);                      \
            acc3 = fmaf(e3, wv, acc3);                      \
        }
        OSTEP(0, xv0.x, xv1.x, xv2.x, xv3.x)
        OSTEP(1, xv0.y, xv1.y, xv2.y, xv3.y)
        OSTEP(2, xv0.z, xv1.z, xv2.z, xv3.z)
        OSTEP(3, xv0.w, xv1.w, xv2.w, xv3.w)
#undef OSTEP
    }
    float bb = bos[c];
    int g0 = rowBase + lr;
    if (g0 < n)      out[(size_t)g0 * 40 + c]        = acc0 + bb;
    if (g0 + 8 < n)  out[(size_t)(g0 + 8) * 40 + c]  = acc1 + bb;
    if (g0 + 16 < n) out[(size_t)(g0 + 16) * 40 + c] = acc2 + bb;
    if (g0 + 24 < n) out[(size_t)(g0 + 24) * 40 + c] = acc3 + bb;
}

extern "C" void kernel_launch(void* const* d_in, const int* in_sizes, int n_in,
                              void* d_out, int out_size, void* d_ws, size_t ws_size,
                              hipStream_t stream) {
    const float* x_in  = (const float*)d_in[0];
    const int*   ebuf  = (const int*)d_in[1];
    const float* gamma = (const float*)d_in[2];
    const float* beta  = (const float*)d_in[3];
    const float* Wall  = (const float*)d_in[4];
    const float* ball  = (const float*)d_in[5];
    const float* Wo    = (const float*)d_in[6];
    const float* bo    = (const float*)d_in[7];
    float* out = (float*)d_out;
    const int N = in_sizes[0] / HDIM;
    const int E = in_sizes[1] / 2;
    const int C = 40;

    char* base = (char*)d_ws;
    size_t off = 0;
    auto alloc = [&](size_t bytes) -> void* {
        void* p = base + off;
        off = align256(off + bytes);
        return p;
    };
    const int g_agg = (N + 15) / 16;   // agg blocks (= BN partial rows)
    const int g_bn0 = 1024;            // layer-0 BN partial rows
    int part_rows = (g_agg > g_bn0) ? g_agg : g_bn0;
    __half*   Xh0     = (__half*)alloc((size_t)N * HDIM * 2);
    __half*   Xh1     = (__half*)alloc((size_t)N * HDIM * 2);
    __half*   Q       = (__half*)alloc((size_t)N * HDIM * 2);
    int*      csr_src = (int*)alloc((size_t)E * 4);
    int*      rank    = (int*)alloc((size_t)E * 4);
    int*      deg     = (int*)alloc((size_t)N * 4);
    float*    dinv    = (float*)alloc((size_t)N * 4);
    int*      row_ptr = (int*)alloc((size_t)(N + 1) * 4);
    float*    part    = (float*)alloc((size_t)part_rows * 256 * 4);
    float*    part2   = (float*)alloc((size_t)64 * 256 * 4);
    _Float16* Wf      = (_Float16*)alloc((size_t)HDIM * HDIM * 2);
    float*    hb      = (float*)alloc((size_t)HDIM * 4);
    int*      bsum    = (int*)alloc((size_t)256 * 4);
    int*      bofs    = (int*)alloc((size_t)256 * 4);
    int*      flag    = (int*)alloc(4);

    hipMemsetAsync(deg, 0, (size_t)N * 4, stream);
    detect_kernel<<<1, 256, 0, stream>>>(ebuf, flag);
    int ge = (E + 255) / 256;
    deg_rank<<<ge, 256, 0, stream>>>(ebuf, flag, deg, rank, E);
    int nb = (N + SCAN_CHUNK - 1) / SCAN_CHUNK;   // 98 for N=100000 (<=128 required)
    scan_partial<<<nb, 256, 0, stream>>>(deg, bsum, N);
    scan_offsets<<<1, 128, 0, stream>>>(bsum, bofs, nb);
    scan_final<<<nb, 256, 0, stream>>>(deg, bofs, row_ptr, dinv, N, E);
    fill_csr<<<(E + 511) / 512, 256, 0, stream>>>(ebuf, flag, row_ptr, rank, csr_src, E);

    int gg = (N + 127) / 128;
    for (int l = 0; l < 3; ++l) {
        const void* xc = (l == 0) ? (const void*)x_in
                                  : (l == 1) ? (const void*)Xh0 : (const void*)Xh1;
        __half* xn = (l == 0) ? Xh0 : (l == 1) ? Xh1 : Xh0;
        int rows;
        if (l == 0) {
            bn_partial_f32v<<<g_bn0, 256, 0, stream>>>((const float4*)xc, part, N);
            rows = g_bn0;
        } else {
            rows = g_agg;
        }
        bn_reduce1<<<64, 256, 0, stream>>>(part, part2, rows);
        bn_finalize<<<1, 128, 0, stream>>>(part2, gamma + l * HDIM, beta + l * HDIM,
                                           Wall + (size_t)l * HDIM * HDIM, Wf, hb, N, 64);
        if (l == 0) gemm_mfma<false><<<gg, 256, 0, stream>>>(xc, Wf, hb, dinv, Q, N);
        else        gemm_mfma<true ><<<gg, 256, 0, stream>>>(xc, Wf, hb, dinv, Q, N);
        // fused BN stats only needed when another BN layer follows
        float* statp = (l < 2) ? part : nullptr;
        agg_kernel<<<g_agg, 256, 0, stream>>>(Q, row_ptr, csr_src, dinv,
                                              ball + l * HDIM, xn, statp, N);
    }
    gemm_out<<<(N + 31) / 32, 320, 0, stream>>>(Xh0, Wo, bo, out, N, C);
}

// Round 9
// 507.638 us; speedup vs baseline: 3.5895x; 1.0491x over previous
//
#include <hip/hip_runtime.h>
#include <hip/hip_bf16.h>
#include <hip/hip_fp16.h>
#include <cstdint>

#define HDIM 128
#define BN_EPS 1e-5f
#define SCAN_CHUNK 1024
#define NCOPY 8

typedef _Float16 hf2 __attribute__((ext_vector_type(2)));
typedef _Float16 hf8 __attribute__((ext_vector_type(8)));
typedef float f32x4 __attribute__((ext_vector_type(4)));

static inline size_t align256(size_t x) { return (x + 255) & ~size_t(255); }

// ---------- edge dtype detection (int64 vs int32) ----------
__global__ void detect_kernel(const int* __restrict__ ebuf, int* __restrict__ flag) {
    __shared__ int r[256];
    int tid = threadIdx.x;
    int o = 0;
    for (int i = tid; i < 4096; i += 256) o |= ebuf[2 * i + 1];
    r[tid] = o;
    __syncthreads();
    for (int s = 128; s > 0; s >>= 1) {
        if (tid < s) r[tid] |= r[tid + s];
        __syncthreads();
    }
    if (tid == 0) *flag = (r[0] == 0) ? 1 : 0;  // all-zero odd words => int64
}

// ---------- degree count + rank, XCD-sharded counters ----------
// copy = blockIdx & 7: consecutive blocks round-robin XCDs -> each deg8 copy
// stays (mostly) in one XCD's L2 -> atomic lines don't ping-pong cross-XCD.
__global__ void deg_rank(const int* __restrict__ ebuf, const int* __restrict__ flag,
                         int* __restrict__ deg8, int* __restrict__ rank, int E, int n) {
    int e = blockIdx.x * 256 + threadIdx.x;
    if (e >= E) return;
    int d = (*flag) ? ebuf[2 * (E + e)] : ebuf[E + e];
    int copy = blockIdx.x & (NCOPY - 1);
    rank[e] = atomicAdd(&deg8[copy * n + d], 1);
}

// ---------- combine shards: deg total + per-copy exclusive offsets (in place) ----------
__global__ void combine_deg(int* __restrict__ deg8, int* __restrict__ deg, int n) {
    int d = blockIdx.x * 256 + threadIdx.x;
    if (d >= n) return;
    int run = 0;
#pragma unroll
    for (int c = 0; c < NCOPY; ++c) {
        int v = deg8[c * n + d];
        deg8[c * n + d] = run;      // exclusive offset of this copy
        run += v;
    }
    deg[d] = run;
}

// ---------- multi-block exclusive scan of deg -> row_ptr (+dinv fused) ----------
__global__ __launch_bounds__(256) void scan_partial(const int* __restrict__ deg,
                                                    int* __restrict__ bsum, int n) {
    int base = blockIdx.x * SCAN_CHUNK;
    int t = threadIdx.x, lane = t & 63, w = t >> 6;
    int s = 0;
#pragma unroll
    for (int i = 0; i < 4; ++i) {
        int idx = base + t + 256 * i;
        if (idx < n) s += deg[idx];
    }
#pragma unroll
    for (int off = 32; off > 0; off >>= 1) s += __shfl_down(s, off);
    __shared__ int wred[4];
    if (lane == 0) wred[w] = s;
    __syncthreads();
    if (t == 0) bsum[blockIdx.x] = wred[0] + wred[1] + wred[2] + wred[3];
}

__global__ __launch_bounds__(128) void scan_offsets(const int* __restrict__ bsum,
                                                    int* __restrict__ bofs, int nb) {
    int t = threadIdx.x;
    int v = (t < nb) ? bsum[t] : 0;
    int x = v;
#pragma unroll
    for (int off = 1; off < 64; off <<= 1) {
        int y = __shfl_up(x, off);
        if ((t & 63) >= off) x += y;
    }
    __shared__ int w0tot;
    if (t == 63) w0tot = x;
    __syncthreads();
    int incl = x + ((t >= 64) ? w0tot : 0);
    if (t < nb) bofs[t] = incl - v;
}

__global__ __launch_bounds__(256) void scan_final(const int* __restrict__ deg,
                                                  const int* __restrict__ bofs,
                                                  int* __restrict__ row_ptr,
                                                  float* __restrict__ dinv, int n, int E) {
    int base = blockIdx.x * SCAN_CHUNK;
    int t = threadIdx.x, lane = t & 63, w = t >> 6;
    int d0[4]; int s = 0;
#pragma unroll
    for (int i = 0; i < 4; ++i) {
        int idx = base + t * 4 + i;
        d0[i] = (idx < n) ? deg[idx] : 0;
        s += d0[i];
    }
    int x = s;
#pragma unroll
    for (int off = 1; off < 64; off <<= 1) {
        int y = __shfl_up(x, off);
        if (lane >= off) x += y;
    }
    __shared__ int wsum[4];
    if (lane == 63) wsum[w] = x;
    __syncthreads();
    int woff = 0;
#pragma unroll
    for (int k = 0; k < 4; ++k) if (k < w) woff += wsum[k];
    int ex = x - s + woff + bofs[blockIdx.x];
#pragma unroll
    for (int i = 0; i < 4; ++i) {
        int idx = base + t * 4 + i;
        if (idx < n) {
            row_ptr[idx] = ex;
            dinv[idx] = rsqrtf((float)(d0[i] + 1));   // +1 self-loop
            ex += d0[i];
        }
    }
    if (blockIdx.x == 0 && t == 0) row_ptr[n] = E;
}

// ---------- CSR fill: no atomic; pos = row_ptr + copy-offset + rank ----------
__global__ void fill_csr(const int* __restrict__ ebuf, const int* __restrict__ flag,
                         const int* __restrict__ row_ptr, const int* __restrict__ deg8,
                         const int* __restrict__ rank, int* __restrict__ csr_src,
                         int E, int n) {
    int base = blockIdx.x * 512 + threadIdx.x;
    bool f = (*flag != 0);
#pragma unroll
    for (int i = 0; i < 2; ++i) {
        int e = base + i * 256;
        if (e < E) {
            int s = f ? ebuf[2 * e] : ebuf[e];
            int d = f ? ebuf[2 * (E + e)] : ebuf[E + e];
            int copy = (e >> 8) & (NCOPY - 1);   // must match deg_rank's blockIdx&7
            csr_src[row_ptr[d] + deg8[copy * n + d] + rank[e]] = s;
        }
    }
}

// ---------- BN statistics, fp32 input (layer 0): vectorized, 1024 blocks ----------
__global__ __launch_bounds__(256) void bn_partial_f32v(const float4* __restrict__ x4,
                                                       float* __restrict__ part, int n) {
    int t = threadIdx.x;
    int c4 = t & 31;        // float4 column (4 channels)
    int rsub = t >> 5;      // 0..7
    int rowsPer = (n + gridDim.x - 1) / gridDim.x;
    int r0 = blockIdx.x * rowsPer, r1 = min(r0 + rowsPer, n);
    float s[4] = {0.f, 0.f, 0.f, 0.f}, q[4] = {0.f, 0.f, 0.f, 0.f};
    for (int r = r0 + rsub; r < r1; r += 8) {
        float4 v = x4[(size_t)r * 32 + c4];
        s[0] += v.x; q[0] += v.x * v.x;
        s[1] += v.y; q[1] += v.y * v.y;
        s[2] += v.z; q[2] += v.z * v.z;
        s[3] += v.w; q[3] += v.w * v.w;
    }
    __shared__ float sS[8][HDIM], sQ[8][HDIM];
#pragma unroll
    for (int j = 0; j < 4; ++j) { sS[rsub][c4 * 4 + j] = s[j]; sQ[rsub][c4 * 4 + j] = q[j]; }
    __syncthreads();
    if (t < HDIM) {
        float ss = 0.f, qq = 0.f;
#pragma unroll
        for (int k = 0; k < 8; ++k) { ss += sS[k][t]; qq += sQ[k][t]; }
        ((float2*)part)[(size_t)blockIdx.x * 128 + t] = make_float2(ss, qq);
    }
}

// ---------- reduce partials (rows x 256) -> 64 x 256 ----------
__global__ __launch_bounds__(256) void bn_reduce1(const float* __restrict__ part,
                                                  float* __restrict__ part2, int rows) {
    int t = threadIdx.x;
    int per = (rows + gridDim.x - 1) / gridDim.x;
    int b0 = blockIdx.x * per, b1 = min(b0 + per, rows);
    float acc = 0.f;
    for (int r = b0; r < b1; ++r) acc += part[(size_t)r * 256 + t];
    part2[(size_t)blockIdx.x * 256 + t] = acc;
}

// ---------- finalize stats; 8 blocks x 16 k-rows; hb as 8 partials ----------
// Wf slot: (((col>>4)*4 + (k>>5))*64 + ((k>>3)&3)*16 + (col&15))*8 + (k&7)
__global__ __launch_bounds__(128) void bn_finalize(const float* __restrict__ part,
                                                   const float* __restrict__ gamma,
                                                   const float* __restrict__ beta,
                                                   const float* __restrict__ W,
                                                   _Float16* __restrict__ Wf,
                                                   float* __restrict__ hbp, int n, int nb) {
    int c = threadIdx.x;
    // redundant per-block reduction of part2 (64 rows x 256) -> sc/sf
    float s = 0.f, s2 = 0.f;
    for (int b = 0; b < nb; ++b) {
        float2 v = ((const float2*)part)[(size_t)b * 128 + c];
        s += v.x; s2 += v.y;
    }
    float mean = s / n;
    float var = s2 / n - mean * mean;
    float sc = gamma[c] * rsqrtf(var + BN_EPS);
    float sf = beta[c] - mean * sc;
    __shared__ float scs[HDIM], shs[HDIM];
    scs[c] = sc; shs[c] = sf;
    __syncthreads();
    float acc = 0.f;
    int tbase = (c >> 4) * 4;       // n-tile
    int nlane = c & 15;
    int k0 = blockIdx.x * 16;
#pragma unroll 4
    for (int kk = 0; kk < 16; ++kk) {
        int k = k0 + kk;
        float w = W[k * HDIM + c];   // coalesced across c
        int idx = (((tbase + (k >> 5)) * 64) + (((k >> 3) & 3) * 16 + nlane)) * 8 + (k & 7);
        Wf[idx] = (_Float16)(scs[k] * w);
        acc += shs[k] * w;
    }
    hbp[blockIdx.x * HDIM + c] = acc;   // summed in gemm prologue
}

// ---------- MFMA GEMM: Q[N][128] = fp16(dinv[r] * (BN(x) @ W + hb)) ----------
template<bool F16SRC>
__global__ __launch_bounds__(256) void gemm_mfma(const void* __restrict__ xsrc,
                                                 const _Float16* __restrict__ Wf,
                                                 const float* __restrict__ hbp,
                                                 const float* __restrict__ dinv,
                                                 __half* __restrict__ Q, int n) {
    constexpr int XS = 136;                       // halves per LDS row (272B, 16B-aligned)
    __shared__ _Float16 xs[128 * XS];
    __shared__ float dvs[128];
    __shared__ float hbs[128];
    int t = threadIdx.x;
    int rowBase = blockIdx.x * 128;
    if (t < 128) {
        int gr = rowBase + t;
        dvs[t] = (gr < n) ? dinv[gr] : 0.f;
        float hsum = 0.f;
#pragma unroll
        for (int b = 0; b < 8; ++b) hsum += hbp[b * HDIM + t];
        hbs[t] = hsum;
    }
    // ---- load all B fragments into registers (coalesced, L2-hot) ----
    int wid = t >> 6, l = t & 63;
    int wm = wid >> 1, wn = wid & 1;
    const hf8* wf8 = (const hf8*)Wf;
    hf8 bf[4][4];                                 // [n-tile local][kk]
#pragma unroll
    for (int i = 0; i < 4; ++i)
#pragma unroll
        for (int kk = 0; kk < 4; ++kk)
            bf[i][kk] = wf8[((4 * wn + i) * 4 + kk) * 64 + l];
    // ---- stage x tile into LDS as fp16 ----
    if (F16SRC) {
        const uint4* xg = (const uint4*)xsrc;     // 16 uint4 per row
#pragma unroll
        for (int i = 0; i < 8; ++i) {
            int idx = t + 256 * i;                // 2048
            int row = idx >> 4, o4 = idx & 15;
            int gr = rowBase + row;
            uint4 v = make_uint4(0, 0, 0, 0);
            if (gr < n) v = xg[(size_t)gr * 16 + o4];
            *(uint4*)&xs[row * XS + o4 * 8] = v;
        }
    } else {
        const float4* xg = (const float4*)xsrc;   // 32 float4 per row
#pragma unroll
        for (int i = 0; i < 16; ++i) {
            int idx = t + 256 * i;                // 4096
            int row = idx >> 5, o = idx & 31;
            int gr = rowBase + row;
            float4 v = make_float4(0.f, 0.f, 0.f, 0.f);
            if (gr < n) v = xg[(size_t)gr * 32 + o];
            hf2 a; a.x = (_Float16)v.x; a.y = (_Float16)v.y;
            hf2 b; b.x = (_Float16)v.z; b.y = (_Float16)v.w;
            *(hf2*)&xs[row * XS + o * 4]     = a;
            *(hf2*)&xs[row * XS + o * 4 + 2] = b;
        }
    }
    __syncthreads();
    // ---- MFMA main: 4 m-tiles x 4 n-tiles per wave over 4 k-steps ----
    f32x4 acc[4][4] = {};
    int mlane = l & 15, agrp = l >> 4;
#pragma unroll
    for (int kk = 0; kk < 4; ++kk) {
        hf8 af[4];
#pragma unroll
        for (int mt = 0; mt < 4; ++mt)
            af[mt] = *(const hf8*)&xs[(64 * wm + 16 * mt + mlane) * XS + 32 * kk + 8 * agrp];
#pragma unroll
        for (int mt = 0; mt < 4; ++mt)
#pragma unroll
            for (int i = 0; i < 4; ++i)
                acc[mt][i] = __builtin_amdgcn_mfma_f32_16x16x32_f16(af[mt], bf[i][kk],
                                                                    acc[mt][i], 0, 0, 0);
    }
    // ---- epilogue: C/D layout col=lane&15, row=(lane>>4)*4+j ----
#pragma unroll
    for (int mt = 0; mt < 4; ++mt) {
        int r0 = 64 * wm + 16 * mt + agrp * 4;
#pragma unroll
        for (int j = 0; j < 4; ++j) {
            int r = r0 + j;
            int grow = rowBase + r;
            if (grow < n) {
                float dv = dvs[r];
#pragma unroll
                for (int i = 0; i < 4; ++i) {
                    int c = 16 * (4 * wn + i) + mlane;
                    Q[(size_t)grow * 128 + c] = __float2half(dv * (acc[mt][i][j] + hbs[c]));
                }
            }
        }
    }
}

// ---------- aggregation + fused next-layer BN partial stats ----------
__device__ __forceinline__ void add8(float acc[8], uint4 v) {
    const __half2* p = (const __half2*)&v;
#pragma unroll
    for (int j = 0; j < 4; ++j) {
        float2 f = __half22float2(p[j]);
        acc[2 * j]     += f.x;
        acc[2 * j + 1] += f.y;
    }
}

__global__ __launch_bounds__(256) void agg_kernel(const __half* __restrict__ h,
                                                  const int* __restrict__ row_ptr,
                                                  const int* __restrict__ csr_src,
                                                  const float* __restrict__ dinv,
                                                  const float* __restrict__ bias,
                                                  __half* __restrict__ xn,
                                                  float* __restrict__ part, int n) {
    int t = threadIdx.x;
    int lane16 = t & 15;              // channel group: 8 halves each
    int g = t >> 4;                   // node slot in block
    int d = blockIdx.x * 16 + g;
    bool active = (d < n);
    const uint4* h4 = (const uint4*)h;
    float v[8];
#pragma unroll
    for (int j = 0; j < 8; ++j) v[j] = 0.f;
    if (active) {
        float acc[8];
        {
            uint4 hv = h4[(size_t)d * 16 + lane16];   // self-loop term (weight 1)
            const __half2* p = (const __half2*)&hv;
#pragma unroll
            for (int j = 0; j < 4; ++j) {
                float2 f = __half22float2(p[j]);
                acc[2 * j]     = f.x;
                acc[2 * j + 1] = f.y;
            }
        }
        int e0 = row_ptr[d], e1 = row_ptr[d + 1];
        int e = e0;
        for (; e + 16 <= e1; e += 16) {
            int idx[16];
#pragma unroll
            for (int i = 0; i < 16; ++i) idx[i] = csr_src[e + i];
            uint4 vv[16];
#pragma unroll
            for (int i = 0; i < 16; ++i) vv[i] = h4[(size_t)idx[i] * 16 + lane16];
#pragma unroll
            for (int i = 0; i < 16; ++i) add8(acc, vv[i]);
        }
        int rem = e1 - e;
        if (rem > 0) {
            int idx[16];
#pragma unroll
            for (int i = 0; i < 16; ++i)
                if (i < rem) idx[i] = csr_src[e + i];
            uint4 vv[16];
#pragma unroll
            for (int i = 0; i < 16; ++i)
                if (i < rem) vv[i] = h4[(size_t)idx[i] * 16 + lane16];
#pragma unroll
            for (int i = 0; i < 16; ++i)
                if (i < rem) add8(acc, vv[i]);
        }
        float dv = dinv[d];
        const float4* bb = (const float4*)(bias + lane16 * 8);
        float4 b0 = bb[0], b1 = bb[1];
        v[0] = fmaxf(fmaf(dv, acc[0], b0.x), 0.f);
        v[1] = fmaxf(fmaf(dv, acc[1], b0.y), 0.f);
        v[2] = fmaxf(fmaf(dv, acc[2], b0.z), 0.f);
        v[3] = fmaxf(fmaf(dv, acc[3], b0.w), 0.f);
        v[4] = fmaxf(fmaf(dv, acc[4], b1.x), 0.f);
        v[5] = fmaxf(fmaf(dv, acc[5], b1.y), 0.f);
        v[6] = fmaxf(fmaf(dv, acc[6], b1.z), 0.f);
        v[7] = fmaxf(fmaf(dv, acc[7], b1.w), 0.f);
        union { uint4 u; __half2 h2[4]; } o;
        o.h2[0] = __floats2half2_rn(v[0], v[1]);
        o.h2[1] = __floats2half2_rn(v[2], v[3]);
        o.h2[2] = __floats2half2_rn(v[4], v[5]);
        o.h2[3] = __floats2half2_rn(v[6], v[7]);
        ((uint4*)xn)[(size_t)d * 16 + lane16] = o.u;
    }
    if (part) {   // fused BN partial stats for the next layer
        __shared__ float redS[16][HDIM];
        __shared__ float redQ[16][HDIM];
#pragma unroll
        for (int j = 0; j < 8; ++j) {
            redS[g][lane16 * 8 + j] = v[j];
            redQ[g][lane16 * 8 + j] = v[j] * v[j];
        }
        __syncthreads();
        if (t < HDIM) {
            float s = 0.f, q = 0.f;
#pragma unroll
            for (int k = 0; k < 16; ++k) { s += redS[k][t]; q += redQ[k][t]; }
            ((float2*)part)[(size_t)blockIdx.x * 128 + t] = make_float2(s, q);
        }
    }
}

// ---------- final projection: out[N][40] = x(fp16) @ Wo + bo ----------
__global__ __launch_bounds__(320) void gemm_out(const __half* __restrict__ x,
                                                const float* __restrict__ Wo,
                                                const float* __restrict__ bo,
                                                float* __restrict__ out, int n, int C) {
    __shared__ __align__(16) float wls[HDIM * 40];   // 20 KiB
    __shared__ __align__(16) float xs[32 * HDIM];    // 16 KiB
    __shared__ float bos[40];
    int t = threadIdx.x;
    for (int i = t; i < HDIM * 40; i += 320) wls[i] = Wo[i];
    if (t < 40) bos[t] = bo[t];
    int c = t % 40, lr = t / 40;  // lr in 0..7
    int rowBase = blockIdx.x * 32;
    const uint4* xg = (const uint4*)x;
    for (int i = t; i < 512; i += 320) {  // 512 uint4 = 32 rows of fp16
        int row = i >> 4, o4 = i & 15;
        int gr = rowBase + row;
        uint4 v = make_uint4(0, 0, 0, 0);
        if (gr < n) v = xg[(size_t)gr * 16 + o4];
        union { uint4 u; __half2 h2[4]; } cv; cv.u = v;
        float2 f0 = __half22float2(cv.h2[0]);
        float2 f1 = __half22float2(cv.h2[1]);
        float2 f2 = __half22float2(cv.h2[2]);
        float2 f3 = __half22float2(cv.h2[3]);
        ((float4*)xs)[i * 2]     = make_float4(f0.x, f0.y, f1.x, f1.y);
        ((float4*)xs)[i * 2 + 1] = make_float4(f2.x, f2.y, f3.x, f3.y);
    }
    __syncthreads();
    const float4* xsr0 = (const float4*)(xs + (lr + 0) * HDIM);
    const float4* xsr1 = (const float4*)(xs + (lr + 8) * HDIM);
    const float4* xsr2 = (const float4*)(xs + (lr + 16) * HDIM);
    const float4* xsr3 = (const float4*)(xs + (lr + 24) * HDIM);
    float acc0 = 0.f, acc1 = 0.f, acc2 = 0.f, acc3 = 0.f;
#pragma unroll 4
    for (int k4 = 0; k4 < 32; ++k4) {
        float4 xv0 = xsr0[k4], xv1 = xsr1[k4], xv2 = xsr2[k4], xv3 = xsr3[k4];
#define OSTEP(kk, e0, e1, e2, e3)                          \
        {                                                   \
            float wv = wls[(k4 * 4 + kk) * 40 + c];         \
            acc0 = fmaf(e0, wv, acc0);                      \
            acc1 = fmaf(e1, wv, acc1);                      \
            acc2 = fmaf(e2, wv, acc2);                      \
            acc3 = fmaf(e3, wv, acc3);                      \
        }
        OSTEP(0, xv0.x, xv1.x, xv2.x, xv3.x)
        OSTEP(1, xv0.y, xv1.y, xv2.y, xv3.y)
        OSTEP(2, xv0.z, xv1.z, xv2.z, xv3.z)
        OSTEP(3, xv0.w, xv1.w, xv2.w, xv3.w)
#undef OSTEP
    }
    float bb = bos[c];
    int g0 = rowBase + lr;
    if (g0 < n)      out[(size_t)g0 * 40 + c]        = acc0 + bb;
    if (g0 + 8 < n)  out[(size_t)(g0 + 8) * 40 + c]  = acc1 + bb;
    if (g0 + 16 < n) out[(size_t)(g0 + 16) * 40 + c] = acc2 + bb;
    if (g0 + 24 < n) out[(size_t)(g0 + 24) * 40 + c] = acc3 + bb;
}

extern "C" void kernel_launch(void* const* d_in, const int* in_sizes, int n_in,
                              void* d_out, int out_size, void* d_ws, size_t ws_size,
                              hipStream_t stream) {
    const float* x_in  = (const float*)d_in[0];
    const int*   ebuf  = (const int*)d_in[1];
    const float* gamma = (const float*)d_in[2];
    const float* beta  = (const float*)d_in[3];
    const float* Wall  = (const float*)d_in[4];
    const float* ball  = (const float*)d_in[5];
    const float* Wo    = (const float*)d_in[6];
    const float* bo    = (const float*)d_in[7];
    float* out = (float*)d_out;
    const int N = in_sizes[0] / HDIM;
    const int E = in_sizes[1] / 2;
    const int C = 40;

    char* base = (char*)d_ws;
    size_t off = 0;
    auto alloc = [&](size_t bytes) -> void* {
        void* p = base + off;
        off = align256(off + bytes);
        return p;
    };
    const int g_agg = (N + 15) / 16;   // agg blocks (= BN partial rows)
    const int g_bn0 = 1024;            // layer-0 BN partial rows
    int part_rows = (g_agg > g_bn0) ? g_agg : g_bn0;
    __half*   Xh0     = (__half*)alloc((size_t)N * HDIM * 2);
    __half*   Xh1     = (__half*)alloc((size_t)N * HDIM * 2);
    __half*   Q       = (__half*)alloc((size_t)N * HDIM * 2);
    int*      csr_src = (int*)alloc((size_t)E * 4);
    int*      rank    = (int*)alloc((size_t)E * 4);
    int*      deg8    = (int*)alloc((size_t)NCOPY * N * 4);
    int*      deg     = (int*)alloc((size_t)N * 4);
    float*    dinv    = (float*)alloc((size_t)N * 4);
    int*      row_ptr = (int*)alloc((size_t)(N + 1) * 4);
    float*    part    = (float*)alloc((size_t)part_rows * 256 * 4);
    float*    part2   = (float*)alloc((size_t)64 * 256 * 4);
    _Float16* Wf      = (_Float16*)alloc((size_t)HDIM * HDIM * 2);
    float*    hbp     = (float*)alloc((size_t)8 * HDIM * 4);
    int*      bsum    = (int*)alloc((size_t)256 * 4);
    int*      bofs    = (int*)alloc((size_t)256 * 4);
    int*      flag    = (int*)alloc(4);

    hipMemsetAsync(deg8, 0, (size_t)NCOPY * N * 4, stream);
    detect_kernel<<<1, 256, 0, stream>>>(ebuf, flag);
    int ge = (E + 255) / 256;
    deg_rank<<<ge, 256, 0, stream>>>(ebuf, flag, deg8, rank, E, N);
    combine_deg<<<(N + 255) / 256, 256, 0, stream>>>(deg8, deg, N);
    int nb = (N + SCAN_CHUNK - 1) / SCAN_CHUNK;   // 98 for N=100000 (<=128 required)
    scan_partial<<<nb, 256, 0, stream>>>(deg, bsum, N);
    scan_offsets<<<1, 128, 0, stream>>>(bsum, bofs, nb);
    scan_final<<<nb, 256, 0, stream>>>(deg, bofs, row_ptr, dinv, N, E);
    fill_csr<<<(E + 511) / 512, 256, 0, stream>>>(ebuf, flag, row_ptr, deg8, rank,
                                                  csr_src, E, N);

    int gg = (N + 127) / 128;
    for (int l = 0; l < 3; ++l) {
        const void* xc = (l == 0) ? (const void*)x_in
                                  : (l == 1) ? (const void*)Xh0 : (const void*)Xh1;
        __half* xn = (l == 0) ? Xh0 : (l == 1) ? Xh1 : Xh0;
        int rows;
        if (l == 0) {
            bn_partial_f32v<<<g_bn0, 256, 0, stream>>>((const float4*)xc, part, N);
            rows = g_bn0;
        } else {
            rows = g_agg;
        }
        bn_reduce1<<<64, 256, 0, stream>>>(part, part2, rows);
        bn_finalize<<<8, 128, 0, stream>>>(part2, gamma + l * HDIM, beta + l * HDIM,
                                           Wall + (size_t)l * HDIM * HDIM, Wf, hbp, N, 64);
        if (l == 0) gemm_mfma<false><<<gg, 256, 0, stream>>>(xc, Wf, hbp, dinv, Q, N);
        else        gemm_mfma<true ><<<gg, 256, 0, stream>>>(xc, Wf, hbp, dinv, Q, N);
        // fused BN stats only needed when another BN layer follows
        float* statp = (l < 2) ? part : nullptr;
        agg_kernel<<<g_agg, 256, 0, stream>>>(Q, row_ptr, csr_src, dinv,
                                              ball + l * HDIM, xn, statp, N);
    }
    gemm_out<<<(N + 31) / 32, 320, 0, stream>>>(Xh0, Wo, bo, out, N, C);
}